// Round 1
// baseline (6008.093 us; speedup 1.0000x reference)
//
#include <hip/hip_runtime.h>
#include <math.h>

// Problem constants
#define NQ 12
#define EQ 7
#define SQ 1024
#define TSQ 3
#define DIN 26400
#define BQ 2
#define TQ 4
#define BT 8          // B*T
#define BNN 288       // B*N*N
#define NROWS 2016    // E*BNN
#define G3S 3072      // 3*S

// ---------------- generic tiled GEMM: C = A(MxK) * B(NxK)^T (+bias) ----------------
#define TM 64
#define TN 64
#define TK 16

__global__ __launch_bounds__(256)
void gemm_tn(const float* __restrict__ A, long sAb, int lda,
             const float* __restrict__ Bm, long sBb, int ldb,
             const float* __restrict__ bias, long sBiasb,
             float* __restrict__ C, long sCb, int ldc,
             int M, int Nn, int K, int act)
{
    const int bz = blockIdx.z;
    A  += (long)bz * sAb;
    Bm += (long)bz * sBb;
    C  += (long)bz * sCb;

    __shared__ __align__(16) float As[TK][TM + 4];
    __shared__ __align__(16) float Bs[TK][TN + 4];

    const int tid = threadIdx.x;
    const int tx = tid & 15;
    const int ty = tid >> 4;
    const int row0 = blockIdx.x * TM;
    const int col0 = blockIdx.y * TN;
    const int lr = tid >> 2;          // 0..63
    const int lk = (tid & 3) << 2;    // 0,4,8,12

    float acc[4][4] = {};

    for (int k0 = 0; k0 < K; k0 += TK) {
        int ar = row0 + lr;
        float4 av = make_float4(0.f, 0.f, 0.f, 0.f);
        if (ar < M) av = *(const float4*)(A + (long)ar * lda + k0 + lk);
        As[lk + 0][lr] = av.x; As[lk + 1][lr] = av.y;
        As[lk + 2][lr] = av.z; As[lk + 3][lr] = av.w;

        int br = col0 + lr;
        float4 bv = make_float4(0.f, 0.f, 0.f, 0.f);
        if (br < Nn) bv = *(const float4*)(Bm + (long)br * ldb + k0 + lk);
        Bs[lk + 0][lr] = bv.x; Bs[lk + 1][lr] = bv.y;
        Bs[lk + 2][lr] = bv.z; Bs[lk + 3][lr] = bv.w;

        __syncthreads();
#pragma unroll
        for (int kk = 0; kk < TK; ++kk) {
            const float4 a4 = *(const float4*)&As[kk][ty << 2];
            const float4 b4 = *(const float4*)&Bs[kk][tx << 2];
            acc[0][0] += a4.x * b4.x; acc[0][1] += a4.x * b4.y;
            acc[0][2] += a4.x * b4.z; acc[0][3] += a4.x * b4.w;
            acc[1][0] += a4.y * b4.x; acc[1][1] += a4.y * b4.y;
            acc[1][2] += a4.y * b4.z; acc[1][3] += a4.y * b4.w;
            acc[2][0] += a4.z * b4.x; acc[2][1] += a4.z * b4.y;
            acc[2][2] += a4.z * b4.z; acc[2][3] += a4.z * b4.w;
            acc[3][0] += a4.w * b4.x; acc[3][1] += a4.w * b4.y;
            acc[3][2] += a4.w * b4.z; acc[3][3] += a4.w * b4.w;
        }
        __syncthreads();
    }

#pragma unroll
    for (int i = 0; i < 4; ++i) {
        int r = row0 + (ty << 2) + i;
        if (r >= M) continue;
#pragma unroll
        for (int j = 0; j < 4; ++j) {
            int c = col0 + (tx << 2) + j;
            if (c >= Nn) continue;
            float v = acc[i][j];
            if (bias) v += bias[(long)bz * sBiasb + c];
            if (act == 1) v = 1.f / (1.f + expf(-v));
            else if (act == 2) v = tanhf(v);
            C[(long)r * ldc + c] = v;
        }
    }
}

// ---------------- threefry2x32 (JAX-compatible) ----------------
__device__ inline unsigned rotl32(unsigned v, int r) { return (v << r) | (v >> (32 - r)); }

__device__ inline void tf2x32(unsigned k0, unsigned k1, unsigned x0, unsigned x1,
                              unsigned& o0, unsigned& o1)
{
    unsigned ks2 = k0 ^ k1 ^ 0x1BD11BDAu;
    x0 += k0; x1 += k1;
    x0 += x1; x1 = rotl32(x1, 13); x1 ^= x0;
    x0 += x1; x1 = rotl32(x1, 15); x1 ^= x0;
    x0 += x1; x1 = rotl32(x1, 26); x1 ^= x0;
    x0 += x1; x1 = rotl32(x1,  6); x1 ^= x0;
    x0 += k1; x1 += ks2 + 1u;
    x0 += x1; x1 = rotl32(x1, 17); x1 ^= x0;
    x0 += x1; x1 = rotl32(x1, 29); x1 ^= x0;
    x0 += x1; x1 = rotl32(x1, 16); x1 ^= x0;
    x0 += x1; x1 = rotl32(x1, 24); x1 ^= x0;
    x0 += ks2; x1 += k0 + 2u;
    x0 += x1; x1 = rotl32(x1, 13); x1 ^= x0;
    x0 += x1; x1 = rotl32(x1, 15); x1 ^= x0;
    x0 += x1; x1 = rotl32(x1, 26); x1 ^= x0;
    x0 += x1; x1 = rotl32(x1,  6); x1 ^= x0;
    x0 += k0; x1 += k1 + 3u;
    x0 += x1; x1 = rotl32(x1, 17); x1 ^= x0;
    x0 += x1; x1 = rotl32(x1, 29); x1 ^= x0;
    x0 += x1; x1 = rotl32(x1, 16); x1 ^= x0;
    x0 += x1; x1 = rotl32(x1, 24); x1 ^= x0;
    x0 += k1; x1 += ks2 + 4u;
    x0 += x1; x1 = rotl32(x1, 13); x1 ^= x0;
    x0 += x1; x1 = rotl32(x1, 15); x1 ^= x0;
    x0 += x1; x1 = rotl32(x1, 26); x1 ^= x0;
    x0 += x1; x1 = rotl32(x1,  6); x1 ^= x0;
    x0 += ks2; x1 += k0 + 5u;
    o0 = x0; o1 = x1;
}

__device__ inline float bits_to_normal(unsigned bits)
{
    float f = __uint_as_float((bits >> 9) | 0x3f800000u) - 1.0f;
    const float lo = -0.99999994f;   // nextafter(-1,0)
    float u = f * (1.0f - lo) + lo;
    u = fmaxf(u, lo);
    return 1.41421356237f * erfinvf(u);
}

#define HALF_E 147456   // (BNN*S)/2

__global__ void h0_fill(float* __restrict__ h, int t, float h0std)
{
    int i = blockIdx.x * blockDim.x + threadIdx.x;  // 0..147455
    int e = blockIdx.y;
    unsigned k0, k1, o0, o1;
    tf2x32(0u, 42u, 0u, (unsigned)(t * EQ + e), k0, k1);
    tf2x32(k0, k1, (unsigned)i, (unsigned)(i + HALF_E), o0, o1);
    float* he = h + (long)e * (BNN * SQ);
    he[i] = bits_to_normal(o0) * h0std;
    he[i + HALF_E] = bits_to_normal(o1) * h0std;
}

// ---------------- cbias[g] = bih[g] + sum_s bcomp[s]*Wih[g,s] ----------------
__global__ void cbias_k(const float* __restrict__ Wih, const float* __restrict__ bih,
                        const float* __restrict__ bcomp, float* __restrict__ cbias)
{
    int g = blockIdx.x * blockDim.x + threadIdx.x;
    if (g >= G3S) return;
    const float* w = Wih + (long)g * SQ;
    float s = 0.f;
    for (int k = 0; k < SQ; k += 4) {
        float4 wv = *(const float4*)(w + k);
        float4 bv = *(const float4*)(bcomp + k);
        s += wv.x * bv.x + wv.y * bv.y + wv.z * bv.z + wv.w * bv.w;
    }
    cbias[g] = s + bih[g];
}

__device__ inline float sigmoidf(float x) { return 1.f / (1.f + expf(-x)); }

// ---------------- fused GRU gate + state update + score ----------------
__global__ __launch_bounds__(256)
void gru_step(const float* __restrict__ Gn, const float* __restrict__ Gm,
              const float* __restrict__ cb, const float* __restrict__ gh,
              float* __restrict__ h, const float* __restrict__ Wa,
              const float* __restrict__ ba, float* __restrict__ gs, int tt)
{
    const int row = blockIdx.x;            // 0..2015 : e*288 + b*144 + n*12 + m
    const int e = row / BNN;
    const int r = row % BNN;
    const int b = r / 144;
    const int n = (r / 12) % 12;
    const int m = r % 12;
    const int bt = b * TQ + tt;

    const float* gn = Gn + ((long)(e * 96 + bt * 12 + n)) * G3S;
    const float* gm = Gm + ((long)(e * 96 + bt * 12 + m)) * G3S;
    const float* gq = gh + (long)row * G3S;
    float* hp = h + (long)row * SQ;

    const int s = threadIdx.x * 4;

    float4 gnR = *(const float4*)(gn + s);
    float4 gnZ = *(const float4*)(gn + SQ + s);
    float4 gnN = *(const float4*)(gn + 2 * SQ + s);
    float4 gmR = *(const float4*)(gm + s);
    float4 gmZ = *(const float4*)(gm + SQ + s);
    float4 gmN = *(const float4*)(gm + 2 * SQ + s);
    float4 cbR = *(const float4*)(cb + s);
    float4 cbZ = *(const float4*)(cb + SQ + s);
    float4 cbN = *(const float4*)(cb + 2 * SQ + s);
    float4 ghR = *(const float4*)(gq + s);
    float4 ghZ = *(const float4*)(gq + SQ + s);
    float4 ghN = *(const float4*)(gq + 2 * SQ + s);
    float4 hv  = *(const float4*)(hp + s);
    float4 wv  = *(const float4*)(Wa + (long)e * SQ + s);

    float4 hn4;
    float dot = 0.f;

#define GRU_COMP(c)                                                 \
    {                                                               \
        float gr = gnR.c + gmR.c + cbR.c + ghR.c;                   \
        float gz = gnZ.c + gmZ.c + cbZ.c + ghZ.c;                   \
        float gi = gnN.c + gmN.c + cbN.c;                           \
        float rg = sigmoidf(gr);                                    \
        float zg = sigmoidf(gz);                                    \
        float nn = tanhf(gi + rg * ghN.c);                          \
        float hn = (1.f - zg) * nn + zg * hv.c;                     \
        hn4.c = hn;                                                 \
        dot += hn * wv.c;                                           \
    }
    GRU_COMP(x) GRU_COMP(y) GRU_COMP(z) GRU_COMP(w)
#undef GRU_COMP

    *(float4*)(hp + s) = hn4;

    for (int off = 32; off > 0; off >>= 1) dot += __shfl_down(dot, off);
    __shared__ float red[4];
    if ((threadIdx.x & 63) == 0) red[threadIdx.x >> 6] = dot;
    __syncthreads();
    if (threadIdx.x == 0) {
        float tot = red[0] + red[1] + red[2] + red[3] + ba[e];
        gs[((bt * 12 + n) * 12 + m) * EQ + e] = sigmoidf(tot);
    }
}

// ---------------- merged[bt,n,s] = sum_{m,e} gs[bt,n,m,e]*msgs[bt,m,e,s] ----------------
__global__ __launch_bounds__(256)
void merged_k(const float* __restrict__ gs, const float* __restrict__ msgs,
              float* __restrict__ merged)
{
    const int bn = blockIdx.x;   // bt*12+n, 0..95
    const int bt = bn / 12;
    __shared__ float g[84];
    if (threadIdx.x < 84) g[threadIdx.x] = gs[bn * 84 + threadIdx.x];
    __syncthreads();
    const int s = threadIdx.x * 4;
    float4 acc = make_float4(0.f, 0.f, 0.f, 0.f);
    for (int j = 0; j < 84; ++j) {
        const float4 mv = *(const float4*)(msgs + ((long)(bt * 84 + j)) * SQ + s);
        float gj = g[j];
        acc.x += gj * mv.x; acc.y += gj * mv.y;
        acc.z += gj * mv.z; acc.w += gj * mv.w;
    }
    *(float4*)(merged + (long)bn * SQ + s) = acc;
}

// ---------------- small elementwise helpers ----------------
__global__ void amat_k(const float* __restrict__ merged, const float* __restrict__ prop,
                       float* __restrict__ amat)
{
    int i = blockIdx.x * 256 + threadIdx.x;   // 0..98303
    int rrow = i >> 10, c = i & 1023;
    amat[(long)rrow * 2048 + c] = merged[i];
    amat[(long)rrow * 2048 + 1024 + c] = prop[i];
}

__global__ void ahat_k(const float* __restrict__ rbuf, const float* __restrict__ prop,
                       float* __restrict__ amat)
{
    int i = blockIdx.x * 256 + threadIdx.x;
    int rrow = i >> 10, c = i & 1023;
    amat[(long)rrow * 2048 + 1024 + c] = rbuf[i] * prop[i];
}

__global__ void propupd_k(const float* __restrict__ zbuf, const float* __restrict__ hhat,
                          float* __restrict__ prop)
{
    int i = blockIdx.x * 256 + threadIdx.x;
    float z = zbuf[i];
    prop[i] = (1.f - z) * prop[i] + z * hhat[i];
}

__global__ void prop_reduce(const float* __restrict__ ptmp, const float* __restrict__ bc,
                            float* __restrict__ prop)
{
    int i = blockIdx.x * 256 + threadIdx.x;   // 0..98303
    float s = 0.f;
    for (int z = 0; z < 10; ++z) s += ptmp[(long)z * 98304 + i];
    prop[i] = s + bc[i & 1023];
}

// ---------------- final outputs ----------------
__global__ __launch_bounds__(256)
void outputs_k(const float* __restrict__ gs, float* __restrict__ out)
{
    __shared__ float s_act[672];
    __shared__ float s_asum[96];
    int tid = threadIdx.x;
    for (int idx = tid; idx < 672; idx += 256) {
        int bn = idx / 7, e = idx % 7;
        float sum = 0.f;
        for (int m = 0; m < 12; ++m) {
            float g0 = gs[bn * 84 + m * 7];
            sum += (1.f - g0) * gs[bn * 84 + m * 7 + e];
        }
        s_act[idx] = sum;
        out[idx] = sum;                       // action_score (B,T,N,E)
    }
    for (int idx = tid; idx < 96; idx += 256) {
        float a = 0.f;
        for (int m = 0; m < 12; ++m) a += 1.f - gs[idx * 84 + m * 7];
        s_asum[idx] = a;
    }
    for (int idx = tid; idx < 1152; idx += 256) {
        int bn = idx / 12, m = idx % 12;
        out[720 + idx] = 1.f - gs[bn * 84 + m * 7];   // actor_score (B,T,N,N)
    }
    __syncthreads();
    if (tid < 8) {   // bt
        float tmp[6];
        float mx = -1e30f;
        for (int e = 1; e < 7; ++e) {
            float sum = 0.f;
            for (int n = 0; n < 12; ++n) {
                int bn = tid * 12 + n;
                sum += s_act[bn * 7 + e] * s_asum[bn];
            }
            tmp[e - 1] = sum;
            mx = fmaxf(mx, sum);
        }
        float den = 0.f;
        for (int e = 0; e < 6; ++e) { tmp[e] = expf(tmp[e] - mx); den += tmp[e]; }
        for (int e = 0; e < 6; ++e) out[672 + tid * 6 + e] = tmp[e] / den;  // acty (B,T,6)
    }
}

// ---------------- host ----------------
static void launch_gemm(const float* A, long sAb, int lda,
                        const float* Bm, long sBb, int ldb,
                        const float* bias, long sBiasb,
                        float* C, long sCb, int ldc,
                        int M, int Nn, int K, int act, int batch, hipStream_t stream)
{
    dim3 grid((M + TM - 1) / TM, (Nn + TN - 1) / TN, batch);
    hipLaunchKernelGGL(gemm_tn, grid, dim3(256), 0, stream,
                       A, sAb, lda, Bm, sBb, ldb, bias, sBiasb, C, sCb, ldc, M, Nn, K, act);
}

extern "C" void kernel_launch(void* const* d_in, const int* in_sizes, int n_in,
                              void* d_out, int out_size, void* d_ws, size_t ws_size,
                              hipStream_t stream)
{
    const float* pose  = (const float*)d_in[0];
    const float* Wc    = (const float*)d_in[5];
    const float* bc    = (const float*)d_in[6];
    const float* We    = (const float*)d_in[7];
    const float* be    = (const float*)d_in[8];
    const float* Wcomp = (const float*)d_in[9];
    const float* bcomp = (const float*)d_in[10];
    const float* Wr    = (const float*)d_in[11];
    const float* br    = (const float*)d_in[12];
    const float* Wz    = (const float*)d_in[13];
    const float* bz    = (const float*)d_in[14];
    const float* Wh    = (const float*)d_in[15];
    const float* bh    = (const float*)d_in[16];
    const float* Wih   = (const float*)d_in[17];
    const float* Whh   = (const float*)d_in[18];
    const float* bih   = (const float*)d_in[19];
    const float* bhh   = (const float*)d_in[20];
    const float* Wa    = (const float*)d_in[21];
    const float* ba    = (const float*)d_in[22];

    float* ws = (float*)d_ws;
    // workspace layout (floats)
    float* prop   = ws;                    // 98304
    float* msgs   = prop + 98304;          // 688128
    float* Xn     = msgs + 688128;         // 688128
    float* Xm     = Xn + 688128;           // 688128
    float* Gn     = Xm + 688128;           // 2064384
    float* Gm     = Gn + 2064384;          // 2064384
    float* cbias  = Gm + 2064384;          // 3072
    float* h      = cbias + 3072;          // 2064384
    float* gh     = h + 2064384;           // 6193152
    float* gs     = gh + 6193152;          // 8064
    float* merged = gs + 8064;             // 98304
    float* amat   = merged + 98304;        // 196608
    float* rbuf   = amat + 196608;         // 98304
    float* zbuf   = rbuf + 98304;          // 98304
    float* hhat   = zbuf + 98304;          // 98304
    float* ptmp   = gh;                    // alias: 10*98304 fits in gh region

    const float h0std = sqrtf(2.0f / (288.0f * 1024.0f + 1024.0f));

    // cbias (once per call)
    hipLaunchKernelGGL(cbias_k, dim3(12), dim3(256), 0, stream, Wih, bih, bcomp, cbias);

    // prop = pose @ Wc^T + bc, split-K (10 slices of 2640)
    launch_gemm(pose, 2640, DIN, Wc, 2640, DIN, nullptr, 0,
                ptmp, 98304, 1024, 96, 1024, 2640, 0, 10, stream);
    hipLaunchKernelGGL(prop_reduce, dim3(384), dim3(256), 0, stream, ptmp, bc, prop);

    for (int t = 0; t <= TSQ; ++t) {
        // msgs[bt,n,e,s] (batched over e)
        launch_gemm(prop, 0, SQ, We, (long)SQ * SQ, SQ, be, SQ,
                    msgs, SQ, EQ * SQ, 96, SQ, SQ, 0, EQ, stream);
        // Xn = rf @ Wc1^T ; Xm = rf @ Wc2^T  (rf = msgs[:,:,e,:])
        launch_gemm(msgs, SQ, EQ * SQ, Wcomp, 0, 2 * SQ, nullptr, 0,
                    Xn, 98304, SQ, 96, SQ, SQ, 0, EQ, stream);
        launch_gemm(msgs, SQ, EQ * SQ, Wcomp + SQ, 0, 2 * SQ, nullptr, 0,
                    Xm, 98304, SQ, 96, SQ, SQ, 0, EQ, stream);
        // Gn = Xn @ Wih^T ; Gm = Xm @ Wih^T
        launch_gemm(Xn, 0, SQ, Wih, 0, SQ, nullptr, 0,
                    Gn, 0, G3S, 672, G3S, SQ, 0, 1, stream);
        launch_gemm(Xm, 0, SQ, Wih, 0, SQ, nullptr, 0,
                    Gm, 0, G3S, 672, G3S, SQ, 0, 1, stream);
        // h0 ~ threefry normal * h0_std
        hipLaunchKernelGGL(h0_fill, dim3(576, EQ), dim3(256), 0, stream, h, t, h0std);
        // GRU scan
        for (int tt = 0; tt < TQ; ++tt) {
            launch_gemm(h, 0, SQ, Whh, 0, SQ, bhh, 0,
                        gh, 0, G3S, NROWS, G3S, SQ, 0, 1, stream);
            hipLaunchKernelGGL(gru_step, dim3(NROWS), dim3(256), 0, stream,
                               Gn, Gm, cbias, gh, h, Wa, ba, gs, tt);
        }
        if (t < TSQ) {
            hipLaunchKernelGGL(merged_k, dim3(96), dim3(256), 0, stream, gs, msgs, merged);
            hipLaunchKernelGGL(amat_k, dim3(384), dim3(256), 0, stream, merged, prop, amat);
            launch_gemm(amat, 0, 2 * SQ, Wr, 0, 2 * SQ, br, 0,
                        rbuf, 0, SQ, 96, SQ, 2 * SQ, 1, 1, stream);
            launch_gemm(amat, 0, 2 * SQ, Wz, 0, 2 * SQ, bz, 0,
                        zbuf, 0, SQ, 96, SQ, 2 * SQ, 1, 1, stream);
            hipLaunchKernelGGL(ahat_k, dim3(384), dim3(256), 0, stream, rbuf, prop, amat);
            launch_gemm(amat, 0, 2 * SQ, Wh, 0, 2 * SQ, bh, 0,
                        hhat, 0, SQ, 96, SQ, 2 * SQ, 2, 1, stream);
            hipLaunchKernelGGL(propupd_k, dim3(384), dim3(256), 0, stream, zbuf, hhat, prop);
        }
    }

    hipLaunchKernelGGL(outputs_k, dim3(1), dim3(256), 0, stream, gs, (float*)d_out);
}

// Round 2
// 2930.003 us; speedup vs baseline: 2.0505x; 2.0505x over previous
//
#include <hip/hip_runtime.h>
#include <math.h>

// Problem constants
#define NQ 12
#define EQ 7
#define SQ 1024
#define TSQ 3
#define DIN 26400
#define BQ 2
#define TQ 4
#define BT 8          // B*T
#define BNN 288       // B*N*N
#define NROWS 2016    // E*BNN
#define G3S 3072      // 3*S
#define BK 32

typedef unsigned short u16;
typedef float f32x4 __attribute__((ext_vector_type(4)));
typedef short s16x8 __attribute__((ext_vector_type(8)));

// fp32 -> bf16, round-to-nearest (ties away)
__device__ __forceinline__ short bh(float f) {
    unsigned u = __float_as_uint(f);
    return (short)((u + 0x8000u) >> 16);
}

__device__ __forceinline__ s16x8 pack8(float4 a, float4 b) {
    s16x8 r;
    r[0] = bh(a.x); r[1] = bh(a.y); r[2] = bh(a.z); r[3] = bh(a.w);
    r[4] = bh(b.x); r[5] = bh(b.y); r[6] = bh(b.z); r[7] = bh(b.w);
    return r;
}

__device__ __forceinline__ void gload16(const void* g, void* l) {
    __builtin_amdgcn_global_load_lds(
        (const __attribute__((address_space(1))) unsigned*)g,
        (__attribute__((address_space(3))) unsigned*)l, 16, 0, 0);
}

// ================= bf16 MFMA GEMM: C = A(MxK) * B(NxK)^T =================
// AS32/BS32: operand is fp32 in global (convert during staging) vs bf16.
// LDS layout per buffer: [kg 0..3][row 0..127][8 bf16] (16B per slot).
template<int AS32, int BS32>
__global__ __launch_bounds__(256)
void gemm_mfma(const void* __restrict__ Ap, long sAb, int lda,
               const void* __restrict__ Bp, long sBb, int ldb,
               const float* __restrict__ bias, long sBiasb,
               float* __restrict__ C, long sCb, int ldc,
               u16* __restrict__ Cb, long sCbb, int ldcb,
               int M, int Nn, int K, int act)
{
    __shared__ __align__(16) u16 lA[2][512][8];
    __shared__ __align__(16) u16 lB[2][512][8];

    const int bz = blockIdx.z;
    const char* Abase = (const char*)Ap + (long)bz * sAb * (AS32 ? 4 : 2);
    const char* Bbase = (const char*)Bp + (long)bz * sBb * (BS32 ? 4 : 2);

    const int tid = threadIdx.x;
    const int lane = tid & 63;
    const int wave = tid >> 6;
    const int row0 = blockIdx.x * 128;
    const int col0 = blockIdx.y * 128;
    const int wrow = (wave >> 1) * 64;
    const int wcol = (wave & 1) * 64;

    // staging slots: slot s -> kg = s>>7, row = s&127, LDS byte = s*16
    const int s0 = tid, s1 = tid + 256;
    const int kg0 = s0 >> 7, r0 = s0 & 127;
    const int kg1 = s1 >> 7, r1 = s1 & 127;
    long ar0 = row0 + r0; if (ar0 >= M) ar0 = M - 1;
    long ar1 = row0 + r1; if (ar1 >= M) ar1 = M - 1;
    long br0 = col0 + r0; if (br0 >= Nn) br0 = Nn - 1;
    long br1 = col0 + r1; if (br1 >= Nn) br1 = Nn - 1;

    f32x4 acc[4][4] = {};

#define STAGE(b, kt) do {                                                     \
    const int k0_ = (kt) * BK;                                                \
    if constexpr (AS32) {                                                     \
        const float* A32 = (const float*)Abase;                               \
        const float* p0 = A32 + ar0 * lda + k0_ + kg0 * 8;                    \
        const float* p1 = A32 + ar1 * lda + k0_ + kg1 * 8;                    \
        float4 x0 = *(const float4*)p0, x1 = *(const float4*)(p0 + 4);        \
        float4 y0 = *(const float4*)p1, y1 = *(const float4*)(p1 + 4);        \
        *(s16x8*)&lA[b][s0][0] = pack8(x0, x1);                               \
        *(s16x8*)&lA[b][s1][0] = pack8(y0, y1);                               \
    } else {                                                                  \
        const u16* A16 = (const u16*)Abase;                                   \
        gload16(A16 + ar0 * lda + k0_ + kg0 * 8, &lA[b][s0][0]);              \
        gload16(A16 + ar1 * lda + k0_ + kg1 * 8, &lA[b][s1][0]);              \
    }                                                                         \
    if constexpr (BS32) {                                                     \
        const float* B32 = (const float*)Bbase;                               \
        const float* q0 = B32 + br0 * ldb + k0_ + kg0 * 8;                    \
        const float* q1 = B32 + br1 * ldb + k0_ + kg1 * 8;                    \
        float4 x0 = *(const float4*)q0, x1 = *(const float4*)(q0 + 4);        \
        float4 y0 = *(const float4*)q1, y1 = *(const float4*)(q1 + 4);        \
        *(s16x8*)&lB[b][s0][0] = pack8(x0, x1);                               \
        *(s16x8*)&lB[b][s1][0] = pack8(y0, y1);                               \
    } else {                                                                  \
        const u16* B16 = (const u16*)Bbase;                                   \
        gload16(B16 + br0 * ldb + k0_ + kg0 * 8, &lB[b][s0][0]);              \
        gload16(B16 + br1 * ldb + k0_ + kg1 * 8, &lB[b][s1][0]);              \
    }                                                                         \
} while (0)

    const int nk = K / BK;
    STAGE(0, 0);
    __syncthreads();
    int buf = 0;
    const int kg = lane >> 4;
    const int lr = lane & 15;
    for (int kt = 0; kt < nk; ++kt) {
        if (kt + 1 < nk) STAGE(buf ^ 1, kt + 1);
        s16x8 af[4], bfr[4];
#pragma unroll
        for (int m = 0; m < 4; ++m)
            af[m] = *(const s16x8*)&lA[buf][kg * 128 + wrow + m * 16 + lr][0];
#pragma unroll
        for (int n = 0; n < 4; ++n)
            bfr[n] = *(const s16x8*)&lB[buf][kg * 128 + wcol + n * 16 + lr][0];
#pragma unroll
        for (int m = 0; m < 4; ++m)
#pragma unroll
            for (int n = 0; n < 4; ++n)
                acc[m][n] = __builtin_amdgcn_mfma_f32_16x16x32_bf16(af[m], bfr[n], acc[m][n], 0, 0, 0);
        __syncthreads();
        buf ^= 1;
    }
#undef STAGE

    // C/D layout (m89-verified): col = lane&15, row = (lane>>4)*4 + reg
    const int ccol = lane & 15;
    const int crow = (lane >> 4) * 4;
#pragma unroll
    for (int n = 0; n < 4; ++n) {
        const int c = col0 + wcol + n * 16 + ccol;
        const float bv = bias ? bias[(long)bz * sBiasb + c] : 0.f;
#pragma unroll
        for (int m = 0; m < 4; ++m) {
            const int rb = row0 + wrow + m * 16 + crow;
#pragma unroll
            for (int q = 0; q < 4; ++q) {
                const int r = rb + q;
                if (r >= M) continue;
                float v = acc[m][n][q] + bv;
                if (act == 1) v = 1.f / (1.f + expf(-v));
                else if (act == 2) v = tanhf(v);
                if (C)  C[(long)bz * sCb + (long)r * ldc + c] = v;
                if (Cb) Cb[(long)bz * sCbb + (long)r * ldcb + c] = (u16)bh(v);
            }
        }
    }
}

// ---------------- fp32 -> bf16 bulk convert ----------------
__global__ void cvt_bf16_k(const float* __restrict__ src, u16* __restrict__ dst, int n4)
{
    int i = blockIdx.x * 256 + threadIdx.x;
    if (i >= n4) return;
    float4 v = ((const float4*)src)[i];
    ushort4 o;
    o.x = (u16)bh(v.x); o.y = (u16)bh(v.y); o.z = (u16)bh(v.z); o.w = (u16)bh(v.w);
    ((ushort4*)dst)[i] = o;
}

// ---------------- threefry2x32 (JAX-compatible) ----------------
__device__ inline unsigned rotl32(unsigned v, int r) { return (v << r) | (v >> (32 - r)); }

__device__ inline void tf2x32(unsigned k0, unsigned k1, unsigned x0, unsigned x1,
                              unsigned& o0, unsigned& o1)
{
    unsigned ks2 = k0 ^ k1 ^ 0x1BD11BDAu;
    x0 += k0; x1 += k1;
    x0 += x1; x1 = rotl32(x1, 13); x1 ^= x0;
    x0 += x1; x1 = rotl32(x1, 15); x1 ^= x0;
    x0 += x1; x1 = rotl32(x1, 26); x1 ^= x0;
    x0 += x1; x1 = rotl32(x1,  6); x1 ^= x0;
    x0 += k1; x1 += ks2 + 1u;
    x0 += x1; x1 = rotl32(x1, 17); x1 ^= x0;
    x0 += x1; x1 = rotl32(x1, 29); x1 ^= x0;
    x0 += x1; x1 = rotl32(x1, 16); x1 ^= x0;
    x0 += x1; x1 = rotl32(x1, 24); x1 ^= x0;
    x0 += ks2; x1 += k0 + 2u;
    x0 += x1; x1 = rotl32(x1, 13); x1 ^= x0;
    x0 += x1; x1 = rotl32(x1, 15); x1 ^= x0;
    x0 += x1; x1 = rotl32(x1, 26); x1 ^= x0;
    x0 += x1; x1 = rotl32(x1,  6); x1 ^= x0;
    x0 += k0; x1 += k1 + 3u;
    x0 += x1; x1 = rotl32(x1, 17); x1 ^= x0;
    x0 += x1; x1 = rotl32(x1, 29); x1 ^= x0;
    x0 += x1; x1 = rotl32(x1, 16); x1 ^= x0;
    x0 += x1; x1 = rotl32(x1, 24); x1 ^= x0;
    x0 += k1; x1 += ks2 + 4u;
    x0 += x1; x1 = rotl32(x1, 13); x1 ^= x0;
    x0 += x1; x1 = rotl32(x1, 15); x1 ^= x0;
    x0 += x1; x1 = rotl32(x1, 26); x1 ^= x0;
    x0 += x1; x1 = rotl32(x1,  6); x1 ^= x0;
    x0 += ks2; x1 += k0 + 5u;
    o0 = x0; o1 = x1;
}

__device__ inline float bits_to_normal(unsigned bits)
{
    float f = __uint_as_float((bits >> 9) | 0x3f800000u) - 1.0f;
    const float lo = -0.99999994f;
    float u = f * (1.0f - lo) + lo;
    u = fmaxf(u, lo);
    return 1.41421356237f * erfinvf(u);
}

#define HALF_E 147456   // (BNN*S)/2

__global__ void h0_fill(float* __restrict__ h, u16* __restrict__ hb, int t, float h0std)
{
    int i = blockIdx.x * blockDim.x + threadIdx.x;  // 0..147455
    int e = blockIdx.y;
    unsigned k0, k1, o0, o1;
    tf2x32(0u, 42u, 0u, (unsigned)(t * EQ + e), k0, k1);
    tf2x32(k0, k1, (unsigned)i, (unsigned)(i + HALF_E), o0, o1);
    float* he = h + (long)e * (BNN * SQ);
    u16* heb = hb + (long)e * (BNN * SQ);
    float v0 = bits_to_normal(o0) * h0std;
    float v1 = bits_to_normal(o1) * h0std;
    he[i] = v0;            heb[i] = (u16)bh(v0);
    he[i + HALF_E] = v1;   heb[i + HALF_E] = (u16)bh(v1);
}

// ---------------- cbias[g] = bih[g] + sum_s bcomp[s]*Wih[g,s] ----------------
__global__ void cbias_k(const float* __restrict__ Wih, const float* __restrict__ bih,
                        const float* __restrict__ bcomp, float* __restrict__ cbias)
{
    int g = blockIdx.x * blockDim.x + threadIdx.x;
    if (g >= G3S) return;
    const float* w = Wih + (long)g * SQ;
    float s = 0.f;
    for (int k = 0; k < SQ; k += 4) {
        float4 wv = *(const float4*)(w + k);
        float4 bv = *(const float4*)(bcomp + k);
        s += wv.x * bv.x + wv.y * bv.y + wv.z * bv.z + wv.w * bv.w;
    }
    cbias[g] = s + bih[g];
}

__device__ inline float sigmoidf(float x) { return 1.f / (1.f + expf(-x)); }

// ---------------- fused GRU gate + state update + score ----------------
__global__ __launch_bounds__(256)
void gru_step(const float* __restrict__ Gn, const float* __restrict__ Gm,
              const float* __restrict__ cb, const float* __restrict__ gh,
              float* __restrict__ h, u16* __restrict__ hb,
              const float* __restrict__ Wa,
              const float* __restrict__ ba, float* __restrict__ gs, int tt)
{
    const int row = blockIdx.x;            // 0..2015 : e*288 + b*144 + n*12 + m
    const int e = row / BNN;
    const int r = row % BNN;
    const int b = r / 144;
    const int n = (r / 12) % 12;
    const int m = r % 12;
    const int bt = b * TQ + tt;

    const float* gn = Gn + ((long)(e * 96 + bt * 12 + n)) * G3S;
    const float* gm = Gm + ((long)(e * 96 + bt * 12 + m)) * G3S;
    const float* gq = gh + (long)row * G3S;
    float* hp = h + (long)row * SQ;
    u16* hpb = hb + (long)row * SQ;

    const int s = threadIdx.x * 4;

    float4 gnR = *(const float4*)(gn + s);
    float4 gnZ = *(const float4*)(gn + SQ + s);
    float4 gnN = *(const float4*)(gn + 2 * SQ + s);
    float4 gmR = *(const float4*)(gm + s);
    float4 gmZ = *(const float4*)(gm + SQ + s);
    float4 gmN = *(const float4*)(gm + 2 * SQ + s);
    float4 cbR = *(const float4*)(cb + s);
    float4 cbZ = *(const float4*)(cb + SQ + s);
    float4 cbN = *(const float4*)(cb + 2 * SQ + s);
    float4 ghR = *(const float4*)(gq + s);
    float4 ghZ = *(const float4*)(gq + SQ + s);
    float4 ghN = *(const float4*)(gq + 2 * SQ + s);
    float4 hv  = *(const float4*)(hp + s);
    float4 wv  = *(const float4*)(Wa + (long)e * SQ + s);

    float4 hn4;
    float dot = 0.f;

#define GRU_COMP(c)                                                 \
    {                                                               \
        float gr = gnR.c + gmR.c + cbR.c + ghR.c;                   \
        float gz = gnZ.c + gmZ.c + cbZ.c + ghZ.c;                   \
        float gi = gnN.c + gmN.c + cbN.c;                           \
        float rg = sigmoidf(gr);                                    \
        float zg = sigmoidf(gz);                                    \
        float nn = tanhf(gi + rg * ghN.c);                          \
        float hn = (1.f - zg) * nn + zg * hv.c;                     \
        hn4.c = hn;                                                 \
        dot += hn * wv.c;                                           \
    }
    GRU_COMP(x) GRU_COMP(y) GRU_COMP(z) GRU_COMP(w)
#undef GRU_COMP

    *(float4*)(hp + s) = hn4;
    ushort4 hb4;
    hb4.x = (u16)bh(hn4.x); hb4.y = (u16)bh(hn4.y);
    hb4.z = (u16)bh(hn4.z); hb4.w = (u16)bh(hn4.w);
    *(ushort4*)(hpb + s) = hb4;

    for (int off = 32; off > 0; off >>= 1) dot += __shfl_down(dot, off);
    __shared__ float red[4];
    if ((threadIdx.x & 63) == 0) red[threadIdx.x >> 6] = dot;
    __syncthreads();
    if (threadIdx.x == 0) {
        float tot = red[0] + red[1] + red[2] + red[3] + ba[e];
        gs[((bt * 12 + n) * 12 + m) * EQ + e] = sigmoidf(tot);
    }
}

// ---------------- merged[bt,n,s] = sum_{m,e} gs[bt,n,m,e]*msgs_b[bt,m,e,s] ----------------
__global__ __launch_bounds__(256)
void merged_k(const float* __restrict__ gs, const u16* __restrict__ msgs_b,
              float* __restrict__ merged)
{
    const int bn = blockIdx.x;   // bt*12+n, 0..95
    const int bt = bn / 12;
    __shared__ float g[84];
    if (threadIdx.x < 84) g[threadIdx.x] = gs[bn * 84 + threadIdx.x];
    __syncthreads();
    const int s = threadIdx.x * 4;
    float4 acc = make_float4(0.f, 0.f, 0.f, 0.f);
    for (int j = 0; j < 84; ++j) {
        const uint2 mv = *(const uint2*)(msgs_b + ((long)(bt * 84 + j)) * SQ + s);
        float gj = g[j];
        acc.x += gj * __uint_as_float(mv.x << 16);
        acc.y += gj * __uint_as_float(mv.x & 0xffff0000u);
        acc.z += gj * __uint_as_float(mv.y << 16);
        acc.w += gj * __uint_as_float(mv.y & 0xffff0000u);
    }
    *(float4*)(merged + (long)bn * SQ + s) = acc;
}

// ---------------- small elementwise helpers ----------------
__global__ void amat_k(const float* __restrict__ merged, const float* __restrict__ prop,
                       u16* __restrict__ amat_b)
{
    int i = blockIdx.x * 256 + threadIdx.x;   // 0..98303
    int rrow = i >> 10, c = i & 1023;
    amat_b[(long)rrow * 2048 + c] = (u16)bh(merged[i]);
    amat_b[(long)rrow * 2048 + 1024 + c] = (u16)bh(prop[i]);
}

__global__ void ahat_k(const float* __restrict__ rbuf, const float* __restrict__ prop,
                       u16* __restrict__ amat_b)
{
    int i = blockIdx.x * 256 + threadIdx.x;
    int rrow = i >> 10, c = i & 1023;
    amat_b[(long)rrow * 2048 + 1024 + c] = (u16)bh(rbuf[i] * prop[i]);
}

__global__ void propupd_k(const float* __restrict__ zbuf, const float* __restrict__ hhat,
                          float* __restrict__ prop, u16* __restrict__ prop_b)
{
    int i = blockIdx.x * 256 + threadIdx.x;
    float z = zbuf[i];
    float v = (1.f - z) * prop[i] + z * hhat[i];
    prop[i] = v;
    prop_b[i] = (u16)bh(v);
}

__global__ void prop_reduce(const float* __restrict__ ptmp, const float* __restrict__ bc,
                            float* __restrict__ prop, u16* __restrict__ prop_b)
{
    int i = blockIdx.x * 256 + threadIdx.x;   // 0..98303
    float s = 0.f;
    for (int z = 0; z < 25; ++z) s += ptmp[(long)z * 98304 + i];
    float v = s + bc[i & 1023];
    prop[i] = v;
    prop_b[i] = (u16)bh(v);
}

// ---------------- final outputs ----------------
__global__ __launch_bounds__(256)
void outputs_k(const float* __restrict__ gs, float* __restrict__ out)
{
    __shared__ float s_act[672];
    __shared__ float s_asum[96];
    int tid = threadIdx.x;
    for (int idx = tid; idx < 672; idx += 256) {
        int bn = idx / 7, e = idx % 7;
        float sum = 0.f;
        for (int m = 0; m < 12; ++m) {
            float g0 = gs[bn * 84 + m * 7];
            sum += (1.f - g0) * gs[bn * 84 + m * 7 + e];
        }
        s_act[idx] = sum;
        out[idx] = sum;                       // action_score (B,T,N,E)
    }
    for (int idx = tid; idx < 96; idx += 256) {
        float a = 0.f;
        for (int m = 0; m < 12; ++m) a += 1.f - gs[idx * 84 + m * 7];
        s_asum[idx] = a;
    }
    for (int idx = tid; idx < 1152; idx += 256) {
        int bn = idx / 12, m = idx % 12;
        out[720 + idx] = 1.f - gs[bn * 84 + m * 7];   // actor_score (B,T,N,N)
    }
    __syncthreads();
    if (tid < 8) {   // bt
        float tmp[6];
        float mx = -1e30f;
        for (int e = 1; e < 7; ++e) {
            float sum = 0.f;
            for (int n = 0; n < 12; ++n) {
                int bn = tid * 12 + n;
                sum += s_act[bn * 7 + e] * s_asum[bn];
            }
            tmp[e - 1] = sum;
            mx = fmaxf(mx, sum);
        }
        float den = 0.f;
        for (int e = 0; e < 6; ++e) { tmp[e] = expf(tmp[e] - mx); den += tmp[e]; }
        for (int e = 0; e < 6; ++e) out[672 + tid * 6 + e] = tmp[e] / den;  // acty (B,T,6)
    }
}

// ---------------- host ----------------
template<int AS32, int BS32>
static void launch_gemm(const void* A, long sAb, int lda,
                        const void* B, long sBb, int ldb,
                        const float* bias, long sBiasb,
                        float* C, long sCb, int ldc,
                        u16* Cb, long sCbb, int ldcb,
                        int M, int Nn, int K, int act, int batch, hipStream_t stream)
{
    dim3 grid((M + 127) / 128, (Nn + 127) / 128, batch);
    gemm_mfma<AS32, BS32><<<grid, dim3(256), 0, stream>>>(
        A, sAb, lda, B, sBb, ldb, bias, sBiasb, C, sCb, ldc, Cb, sCbb, ldcb, M, Nn, K, act);
}

extern "C" void kernel_launch(void* const* d_in, const int* in_sizes, int n_in,
                              void* d_out, int out_size, void* d_ws, size_t ws_size,
                              hipStream_t stream)
{
    const float* pose  = (const float*)d_in[0];
    const float* Wc    = (const float*)d_in[5];
    const float* bc    = (const float*)d_in[6];
    const float* We    = (const float*)d_in[7];
    const float* be    = (const float*)d_in[8];
    const float* Wcomp = (const float*)d_in[9];
    const float* bcomp = (const float*)d_in[10];
    const float* Wr    = (const float*)d_in[11];
    const float* br    = (const float*)d_in[12];
    const float* Wz    = (const float*)d_in[13];
    const float* bz    = (const float*)d_in[14];
    const float* Wh    = (const float*)d_in[15];
    const float* bh_   = (const float*)d_in[16];
    const float* Wih   = (const float*)d_in[17];
    const float* Whh   = (const float*)d_in[18];
    const float* bih   = (const float*)d_in[19];
    const float* bhh   = (const float*)d_in[20];
    const float* Wa    = (const float*)d_in[21];
    const float* ba    = (const float*)d_in[22];

    float* ws = (float*)d_ws;
    // fp32 region
    float* prop   = ws;                    // 98304
    float* Gn     = prop + 98304;          // 2064384
    float* Gm     = Gn + 2064384;          // 2064384
    float* cbias  = Gm + 2064384;          // 3072
    float* h      = cbias + 3072;          // 2064384
    float* gh     = h + 2064384;           // 6193152 (also ptmp: 25*98304 fits)
    float* gs     = gh + 6193152;          // 8064
    float* merged = gs + 8064;             // 98304
    float* rbuf   = merged + 98304;        // 98304
    float* zbuf   = rbuf + 98304;          // 98304
    float* hhat   = zbuf + 98304;          // 98304
    float* fend   = hhat + 98304;
    // bf16 region
    u16* Whh_b  = (u16*)fend;              // 3145728
    u16* Wih_b  = Whh_b + 3145728;         // 3145728
    u16* msgs_b = Wih_b + 3145728;         // 688128
    u16* Xn_b   = msgs_b + 688128;         // 688128
    u16* Xm_b   = Xn_b + 688128;           // 688128
    u16* h_b    = Xm_b + 688128;           // 2064384
    u16* prop_b = h_b + 2064384;           // 98304
    u16* amat_b = prop_b + 98304;          // 196608
    float* ptmp = gh;

    const float h0std = sqrtf(2.0f / (288.0f * 1024.0f + 1024.0f));

    // once per call: weight conversions + cbias
    hipLaunchKernelGGL(cvt_bf16_k, dim3(3072), dim3(256), 0, stream, Whh, Whh_b, 786432);
    hipLaunchKernelGGL(cvt_bf16_k, dim3(3072), dim3(256), 0, stream, Wih, Wih_b, 786432);
    hipLaunchKernelGGL(cbias_k, dim3(12), dim3(256), 0, stream, Wih, bih, bcomp, cbias);

    // prop = pose @ Wc^T + bc, split-K: 25 slices of 1056 (fp32 sources)
    launch_gemm<1, 1>(pose, 1056, DIN, Wc, 1056, DIN, nullptr, 0,
                      ptmp, 98304, 1024, nullptr, 0, 0, 96, 1024, 1056, 0, 25, stream);
    hipLaunchKernelGGL(prop_reduce, dim3(384), dim3(256), 0, stream, ptmp, bc, prop, prop_b);

    for (int t = 0; t <= TSQ; ++t) {
        // msgs_b[bt,n,e,s] = prop @ We[e]^T + be[e]   (bf16 out only)
        launch_gemm<0, 1>(prop_b, 0, SQ, We, (long)SQ * SQ, SQ, be, SQ,
                          nullptr, 0, 0, msgs_b, SQ, EQ * SQ, 96, SQ, SQ, 0, EQ, stream);
        // Xn = rf @ Wc1^T ; Xm = rf @ Wc2^T (bf16 out)
        launch_gemm<0, 1>(msgs_b, SQ, EQ * SQ, Wcomp, 0, 2 * SQ, nullptr, 0,
                          nullptr, 0, 0, Xn_b, 98304, SQ, 96, SQ, SQ, 0, EQ, stream);
        launch_gemm<0, 1>(msgs_b, SQ, EQ * SQ, Wcomp + SQ, 0, 2 * SQ, nullptr, 0,
                          nullptr, 0, 0, Xm_b, 98304, SQ, 96, SQ, SQ, 0, EQ, stream);
        // Gn = Xn @ Wih^T ; Gm = Xm @ Wih^T (fp32 out)
        launch_gemm<0, 0>(Xn_b, 0, SQ, Wih_b, 0, SQ, nullptr, 0,
                          Gn, 0, G3S, nullptr, 0, 0, 672, G3S, SQ, 0, 1, stream);
        launch_gemm<0, 0>(Xm_b, 0, SQ, Wih_b, 0, SQ, nullptr, 0,
                          Gm, 0, G3S, nullptr, 0, 0, 672, G3S, SQ, 0, 1, stream);
        // h0
        hipLaunchKernelGGL(h0_fill, dim3(576, EQ), dim3(256), 0, stream, h, h_b, t, h0std);
        // GRU scan
        for (int tt = 0; tt < TQ; ++tt) {
            launch_gemm<0, 0>(h_b, 0, SQ, Whh_b, 0, SQ, bhh, 0,
                              gh, 0, G3S, nullptr, 0, 0, NROWS, G3S, SQ, 0, 1, stream);
            hipLaunchKernelGGL(gru_step, dim3(NROWS), dim3(256), 0, stream,
                               Gn, Gm, cbias, gh, h, h_b, Wa, ba, gs, tt);
        }
        if (t < TSQ) {
            hipLaunchKernelGGL(merged_k, dim3(96), dim3(256), 0, stream, gs, msgs_b, merged);
            hipLaunchKernelGGL(amat_k, dim3(384), dim3(256), 0, stream, merged, prop, amat_b);
            launch_gemm<0, 1>(amat_b, 0, 2 * SQ, Wr, 0, 2 * SQ, br, 0,
                              rbuf, 0, SQ, nullptr, 0, 0, 96, SQ, 2 * SQ, 1, 1, stream);
            launch_gemm<0, 1>(amat_b, 0, 2 * SQ, Wz, 0, 2 * SQ, bz, 0,
                              zbuf, 0, SQ, nullptr, 0, 0, 96, SQ, 2 * SQ, 1, 1, stream);
            hipLaunchKernelGGL(ahat_k, dim3(384), dim3(256), 0, stream, rbuf, prop, amat_b);
            launch_gemm<0, 1>(amat_b, 0, 2 * SQ, Wh, 0, 2 * SQ, bh_, 0,
                              hhat, 0, SQ, nullptr, 0, 0, 96, SQ, 2 * SQ, 2, 1, stream);
            hipLaunchKernelGGL(propupd_k, dim3(384), dim3(256), 0, stream, zbuf, hhat, prop, prop_b);
        }
    }

    hipLaunchKernelGGL(outputs_k, dim3(1), dim3(256), 0, stream, gs, (float*)d_out);
}

// Round 3
// 1642.607 us; speedup vs baseline: 3.6577x; 1.7838x over previous
//
#include <hip/hip_runtime.h>
#include <math.h>

// Problem constants
#define NQ 12
#define EQ 7
#define SQ 1024
#define TSQ 3
#define DIN 26400
#define BQ 2
#define TQ 4
#define BT 8          // B*T
#define BNN 288       // B*N*N
#define NROWS 2016    // E*BNN
#define G3S 3072      // 3*S
#define BK 32

typedef unsigned short u16;
typedef float f32x4 __attribute__((ext_vector_type(4)));
typedef short s16x8 __attribute__((ext_vector_type(8)));

__device__ __forceinline__ short bh(float f) {
    unsigned u = __float_as_uint(f);
    return (short)((u + 0x8000u) >> 16);
}
__device__ __forceinline__ float b2f(u16 u) {
    return __uint_as_float((unsigned)u << 16);
}
__device__ __forceinline__ s16x8 pack8(float4 a, float4 b) {
    s16x8 r;
    r[0] = bh(a.x); r[1] = bh(a.y); r[2] = bh(a.z); r[3] = bh(a.w);
    r[4] = bh(b.x); r[5] = bh(b.y); r[6] = bh(b.z); r[7] = bh(b.w);
    return r;
}
__device__ __forceinline__ void gload16(const void* g, void* l) {
    __builtin_amdgcn_global_load_lds(
        (const __attribute__((address_space(1))) unsigned*)g,
        (__attribute__((address_space(3))) unsigned*)l, 16, 0, 0);
}
__device__ inline float sigmoidf(float x) { return 1.f / (1.f + expf(-x)); }

// ================= bf16 MFMA GEMM, 64x128 tile: C = A(MxK) * B(NxK)^T =================
// blockIdx.z packs (batch, ks): az = z/ksplit, ks = z%ksplit.
// A/B batch offset uses az; C offset uses z (so split-K partials land per-slice).
template<int AS32, int BS32>
__global__ __launch_bounds__(256)
void gemm_mfma(const void* __restrict__ Ap, long sAb, int lda,
               const void* __restrict__ Bp, long sBb, int ldb,
               const float* __restrict__ bias, long sBiasb,
               float* __restrict__ C, long sCb, int ldc,
               u16* __restrict__ Cb, long sCbb, int ldcb,
               int M, int Nn, int K, int act, int ksplit)
{
    __shared__ __align__(16) u16 lA[2][256][8];   // [kg0..3][row0..63]
    __shared__ __align__(16) u16 lB[2][512][8];   // [kg0..3][row0..127]

    const int z = blockIdx.z;
    const int az = z / ksplit;
    const int ks = z - az * ksplit;
    const int Ksl = K / ksplit;
    const int kbase = ks * Ksl;

    const char* Abase = (const char*)Ap + (long)az * sAb * (AS32 ? 4 : 2);
    const char* Bbase = (const char*)Bp + (long)az * sBb * (BS32 ? 4 : 2);

    const int tid = threadIdx.x;
    const int lane = tid & 63;
    const int wave = tid >> 6;
    const int row0 = blockIdx.x * 64;
    const int col0 = blockIdx.y * 128;
    const int wcol = wave * 32;

    // A staging: slot = tid, kg = tid>>6, row = tid&63
    const int akg = tid >> 6, ar_ = tid & 63;
    long arow = row0 + ar_; if (arow >= M) arow = M - 1;
    // B staging: slots tid, tid+256: kg = s>>7, row = s&127
    const int bkg0 = tid >> 7, br_0 = tid & 127;
    const int s1 = tid + 256;
    const int bkg1 = s1 >> 7, br_1 = s1 & 127;
    long brow0 = col0 + br_0; if (brow0 >= Nn) brow0 = Nn - 1;
    long brow1 = col0 + br_1; if (brow1 >= Nn) brow1 = Nn - 1;

    f32x4 acc[4][2] = {};

#define STAGE(b, kt) do {                                                     \
    const int k0_ = kbase + (kt) * BK;                                        \
    if constexpr (AS32) {                                                     \
        const float* A32 = (const float*)Abase;                               \
        const float* p0 = A32 + arow * lda + k0_ + akg * 8;                   \
        float4 x0 = *(const float4*)p0, x1 = *(const float4*)(p0 + 4);        \
        *(s16x8*)&lA[b][tid][0] = pack8(x0, x1);                              \
    } else {                                                                  \
        const u16* A16 = (const u16*)Abase;                                   \
        gload16(A16 + arow * lda + k0_ + akg * 8, &lA[b][tid][0]);            \
    }                                                                         \
    if constexpr (BS32) {                                                     \
        const float* B32 = (const float*)Bbase;                               \
        const float* q0 = B32 + brow0 * ldb + k0_ + bkg0 * 8;                 \
        const float* q1 = B32 + brow1 * ldb + k0_ + bkg1 * 8;                 \
        float4 x0 = *(const float4*)q0, x1 = *(const float4*)(q0 + 4);        \
        float4 y0 = *(const float4*)q1, y1 = *(const float4*)(q1 + 4);        \
        *(s16x8*)&lB[b][tid][0] = pack8(x0, x1);                              \
        *(s16x8*)&lB[b][s1][0] = pack8(y0, y1);                               \
    } else {                                                                  \
        const u16* B16 = (const u16*)Bbase;                                   \
        gload16(B16 + brow0 * ldb + k0_ + bkg0 * 8, &lB[b][tid][0]);          \
        gload16(B16 + brow1 * ldb + k0_ + bkg1 * 8, &lB[b][s1][0]);           \
    }                                                                         \
} while (0)

    const int nk = Ksl / BK;
    STAGE(0, 0);
    __syncthreads();
    int buf = 0;
    const int kg = lane >> 4;
    const int lr = lane & 15;
    for (int kt = 0; kt < nk; ++kt) {
        if (kt + 1 < nk) STAGE(buf ^ 1, kt + 1);
        s16x8 af[4], bfr[2];
#pragma unroll
        for (int m = 0; m < 4; ++m)
            af[m] = *(const s16x8*)&lA[buf][kg * 64 + m * 16 + lr][0];
#pragma unroll
        for (int n = 0; n < 2; ++n)
            bfr[n] = *(const s16x8*)&lB[buf][kg * 128 + wcol + n * 16 + lr][0];
#pragma unroll
        for (int m = 0; m < 4; ++m)
#pragma unroll
            for (int n = 0; n < 2; ++n)
                acc[m][n] = __builtin_amdgcn_mfma_f32_16x16x32_bf16(af[m], bfr[n], acc[m][n], 0, 0, 0);
        __syncthreads();
        buf ^= 1;
    }
#undef STAGE

    // C/D layout: col = lane&15, row = (lane>>4)*4 + reg
    const int ccol = lane & 15;
    const int crow = (lane >> 4) * 4;
#pragma unroll
    for (int n = 0; n < 2; ++n) {
        const int c = col0 + wcol + n * 16 + ccol;
        const float bv = bias ? bias[(long)az * sBiasb + c] : 0.f;
#pragma unroll
        for (int m = 0; m < 4; ++m) {
            const int rb = row0 + m * 16 + crow;
#pragma unroll
            for (int q = 0; q < 4; ++q) {
                const int r = rb + q;
                if (r >= M) continue;
                float v = acc[m][n][q] + bv;
                if (act == 1) v = 1.f / (1.f + expf(-v));
                else if (act == 2) v = tanhf(v);
                if (C)  C[(long)z * sCb + (long)r * ldc + c] = v;
                if (Cb) Cb[(long)z * sCbb + (long)r * ldcb + c] = (u16)bh(v);
            }
        }
    }
}

// ---------- generic split-K reduce: bias + activation + f32/bf16 write ----------
__global__ __launch_bounds__(256)
void reduce_k(const float* __restrict__ part, int ksplit, int mn, int Nn,
              const float* __restrict__ bias, long sBiasB, int act,
              float* __restrict__ Cf, long sCfB, int ldcf,
              u16* __restrict__ Cb, long sCbB, int ldcb)
{
    int i4 = blockIdx.x * 256 + threadIdx.x;
    int total4 = mn >> 2;
    if (i4 >= total4) return;
    int b = blockIdx.y;
    const float4* p4 = (const float4*)part;
    float4 s = make_float4(0.f, 0.f, 0.f, 0.f);
    for (int ks = 0; ks < ksplit; ++ks) {
        float4 v = p4[(long)(b * ksplit + ks) * total4 + i4];
        s.x += v.x; s.y += v.y; s.z += v.z; s.w += v.w;
    }
    int i = i4 << 2;
    int r = i / Nn, c = i % Nn;
    if (bias) {
        float4 bv = *(const float4*)(bias + (long)b * sBiasB + c);
        s.x += bv.x; s.y += bv.y; s.z += bv.z; s.w += bv.w;
    }
    if (act == 1) {
        s.x = sigmoidf(s.x); s.y = sigmoidf(s.y); s.z = sigmoidf(s.z); s.w = sigmoidf(s.w);
    } else if (act == 2) {
        s.x = tanhf(s.x); s.y = tanhf(s.y); s.z = tanhf(s.z); s.w = tanhf(s.w);
    }
    if (Cf) *(float4*)(Cf + (long)b * sCfB + (long)r * ldcf + c) = s;
    if (Cb) {
        ushort4 o;
        o.x = (u16)bh(s.x); o.y = (u16)bh(s.y); o.z = (u16)bh(s.z); o.w = (u16)bh(s.w);
        *(ushort4*)(Cb + (long)b * sCbB + (long)r * ldcb + c) = o;
    }
}

// ---------------- fp32 -> bf16 bulk convert ----------------
__global__ void cvt_bf16_k(const float* __restrict__ src, u16* __restrict__ dst, int n4)
{
    int i = blockIdx.x * 256 + threadIdx.x;
    if (i >= n4) return;
    float4 v = ((const float4*)src)[i];
    ushort4 o;
    o.x = (u16)bh(v.x); o.y = (u16)bh(v.y); o.z = (u16)bh(v.z); o.w = (u16)bh(v.w);
    ((ushort4*)dst)[i] = o;
}

// ---------------- Wcomp transpose: W1T[s][d]=Wcomp[d][s], W2T[s][d]=Wcomp[d][1024+s] ----------------
__global__ __launch_bounds__(256)
void transpose_wc(const float* __restrict__ Wcomp, float* __restrict__ W1T, float* __restrict__ W2T)
{
    __shared__ float t1[32][33];
    __shared__ float t2[32][33];
    const int tx = threadIdx.x & 31;
    const int ty = threadIdx.x >> 5;     // 0..7
    const int d0 = blockIdx.x * 32;
    const int s0 = blockIdx.y * 32;
#pragma unroll
    for (int k = 0; k < 4; ++k) {
        int d = d0 + ty + k * 8;
        t1[ty + k * 8][tx] = Wcomp[(long)d * 2048 + s0 + tx];
        t2[ty + k * 8][tx] = Wcomp[(long)d * 2048 + 1024 + s0 + tx];
    }
    __syncthreads();
#pragma unroll
    for (int k = 0; k < 4; ++k) {
        int s = s0 + ty + k * 8;
        W1T[(long)s * 1024 + d0 + tx] = t1[tx][ty + k * 8];
        W2T[(long)s * 1024 + d0 + tx] = t2[tx][ty + k * 8];
    }
}

// ---------------- pack [Wr;Wz] -> bf16, [br;bz] -> fp32 ----------------
__global__ void pack_rz(const float* __restrict__ Wr, const float* __restrict__ Wz,
                        const float* __restrict__ br, const float* __restrict__ bz,
                        u16* __restrict__ Wrz, float* __restrict__ brz)
{
    int i4 = blockIdx.x * 256 + threadIdx.x;   // over 2*1024*2048/4
    if (i4 < 512) {
        int c = i4 * 4;
        float4 b = (c < 1024) ? *(const float4*)(br + c) : *(const float4*)(bz + c - 1024);
        *(float4*)(brz + c) = b;
    }
    if (i4 >= 1048576) return;
    int i = i4 * 4;
    int j = i >> 11;          // row 0..2047
    int c = i & 2047;
    float4 v = (j < 1024) ? *(const float4*)(Wr + (long)j * 2048 + c)
                          : *(const float4*)(Wz + (long)(j - 1024) * 2048 + c);
    ushort4 o;
    o.x = (u16)bh(v.x); o.y = (u16)bh(v.y); o.z = (u16)bh(v.z); o.w = (u16)bh(v.w);
    *(ushort4*)(Wrz + i) = o;
}

// ---------------- threefry2x32 (JAX-compatible) ----------------
__device__ inline unsigned rotl32(unsigned v, int r) { return (v << r) | (v >> (32 - r)); }

__device__ inline void tf2x32(unsigned k0, unsigned k1, unsigned x0, unsigned x1,
                              unsigned& o0, unsigned& o1)
{
    unsigned ks2 = k0 ^ k1 ^ 0x1BD11BDAu;
    x0 += k0; x1 += k1;
    x0 += x1; x1 = rotl32(x1, 13); x1 ^= x0;
    x0 += x1; x1 = rotl32(x1, 15); x1 ^= x0;
    x0 += x1; x1 = rotl32(x1, 26); x1 ^= x0;
    x0 += x1; x1 = rotl32(x1,  6); x1 ^= x0;
    x0 += k1; x1 += ks2 + 1u;
    x0 += x1; x1 = rotl32(x1, 17); x1 ^= x0;
    x0 += x1; x1 = rotl32(x1, 29); x1 ^= x0;
    x0 += x1; x1 = rotl32(x1, 16); x1 ^= x0;
    x0 += x1; x1 = rotl32(x1, 24); x1 ^= x0;
    x0 += ks2; x1 += k0 + 2u;
    x0 += x1; x1 = rotl32(x1, 13); x1 ^= x0;
    x0 += x1; x1 = rotl32(x1, 15); x1 ^= x0;
    x0 += x1; x1 = rotl32(x1, 26); x1 ^= x0;
    x0 += x1; x1 = rotl32(x1,  6); x1 ^= x0;
    x0 += k0; x1 += k1 + 3u;
    x0 += x1; x1 = rotl32(x1, 17); x1 ^= x0;
    x0 += x1; x1 = rotl32(x1, 29); x1 ^= x0;
    x0 += x1; x1 = rotl32(x1, 16); x1 ^= x0;
    x0 += x1; x1 = rotl32(x1, 24); x1 ^= x0;
    x0 += k1; x1 += ks2 + 4u;
    x0 += x1; x1 = rotl32(x1, 13); x1 ^= x0;
    x0 += x1; x1 = rotl32(x1, 15); x1 ^= x0;
    x0 += x1; x1 = rotl32(x1, 26); x1 ^= x0;
    x0 += x1; x1 = rotl32(x1,  6); x1 ^= x0;
    x0 += ks2; x1 += k0 + 5u;
    o0 = x0; o1 = x1;
}

__device__ inline float bits_to_normal(unsigned bits)
{
    float f = __uint_as_float((bits >> 9) | 0x3f800000u) - 1.0f;
    const float lo = -0.99999994f;
    float u = f * (1.0f - lo) + lo;
    u = fmaxf(u, lo);
    return 1.41421356237f * erfinvf(u);
}

#define HALF_E 147456   // (BNN*S)/2

__global__ void h0_fill(float* __restrict__ h, u16* __restrict__ hb, int t, float h0std)
{
    int i = blockIdx.x * blockDim.x + threadIdx.x;  // 0..147455
    int e = blockIdx.y;
    unsigned k0, k1, o0, o1;
    tf2x32(0u, 42u, 0u, (unsigned)(t * EQ + e), k0, k1);
    tf2x32(k0, k1, (unsigned)i, (unsigned)(i + HALF_E), o0, o1);
    float* he = h + (long)e * (BNN * SQ);
    u16* heb = hb + (long)e * (BNN * SQ);
    float v0 = bits_to_normal(o0) * h0std;
    float v1 = bits_to_normal(o1) * h0std;
    he[i] = v0;            heb[i] = (u16)bh(v0);
    he[i + HALF_E] = v1;   heb[i + HALF_E] = (u16)bh(v1);
}

// ---------------- cbias[g] = bih[g] + sum_s bcomp[s]*Wih[g,s] ----------------
__global__ void cbias_k(const float* __restrict__ Wih, const float* __restrict__ bih,
                        const float* __restrict__ bcomp, float* __restrict__ cbias)
{
    int g = blockIdx.x * blockDim.x + threadIdx.x;
    if (g >= G3S) return;
    const float* w = Wih + (long)g * SQ;
    float s = 0.f;
    for (int k = 0; k < SQ; k += 4) {
        float4 wv = *(const float4*)(w + k);
        float4 bv = *(const float4*)(bcomp + k);
        s += wv.x * bv.x + wv.y * bv.y + wv.z * bv.z + wv.w * bv.w;
    }
    cbias[g] = s + bih[g];
}

// ---------------- fused GRU gate + state update + score ----------------
__global__ __launch_bounds__(256)
void gru_step(const float* __restrict__ Gn, const float* __restrict__ Gm,
              const float* __restrict__ cb, const u16* __restrict__ gh_b,
              float* __restrict__ h, u16* __restrict__ hb,
              const float* __restrict__ Wa,
              const float* __restrict__ ba, float* __restrict__ gs, int tt)
{
    const int row = blockIdx.x;            // 0..2015 : e*288 + b*144 + n*12 + m
    const int e = row / BNN;
    const int r = row % BNN;
    const int b = r / 144;
    const int n = (r / 12) % 12;
    const int m = r % 12;
    const int bt = b * TQ + tt;

    const float* gn = Gn + ((long)(e * 96 + bt * 12 + n)) * G3S;
    const float* gm = Gm + ((long)(e * 96 + bt * 12 + m)) * G3S;
    const u16* gq = gh_b + (long)row * G3S;
    float* hp = h + (long)row * SQ;
    u16* hpb = hb + (long)row * SQ;

    const int s = threadIdx.x * 4;

    float4 gnR = *(const float4*)(gn + s);
    float4 gnZ = *(const float4*)(gn + SQ + s);
    float4 gnN = *(const float4*)(gn + 2 * SQ + s);
    float4 gmR = *(const float4*)(gm + s);
    float4 gmZ = *(const float4*)(gm + SQ + s);
    float4 gmN = *(const float4*)(gm + 2 * SQ + s);
    float4 cbR = *(const float4*)(cb + s);
    float4 cbZ = *(const float4*)(cb + SQ + s);
    float4 cbN = *(const float4*)(cb + 2 * SQ + s);
    ushort4 uR = *(const ushort4*)(gq + s);
    ushort4 uZ = *(const ushort4*)(gq + SQ + s);
    ushort4 uN = *(const ushort4*)(gq + 2 * SQ + s);
    float4 ghR = make_float4(b2f(uR.x), b2f(uR.y), b2f(uR.z), b2f(uR.w));
    float4 ghZ = make_float4(b2f(uZ.x), b2f(uZ.y), b2f(uZ.z), b2f(uZ.w));
    float4 ghN = make_float4(b2f(uN.x), b2f(uN.y), b2f(uN.z), b2f(uN.w));
    float4 hv  = *(const float4*)(hp + s);
    float4 wv  = *(const float4*)(Wa + (long)e * SQ + s);

    float4 hn4;
    float dot = 0.f;

#define GRU_COMP(c)                                                 \
    {                                                               \
        float gr = gnR.c + gmR.c + cbR.c + ghR.c;                   \
        float gz = gnZ.c + gmZ.c + cbZ.c + ghZ.c;                   \
        float gi = gnN.c + gmN.c + cbN.c;                           \
        float rg = sigmoidf(gr);                                    \
        float zg = sigmoidf(gz);                                    \
        float nn = tanhf(gi + rg * ghN.c);                          \
        float hn = (1.f - zg) * nn + zg * hv.c;                     \
        hn4.c = hn;                                                 \
        dot += hn * wv.c;                                           \
    }
    GRU_COMP(x) GRU_COMP(y) GRU_COMP(z) GRU_COMP(w)
#undef GRU_COMP

    *(float4*)(hp + s) = hn4;
    ushort4 hb4;
    hb4.x = (u16)bh(hn4.x); hb4.y = (u16)bh(hn4.y);
    hb4.z = (u16)bh(hn4.z); hb4.w = (u16)bh(hn4.w);
    *(ushort4*)(hpb + s) = hb4;

    for (int off = 32; off > 0; off >>= 1) dot += __shfl_down(dot, off);
    __shared__ float red[4];
    if ((threadIdx.x & 63) == 0) red[threadIdx.x >> 6] = dot;
    __syncthreads();
    if (threadIdx.x == 0) {
        float tot = red[0] + red[1] + red[2] + red[3] + ba[e];
        gs[((bt * 12 + n) * 12 + m) * EQ + e] = sigmoidf(tot);
    }
}

// ---------------- merged[bt,n,s] = sum_{m,e} gs[bt,n,m,e]*msgs_b[bt,m,e,s] ----------------
__global__ __launch_bounds__(256)
void merged_k(const float* __restrict__ gs, const u16* __restrict__ msgs_b,
              float* __restrict__ merged)
{
    const int bn = blockIdx.x;   // bt*12+n, 0..95
    const int bt = bn / 12;
    __shared__ float g[84];
    if (threadIdx.x < 84) g[threadIdx.x] = gs[bn * 84 + threadIdx.x];
    __syncthreads();
    const int s = threadIdx.x * 4;
    float4 acc = make_float4(0.f, 0.f, 0.f, 0.f);
    for (int j = 0; j < 84; ++j) {
        const ushort4 mv = *(const ushort4*)(msgs_b + ((long)(bt * 84 + j)) * SQ + s);
        float gj = g[j];
        acc.x += gj * b2f(mv.x);
        acc.y += gj * b2f(mv.y);
        acc.z += gj * b2f(mv.z);
        acc.w += gj * b2f(mv.w);
    }
    *(float4*)(merged + (long)bn * SQ + s) = acc;
}

// ---------------- small elementwise helpers ----------------
__global__ void amat_k(const float* __restrict__ merged, const float* __restrict__ prop,
                       u16* __restrict__ amat_b)
{
    int i = blockIdx.x * 256 + threadIdx.x;   // 0..98303
    int rrow = i >> 10, c = i & 1023;
    amat_b[(long)rrow * 2048 + c] = (u16)bh(merged[i]);
    amat_b[(long)rrow * 2048 + 1024 + c] = (u16)bh(prop[i]);
}

__global__ void ahat_k(const float* __restrict__ rz, const float* __restrict__ prop,
                       u16* __restrict__ amat_b)
{
    int i = blockIdx.x * 256 + threadIdx.x;
    int rrow = i >> 10, c = i & 1023;
    float r = rz[(long)rrow * 2048 + c];
    amat_b[(long)rrow * 2048 + 1024 + c] = (u16)bh(r * prop[i]);
}

__global__ void propupd_k(const float* __restrict__ rz, const float* __restrict__ hhat,
                          float* __restrict__ prop, u16* __restrict__ prop_b)
{
    int i = blockIdx.x * 256 + threadIdx.x;
    int rrow = i >> 10, c = i & 1023;
    float z = rz[(long)rrow * 2048 + 1024 + c];
    float v = (1.f - z) * prop[i] + z * hhat[i];
    prop[i] = v;
    prop_b[i] = (u16)bh(v);
}

// ---------------- final outputs ----------------
__global__ __launch_bounds__(256)
void outputs_k(const float* __restrict__ gs, float* __restrict__ out)
{
    __shared__ float s_act[672];
    __shared__ float s_asum[96];
    int tid = threadIdx.x;
    for (int idx = tid; idx < 672; idx += 256) {
        int bn = idx / 7, e = idx % 7;
        float sum = 0.f;
        for (int m = 0; m < 12; ++m) {
            float g0 = gs[bn * 84 + m * 7];
            sum += (1.f - g0) * gs[bn * 84 + m * 7 + e];
        }
        s_act[idx] = sum;
        out[idx] = sum;                       // action_score (B,T,N,E)
    }
    for (int idx = tid; idx < 96; idx += 256) {
        float a = 0.f;
        for (int m = 0; m < 12; ++m) a += 1.f - gs[idx * 84 + m * 7];
        s_asum[idx] = a;
    }
    for (int idx = tid; idx < 1152; idx += 256) {
        int bn = idx / 12, m = idx % 12;
        out[720 + idx] = 1.f - gs[bn * 84 + m * 7];   // actor_score (B,T,N,N)
    }
    __syncthreads();
    if (tid < 8) {   // bt
        float tmp[6];
        float mx = -1e30f;
        for (int e = 1; e < 7; ++e) {
            float sum = 0.f;
            for (int n = 0; n < 12; ++n) {
                int bn = tid * 12 + n;
                sum += s_act[bn * 7 + e] * s_asum[bn];
            }
            tmp[e - 1] = sum;
            mx = fmaxf(mx, sum);
        }
        float den = 0.f;
        for (int e = 0; e < 6; ++e) { tmp[e] = expf(tmp[e] - mx); den += tmp[e]; }
        for (int e = 0; e < 6; ++e) out[672 + tid * 6 + e] = tmp[e] / den;  // acty (B,T,6)
    }
}

// ---------------- host ----------------
template<int AS32, int BS32>
static void launch_gemm(const void* A, long sAb, int lda,
                        const void* B, long sBb, int ldb,
                        const float* bias, long sBiasb,
                        float* C, long sCb, int ldc,
                        u16* Cb, long sCbb, int ldcb,
                        int M, int Nn, int K, int act, int batch, int ksplit,
                        hipStream_t stream)
{
    dim3 grid((M + 63) / 64, (Nn + 127) / 128, batch * ksplit);
    gemm_mfma<AS32, BS32><<<grid, dim3(256), 0, stream>>>(
        A, sAb, lda, B, sBb, ldb, bias, sBiasb, C, sCb, ldc, Cb, sCbb, ldcb,
        M, Nn, K, act, ksplit);
}

extern "C" void kernel_launch(void* const* d_in, const int* in_sizes, int n_in,
                              void* d_out, int out_size, void* d_ws, size_t ws_size,
                              hipStream_t stream)
{
    const float* pose  = (const float*)d_in[0];
    const float* Wc    = (const float*)d_in[5];
    const float* bc    = (const float*)d_in[6];
    const float* We    = (const float*)d_in[7];
    const float* be    = (const float*)d_in[8];
    const float* Wcomp = (const float*)d_in[9];
    const float* bcomp = (const float*)d_in[10];
    const float* Wr    = (const float*)d_in[11];
    const float* br    = (const float*)d_in[12];
    const float* Wz    = (const float*)d_in[13];
    const float* bz    = (const float*)d_in[14];
    const float* Wh    = (const float*)d_in[15];
    const float* bh_   = (const float*)d_in[16];
    const float* Wih   = (const float*)d_in[17];
    const float* Whh   = (const float*)d_in[18];
    const float* bih   = (const float*)d_in[19];
    const float* bhh   = (const float*)d_in[20];
    const float* Wa    = (const float*)d_in[21];
    const float* ba    = (const float*)d_in[22];

    float* ws = (float*)d_ws;
    // fp32 region
    float* prop    = ws;                    // 98304
    float* Gn      = prop + 98304;          // 2064384
    float* Gm      = Gn + 2064384;          // 2064384
    float* cbias   = Gm + 2064384;          // 3072
    float* h       = cbias + 3072;          // 2064384
    float* scratch = h + 2064384;           // 4128768 (split-K partials / WcT)
    float* gs      = scratch + 4128768;     // 8064
    float* merged  = gs + 8064;             // 98304
    float* rz      = merged + 98304;        // 196608
    float* hhat    = rz + 196608;           // 98304
    float* brz     = hhat + 98304;          // 2048
    float* fend    = brz + 2048;
    // bf16 region
    u16* Whh_b  = (u16*)fend;               // 3145728
    u16* Wn_b   = Whh_b + 3145728;          // 3145728
    u16* Wm_b   = Wn_b + 3145728;           // 3145728
    u16* Wrz_b  = Wm_b + 3145728;           // 4194304
    u16* gh_b   = Wrz_b + 4194304;          // 6193152 (2016*3072)
    u16* msgs_b = gh_b + 6193152;           // 688128
    u16* h_b    = msgs_b + 688128;          // 2064384
    u16* prop_b = h_b + 2064384;            // 98304
    u16* amat_b = prop_b + 98304;           // 196608

    float* W1T = scratch;                   // 1048576 (transient)
    float* W2T = scratch + 1048576;         // 1048576 (transient)

    const float h0std = sqrtf(2.0f / (288.0f * 1024.0f + 1024.0f));

    // ---- once per call ----
    hipLaunchKernelGGL(cvt_bf16_k, dim3(3072), dim3(256), 0, stream, Whh, Whh_b, 786432);
    hipLaunchKernelGGL(cbias_k, dim3(12), dim3(256), 0, stream, Wih, bih, bcomp, cbias);
    hipLaunchKernelGGL(transpose_wc, dim3(32, 32), dim3(256), 0, stream, Wcomp, W1T, W2T);
    hipLaunchKernelGGL(pack_rz, dim3(4096), dim3(256), 0, stream, Wr, Wz, br, bz, Wrz_b, brz);
    // Wn = Wih @ W1T^T ; Wm = Wih @ W2T^T   (3072x1024, bf16 out)
    launch_gemm<1, 1>(Wih, 0, SQ, W1T, 0, SQ, nullptr, 0,
                      nullptr, 0, 0, Wn_b, 0, SQ, G3S, SQ, SQ, 0, 1, 1, stream);
    launch_gemm<1, 1>(Wih, 0, SQ, W2T, 0, SQ, nullptr, 0,
                      nullptr, 0, 0, Wm_b, 0, SQ, G3S, SQ, SQ, 0, 1, 1, stream);
    // prop = pose @ Wc^T + bc : ksplit=25 (K=26400)
    launch_gemm<1, 1>(pose, 0, DIN, Wc, 0, DIN, nullptr, 0,
                      scratch, 98304, SQ, nullptr, 0, 0, 96, SQ, DIN, 0, 1, 25, stream);
    hipLaunchKernelGGL(reduce_k, dim3(96, 1), dim3(256), 0, stream,
                       scratch, 25, 98304, SQ, bc, 0L, 0,
                       prop, 0L, SQ, prop_b, 0L, SQ);

    for (int t = 0; t <= TSQ; ++t) {
        // msgs[bt,n,e,s] = prop @ We[e]^T + be[e] : batch 7, ksplit 2
        launch_gemm<0, 1>(prop_b, 0, SQ, We, (long)SQ * SQ, SQ, nullptr, 0,
                          scratch, 98304, SQ, nullptr, 0, 0, 96, SQ, SQ, 0, EQ, 2, stream);
        hipLaunchKernelGGL(reduce_k, dim3(96, EQ), dim3(256), 0, stream,
                           scratch, 2, 98304, SQ, be, (long)SQ, 0,
                           (float*)nullptr, 0L, 0, msgs_b, (long)SQ, EQ * SQ);
        // Gn = msgs_e @ Wn^T : batch 7, ksplit 2
        launch_gemm<0, 0>(msgs_b, SQ, EQ * SQ, Wn_b, 0, SQ, nullptr, 0,
                          scratch, 294912, G3S, nullptr, 0, 0, 96, G3S, SQ, 0, EQ, 2, stream);
        hipLaunchKernelGGL(reduce_k, dim3(288, EQ), dim3(256), 0, stream,
                           scratch, 2, 294912, G3S, (const float*)nullptr, 0L, 0,
                           Gn, 294912L, G3S, (u16*)nullptr, 0L, 0);
        // Gm = msgs_e @ Wm^T
        launch_gemm<0, 0>(msgs_b, SQ, EQ * SQ, Wm_b, 0, SQ, nullptr, 0,
                          scratch, 294912, G3S, nullptr, 0, 0, 96, G3S, SQ, 0, EQ, 2, stream);
        hipLaunchKernelGGL(reduce_k, dim3(288, EQ), dim3(256), 0, stream,
                           scratch, 2, 294912, G3S, (const float*)nullptr, 0L, 0,
                           Gm, 294912L, G3S, (u16*)nullptr, 0L, 0);
        // h0
        hipLaunchKernelGGL(h0_fill, dim3(576, EQ), dim3(256), 0, stream, h, h_b, t, h0std);
        // GRU scan
        for (int tt = 0; tt < TQ; ++tt) {
            launch_gemm<0, 0>(h_b, 0, SQ, Whh_b, 0, SQ, bhh, 0,
                              nullptr, 0, 0, gh_b, 0, G3S, NROWS, G3S, SQ, 0, 1, 1, stream);
            hipLaunchKernelGGL(gru_step, dim3(NROWS), dim3(256), 0, stream,
                               Gn, Gm, cbias, gh_b, h, h_b, Wa, ba, gs, tt);
        }
        if (t < TSQ) {
            hipLaunchKernelGGL(merged_k, dim3(96), dim3(256), 0, stream, gs, msgs_b, merged);
            hipLaunchKernelGGL(amat_k, dim3(384), dim3(256), 0, stream, merged, prop, amat_b);
            // rz = sigmoid(amat @ [Wr;Wz]^T + brz) : N=2048, K=2048, ksplit=8
            launch_gemm<0, 0>(amat_b, 0, 2 * SQ, Wrz_b, 0, 2 * SQ, nullptr, 0,
                              scratch, 196608, 2 * SQ, nullptr, 0, 0, 96, 2 * SQ, 2 * SQ, 0, 1, 8, stream);
            hipLaunchKernelGGL(reduce_k, dim3(192, 1), dim3(256), 0, stream,
                               scratch, 8, 196608, 2 * SQ, brz, 0L, 1,
                               rz, 0L, 2 * SQ, (u16*)nullptr, 0L, 0);
            hipLaunchKernelGGL(ahat_k, dim3(384), dim3(256), 0, stream, rz, prop, amat_b);
            // hhat = tanh(amat @ Wh^T + bh) : ksplit=8
            launch_gemm<0, 1>(amat_b, 0, 2 * SQ, Wh, 0, 2 * SQ, nullptr, 0,
                              scratch, 98304, SQ, nullptr, 0, 0, 96, SQ, 2 * SQ, 0, 1, 8, stream);
            hipLaunchKernelGGL(reduce_k, dim3(96, 1), dim3(256), 0, stream,
                               scratch, 8, 98304, SQ, bh_, 0L, 2,
                               hhat, 0L, SQ, (u16*)nullptr, 0L, 0);
            hipLaunchKernelGGL(propupd_k, dim3(384), dim3(256), 0, stream, rz, hhat, prop, prop_b);
        }
    }

    hipLaunchKernelGGL(outputs_k, dim3(1), dim3(256), 0, stream, gs, (float*)d_out);
}

// Round 4
// 1497.369 us; speedup vs baseline: 4.0124x; 1.0970x over previous
//
#include <hip/hip_runtime.h>
#include <math.h>

// Problem constants
#define NQ 12
#define EQ 7
#define SQ 1024
#define TSQ 3
#define DIN 26400
#define BQ 2
#define TQ 4
#define BT 8          // B*T
#define BNN 288       // B*N*N
#define NROWS 2016    // E*BNN
#define G3S 3072      // 3*S
#define BK 32

typedef unsigned short u16;
typedef float f32x4 __attribute__((ext_vector_type(4)));
typedef short s16x8 __attribute__((ext_vector_type(8)));

__device__ __forceinline__ short bh(float f) {
    unsigned u = __float_as_uint(f);
    return (short)((u + 0x8000u) >> 16);
}
__device__ __forceinline__ float b2f(u16 u) {
    return __uint_as_float((unsigned)u << 16);
}
__device__ __forceinline__ s16x8 pack8(float4 a, float4 b) {
    s16x8 r;
    r[0] = bh(a.x); r[1] = bh(a.y); r[2] = bh(a.z); r[3] = bh(a.w);
    r[4] = bh(b.x); r[5] = bh(b.y); r[6] = bh(b.z); r[7] = bh(b.w);
    return r;
}
__device__ __forceinline__ void gload16(const void* g, void* l) {
    __builtin_amdgcn_global_load_lds(
        (const __attribute__((address_space(1))) unsigned*)g,
        (__attribute__((address_space(3))) unsigned*)l, 16, 0, 0);
}
__device__ inline float sigmoidf(float x) { return 1.f / (1.f + expf(-x)); }

// ================= bf16 MFMA GEMM, 64x128 tile: C = A(MxK) * B(NxK)^T =================
template<int AS32, int BS32>
__global__ __launch_bounds__(256)
void gemm_mfma(const void* __restrict__ Ap, long sAb, int lda,
               const void* __restrict__ Bp, long sBb, int ldb,
               const float* __restrict__ bias, long sBiasb,
               float* __restrict__ C, long sCb, int ldc,
               u16* __restrict__ Cb, long sCbb, int ldcb,
               int M, int Nn, int K, int act, int ksplit)
{
    __shared__ __align__(16) u16 lA[2][256][8];
    __shared__ __align__(16) u16 lB[2][512][8];

    const int z = blockIdx.z;
    const int az = z / ksplit;
    const int ks = z - az * ksplit;
    const int Ksl = K / ksplit;
    const int kbase = ks * Ksl;

    const char* Abase = (const char*)Ap + (long)az * sAb * (AS32 ? 4 : 2);
    const char* Bbase = (const char*)Bp + (long)az * sBb * (BS32 ? 4 : 2);

    const int tid = threadIdx.x;
    const int lane = tid & 63;
    const int wave = tid >> 6;
    const int row0 = blockIdx.x * 64;
    const int col0 = blockIdx.y * 128;
    const int wcol = wave * 32;

    const int akg = tid >> 6, ar_ = tid & 63;
    long arow = row0 + ar_; if (arow >= M) arow = M - 1;
    const int bkg0 = tid >> 7, br_0 = tid & 127;
    const int s1 = tid + 256;
    const int bkg1 = s1 >> 7, br_1 = s1 & 127;
    long brow0 = col0 + br_0; if (brow0 >= Nn) brow0 = Nn - 1;
    long brow1 = col0 + br_1; if (brow1 >= Nn) brow1 = Nn - 1;

    f32x4 acc[4][2] = {};

#define STAGE(b, kt) do {                                                     \
    const int k0_ = kbase + (kt) * BK;                                        \
    if constexpr (AS32) {                                                     \
        const float* A32 = (const float*)Abase;                               \
        const float* p0 = A32 + arow * lda + k0_ + akg * 8;                   \
        float4 x0 = *(const float4*)p0, x1 = *(const float4*)(p0 + 4);        \
        *(s16x8*)&lA[b][tid][0] = pack8(x0, x1);                              \
    } else {                                                                  \
        const u16* A16 = (const u16*)Abase;                                   \
        gload16(A16 + arow * lda + k0_ + akg * 8, &lA[b][tid][0]);            \
    }                                                                         \
    if constexpr (BS32) {                                                     \
        const float* B32 = (const float*)Bbase;                               \
        const float* q0 = B32 + brow0 * ldb + k0_ + bkg0 * 8;                 \
        const float* q1 = B32 + brow1 * ldb + k0_ + bkg1 * 8;                 \
        float4 x0 = *(const float4*)q0, x1 = *(const float4*)(q0 + 4);        \
        float4 y0 = *(const float4*)q1, y1 = *(const float4*)(q1 + 4);        \
        *(s16x8*)&lB[b][tid][0] = pack8(x0, x1);                              \
        *(s16x8*)&lB[b][s1][0] = pack8(y0, y1);                               \
    } else {                                                                  \
        const u16* B16 = (const u16*)Bbase;                                   \
        gload16(B16 + brow0 * ldb + k0_ + bkg0 * 8, &lB[b][tid][0]);          \
        gload16(B16 + brow1 * ldb + k0_ + bkg1 * 8, &lB[b][s1][0]);           \
    }                                                                         \
} while (0)

    const int nk = Ksl / BK;
    STAGE(0, 0);
    __syncthreads();
    int buf = 0;
    const int kg = lane >> 4;
    const int lr = lane & 15;
    for (int kt = 0; kt < nk; ++kt) {
        if (kt + 1 < nk) STAGE(buf ^ 1, kt + 1);
        s16x8 af[4], bfr[2];
#pragma unroll
        for (int m = 0; m < 4; ++m)
            af[m] = *(const s16x8*)&lA[buf][kg * 64 + m * 16 + lr][0];
#pragma unroll
        for (int n = 0; n < 2; ++n)
            bfr[n] = *(const s16x8*)&lB[buf][kg * 128 + wcol + n * 16 + lr][0];
#pragma unroll
        for (int m = 0; m < 4; ++m)
#pragma unroll
            for (int n = 0; n < 2; ++n)
                acc[m][n] = __builtin_amdgcn_mfma_f32_16x16x32_bf16(af[m], bfr[n], acc[m][n], 0, 0, 0);
        __syncthreads();
        buf ^= 1;
    }
#undef STAGE

    const int ccol = lane & 15;
    const int crow = (lane >> 4) * 4;
#pragma unroll
    for (int n = 0; n < 2; ++n) {
        const int c = col0 + wcol + n * 16 + ccol;
        const float bv = bias ? bias[(long)az * sBiasb + c] : 0.f;
#pragma unroll
        for (int m = 0; m < 4; ++m) {
            const int rb = row0 + m * 16 + crow;
#pragma unroll
            for (int q = 0; q < 4; ++q) {
                const int r = rb + q;
                if (r >= M) continue;
                float v = acc[m][n][q] + bv;
                if (act == 1) v = 1.f / (1.f + expf(-v));
                else if (act == 2) v = tanhf(v);
                if (C)  C[(long)z * sCb + (long)r * ldc + c] = v;
                if (Cb) Cb[(long)z * sCbb + (long)r * ldcb + c] = (u16)bh(v);
            }
        }
    }
}

// ============ 128x128-tile fp32-in GEMM (pose / Wnm setup) ============
__global__ __launch_bounds__(256)
void gemm128_f32(const float* __restrict__ A, int lda,
                 const float* __restrict__ Bm, int ldb,
                 float* __restrict__ C, long sCb, int ldc,
                 u16* __restrict__ Cb, int ldcb,
                 int M, int Nn, int K, int ksplit)
{
    __shared__ __align__(16) u16 lA[2][512][8];
    __shared__ __align__(16) u16 lB[2][512][8];

    const int ks = blockIdx.z;
    const int Ksl = K / ksplit;
    const int kbase = ks * Ksl;

    const int tid = threadIdx.x;
    const int lane = tid & 63;
    const int wave = tid >> 6;
    const int row0 = blockIdx.x * 128;
    const int col0 = blockIdx.y * 128;
    const int wrow = (wave >> 1) * 64;
    const int wcol = (wave & 1) * 64;

    const int s0 = tid, s1 = tid + 256;
    const int kg0 = s0 >> 7, r0 = s0 & 127;
    const int kg1 = s1 >> 7, r1 = s1 & 127;
    long ar0 = row0 + r0; if (ar0 >= M) ar0 = M - 1;
    long ar1 = row0 + r1; if (ar1 >= M) ar1 = M - 1;
    long br0 = col0 + r0; if (br0 >= Nn) br0 = Nn - 1;
    long br1 = col0 + r1; if (br1 >= Nn) br1 = Nn - 1;

    f32x4 acc[4][4] = {};

#define STAGE128(b, kt) do {                                                  \
    const int k0_ = kbase + (kt) * BK;                                        \
    const float* p0 = A + ar0 * lda + k0_ + kg0 * 8;                          \
    const float* p1 = A + ar1 * lda + k0_ + kg1 * 8;                          \
    *(s16x8*)&lA[b][s0][0] = pack8(*(const float4*)p0, *(const float4*)(p0 + 4)); \
    *(s16x8*)&lA[b][s1][0] = pack8(*(const float4*)p1, *(const float4*)(p1 + 4)); \
    const float* q0 = Bm + br0 * ldb + k0_ + kg0 * 8;                         \
    const float* q1 = Bm + br1 * ldb + k0_ + kg1 * 8;                         \
    *(s16x8*)&lB[b][s0][0] = pack8(*(const float4*)q0, *(const float4*)(q0 + 4)); \
    *(s16x8*)&lB[b][s1][0] = pack8(*(const float4*)q1, *(const float4*)(q1 + 4)); \
} while (0)

    const int nk = Ksl / BK;
    STAGE128(0, 0);
    __syncthreads();
    int buf = 0;
    const int kg = lane >> 4;
    const int lr = lane & 15;
    for (int kt = 0; kt < nk; ++kt) {
        if (kt + 1 < nk) STAGE128(buf ^ 1, kt + 1);
        s16x8 af[4], bfr[4];
#pragma unroll
        for (int m = 0; m < 4; ++m)
            af[m] = *(const s16x8*)&lA[buf][kg * 128 + wrow + m * 16 + lr][0];
#pragma unroll
        for (int n = 0; n < 4; ++n)
            bfr[n] = *(const s16x8*)&lB[buf][kg * 128 + wcol + n * 16 + lr][0];
#pragma unroll
        for (int m = 0; m < 4; ++m)
#pragma unroll
            for (int n = 0; n < 4; ++n)
                acc[m][n] = __builtin_amdgcn_mfma_f32_16x16x32_bf16(af[m], bfr[n], acc[m][n], 0, 0, 0);
        __syncthreads();
        buf ^= 1;
    }
#undef STAGE128

    const int ccol = lane & 15;
    const int crow = (lane >> 4) * 4;
#pragma unroll
    for (int n = 0; n < 4; ++n) {
        const int c = col0 + wcol + n * 16 + ccol;
#pragma unroll
        for (int m = 0; m < 4; ++m) {
            const int rb = row0 + wrow + m * 16 + crow;
#pragma unroll
            for (int q = 0; q < 4; ++q) {
                const int r = rb + q;
                if (r >= M) continue;
                float v = acc[m][n][q];
                if (C)  C[(long)ks * sCb + (long)r * ldc + c] = v;
                if (Cb) Cb[(long)r * ldcb + c] = (u16)bh(v);
            }
        }
    }
}

// ============ fused gh-GEMM + GRU update + score partial ============
// Grid (32, 16): 64 rows x 64 h-cols; B-panel = 3 gates x 64 rows of Whh.
__global__ __launch_bounds__(256)
void gh_gru(const u16* __restrict__ hb_in, const u16* __restrict__ Whh_b,
            const float* __restrict__ bhh, const float* __restrict__ Gnm,
            const float* __restrict__ cbias,
            float* __restrict__ h, u16* __restrict__ hb_out,
            const float* __restrict__ Wa, float* __restrict__ gs_part, int tt)
{
    __shared__ __align__(16) u16 lA[2][256][8];
    __shared__ __align__(16) u16 lB[2][768][8];
    __shared__ float rowdot[64];

    const int tid = threadIdx.x;
    const int lane = tid & 63;
    const int wave = tid >> 6;
    const int wr = wave >> 1;          // 0..1 : 32-row slice
    const int wc = wave & 1;           // 0..1 : 32-col slice
    const int row0 = blockIdx.x * 64;
    const int col0 = blockIdx.y * 64;

    const int skg = tid >> 6, srow = tid & 63;
    long arow = row0 + srow; if (arow >= NROWS) arow = NROWS - 1;

    f32x4 acc[3][2][2] = {};

#define GSTAGE(b, kt) do {                                                    \
    const int k0_ = (kt) * BK;                                                \
    gload16(hb_in + arow * SQ + k0_ + skg * 8, &lA[b][tid][0]);               \
    gload16(Whh_b + (long)(          col0 + srow) * SQ + k0_ + skg * 8, &lB[b][tid][0]);        \
    gload16(Whh_b + (long)(SQ +     col0 + srow) * SQ + k0_ + skg * 8, &lB[b][tid + 256][0]);   \
    gload16(Whh_b + (long)(2 * SQ + col0 + srow) * SQ + k0_ + skg * 8, &lB[b][tid + 512][0]);   \
} while (0)

    GSTAGE(0, 0);
    __syncthreads();
    int buf = 0;
    const int kg = lane >> 4;
    const int lr = lane & 15;
    for (int kt = 0; kt < 32; ++kt) {
        if (kt + 1 < 32) GSTAGE(buf ^ 1, kt + 1);
        s16x8 af[2], bfr[3][2];
#pragma unroll
        for (int m = 0; m < 2; ++m)
            af[m] = *(const s16x8*)&lA[buf][kg * 64 + wr * 32 + m * 16 + lr][0];
#pragma unroll
        for (int g = 0; g < 3; ++g)
#pragma unroll
            for (int n = 0; n < 2; ++n)
                bfr[g][n] = *(const s16x8*)&lB[buf][g * 256 + kg * 64 + wc * 32 + n * 16 + lr][0];
#pragma unroll
        for (int g = 0; g < 3; ++g)
#pragma unroll
            for (int m = 0; m < 2; ++m)
#pragma unroll
                for (int n = 0; n < 2; ++n)
                    acc[g][m][n] = __builtin_amdgcn_mfma_f32_16x16x32_bf16(af[m], bfr[g][n], acc[g][m][n], 0, 0, 0);
        __syncthreads();
        buf ^= 1;
    }
#undef GSTAGE

    if (tid < 64) rowdot[tid] = 0.f;
    __syncthreads();

    const int ccol = lane & 15;
    const int crow4 = (lane >> 4) * 4;
    int col2[2];
    float cbv[3][2], bhv[3][2], wav[2];
#pragma unroll
    for (int n = 0; n < 2; ++n) {
        const int c = col0 + wc * 32 + n * 16 + ccol;
        col2[n] = c;
#pragma unroll
        for (int g = 0; g < 3; ++g) {
            cbv[g][n] = cbias[g * SQ + c];
            bhv[g][n] = bhh[g * SQ + c];
        }
    }

#pragma unroll
    for (int m = 0; m < 2; ++m) {
#pragma unroll
        for (int q = 0; q < 4; ++q) {
            const int row = row0 + wr * 32 + m * 16 + crow4 + q;
            const bool valid = (row < NROWS);
            float d = 0.f;
            if (valid) {
                const int e = row / BNN;
                const int rr = row - e * BNN;
                const int b_ = rr / 144;
                const int ni = (rr / 12) % 12;
                const int mi = rr % 12;
                const int bt = b_ * TQ + tt;
                const float* gnp = Gnm + ((long)e * 96 + bt * 12 + ni) * 6144;
                const float* gmp = Gnm + ((long)e * 96 + bt * 12 + mi) * 6144 + G3S;
                const float* wap = Wa + (long)e * SQ;
#pragma unroll
                for (int n = 0; n < 2; ++n) {
                    const int c = col2[n];
                    float gr  = acc[0][m][n][q] + bhv[0][n] + gnp[c] + gmp[c] + cbv[0][n];
                    float gz  = acc[1][m][n][q] + bhv[1][n] + gnp[SQ + c] + gmp[SQ + c] + cbv[1][n];
                    float ghn = acc[2][m][n][q] + bhv[2][n];
                    float gin = gnp[2 * SQ + c] + gmp[2 * SQ + c] + cbv[2][n];
                    float rg = sigmoidf(gr);
                    float zg = sigmoidf(gz);
                    float nn2 = tanhf(gin + rg * ghn);
                    float hp = h[(long)row * SQ + c];
                    float hn = (1.f - zg) * nn2 + zg * hp;
                    h[(long)row * SQ + c] = hn;
                    hb_out[(long)row * SQ + c] = (u16)bh(hn);
                    d += hn * wap[c];
                }
            }
            d += __shfl_xor(d, 1); d += __shfl_xor(d, 2);
            d += __shfl_xor(d, 4); d += __shfl_xor(d, 8);
            if (valid && ccol == 0)
                atomicAdd(&rowdot[wr * 32 + m * 16 + crow4 + q], d);
        }
    }
    __syncthreads();
    if (tid < 64) {
        const int row = row0 + tid;
        if (row < NROWS) gs_part[(long)row * 16 + blockIdx.y] = rowdot[tid];
    }
}

// ---------- gs finalize: sum 16 partials + ba -> sigmoid ----------
__global__ void gs_fin(const float* __restrict__ gs_part, const float* __restrict__ ba,
                       float* __restrict__ gs, int tt)
{
    int row = blockIdx.x * 256 + threadIdx.x;
    if (row >= NROWS) return;
    float s = 0.f;
#pragma unroll
    for (int j = 0; j < 16; ++j) s += gs_part[(long)row * 16 + j];
    const int e = row / BNN;
    const int rr = row - e * BNN;
    const int b_ = rr / 144;
    const int ni = (rr / 12) % 12;
    const int mi = rr % 12;
    const int bt = b_ * TQ + tt;
    gs[((bt * 12 + ni) * 12 + mi) * EQ + e] = sigmoidf(s + ba[e]);
}

// ---------- generic split-K reduce ----------
__global__ __launch_bounds__(256)
void reduce_k(const float* __restrict__ part, int ksplit, int mn, int Nn,
              const float* __restrict__ bias, long sBiasB, int act,
              float* __restrict__ Cf, long sCfB, int ldcf,
              u16* __restrict__ Cb, long sCbB, int ldcb)
{
    int i4 = blockIdx.x * 256 + threadIdx.x;
    int total4 = mn >> 2;
    if (i4 >= total4) return;
    int b = blockIdx.y;
    const float4* p4 = (const float4*)part;
    float4 s = make_float4(0.f, 0.f, 0.f, 0.f);
    for (int ks = 0; ks < ksplit; ++ks) {
        float4 v = p4[(long)(b * ksplit + ks) * total4 + i4];
        s.x += v.x; s.y += v.y; s.z += v.z; s.w += v.w;
    }
    int i = i4 << 2;
    int r = i / Nn, c = i % Nn;
    if (bias) {
        float4 bv = *(const float4*)(bias + (long)b * sBiasB + c);
        s.x += bv.x; s.y += bv.y; s.z += bv.z; s.w += bv.w;
    }
    if (act == 1) {
        s.x = sigmoidf(s.x); s.y = sigmoidf(s.y); s.z = sigmoidf(s.z); s.w = sigmoidf(s.w);
    } else if (act == 2) {
        s.x = tanhf(s.x); s.y = tanhf(s.y); s.z = tanhf(s.z); s.w = tanhf(s.w);
    }
    if (Cf) *(float4*)(Cf + (long)b * sCfB + (long)r * ldcf + c) = s;
    if (Cb) {
        ushort4 o;
        o.x = (u16)bh(s.x); o.y = (u16)bh(s.y); o.z = (u16)bh(s.z); o.w = (u16)bh(s.w);
        *(ushort4*)(Cb + (long)b * sCbB + (long)r * ldcb + c) = o;
    }
}

__global__ void cvt_bf16_k(const float* __restrict__ src, u16* __restrict__ dst, int n4)
{
    int i = blockIdx.x * 256 + threadIdx.x;
    if (i >= n4) return;
    float4 v = ((const float4*)src)[i];
    ushort4 o;
    o.x = (u16)bh(v.x); o.y = (u16)bh(v.y); o.z = (u16)bh(v.z); o.w = (u16)bh(v.w);
    ((ushort4*)dst)[i] = o;
}

__global__ __launch_bounds__(256)
void transpose_wc(const float* __restrict__ Wcomp, float* __restrict__ W1T, float* __restrict__ W2T)
{
    __shared__ float t1[32][33];
    __shared__ float t2[32][33];
    const int tx = threadIdx.x & 31;
    const int ty = threadIdx.x >> 5;
    const int d0 = blockIdx.x * 32;
    const int s0 = blockIdx.y * 32;
#pragma unroll
    for (int k = 0; k < 4; ++k) {
        int d = d0 + ty + k * 8;
        t1[ty + k * 8][tx] = Wcomp[(long)d * 2048 + s0 + tx];
        t2[ty + k * 8][tx] = Wcomp[(long)d * 2048 + 1024 + s0 + tx];
    }
    __syncthreads();
#pragma unroll
    for (int k = 0; k < 4; ++k) {
        int s = s0 + ty + k * 8;
        W1T[(long)s * 1024 + d0 + tx] = t1[tx][ty + k * 8];
        W2T[(long)s * 1024 + d0 + tx] = t2[tx][ty + k * 8];
    }
}

__global__ void pack_rz(const float* __restrict__ Wr, const float* __restrict__ Wz,
                        const float* __restrict__ br, const float* __restrict__ bz,
                        u16* __restrict__ Wrz, float* __restrict__ brz)
{
    int i4 = blockIdx.x * 256 + threadIdx.x;
    if (i4 < 512) {
        int c = i4 * 4;
        float4 b = (c < 1024) ? *(const float4*)(br + c) : *(const float4*)(bz + c - 1024);
        *(float4*)(brz + c) = b;
    }
    if (i4 >= 1048576) return;
    int i = i4 * 4;
    int j = i >> 11;
    int c = i & 2047;
    float4 v = (j < 1024) ? *(const float4*)(Wr + (long)j * 2048 + c)
                          : *(const float4*)(Wz + (long)(j - 1024) * 2048 + c);
    ushort4 o;
    o.x = (u16)bh(v.x); o.y = (u16)bh(v.y); o.z = (u16)bh(v.z); o.w = (u16)bh(v.w);
    *(ushort4*)(Wrz + i) = o;
}

// ---------------- threefry2x32 ----------------
__device__ inline unsigned rotl32(unsigned v, int r) { return (v << r) | (v >> (32 - r)); }

__device__ inline void tf2x32(unsigned k0, unsigned k1, unsigned x0, unsigned x1,
                              unsigned& o0, unsigned& o1)
{
    unsigned ks2 = k0 ^ k1 ^ 0x1BD11BDAu;
    x0 += k0; x1 += k1;
    x0 += x1; x1 = rotl32(x1, 13); x1 ^= x0;
    x0 += x1; x1 = rotl32(x1, 15); x1 ^= x0;
    x0 += x1; x1 = rotl32(x1, 26); x1 ^= x0;
    x0 += x1; x1 = rotl32(x1,  6); x1 ^= x0;
    x0 += k1; x1 += ks2 + 1u;
    x0 += x1; x1 = rotl32(x1, 17); x1 ^= x0;
    x0 += x1; x1 = rotl32(x1, 29); x1 ^= x0;
    x0 += x1; x1 = rotl32(x1, 16); x1 ^= x0;
    x0 += x1; x1 = rotl32(x1, 24); x1 ^= x0;
    x0 += ks2; x1 += k0 + 2u;
    x0 += x1; x1 = rotl32(x1, 13); x1 ^= x0;
    x0 += x1; x1 = rotl32(x1, 15); x1 ^= x0;
    x0 += x1; x1 = rotl32(x1, 26); x1 ^= x0;
    x0 += x1; x1 = rotl32(x1,  6); x1 ^= x0;
    x0 += k0; x1 += k1 + 3u;
    x0 += x1; x1 = rotl32(x1, 17); x1 ^= x0;
    x0 += x1; x1 = rotl32(x1, 29); x1 ^= x0;
    x0 += x1; x1 = rotl32(x1, 16); x1 ^= x0;
    x0 += x1; x1 = rotl32(x1, 24); x1 ^= x0;
    x0 += k1; x1 += ks2 + 4u;
    x0 += x1; x1 = rotl32(x1, 13); x1 ^= x0;
    x0 += x1; x1 = rotl32(x1, 15); x1 ^= x0;
    x0 += x1; x1 = rotl32(x1, 26); x1 ^= x0;
    x0 += x1; x1 = rotl32(x1,  6); x1 ^= x0;
    x0 += ks2; x1 += k0 + 5u;
    o0 = x0; o1 = x1;
}

__device__ inline float bits_to_normal(unsigned bits)
{
    float f = __uint_as_float((bits >> 9) | 0x3f800000u) - 1.0f;
    const float lo = -0.99999994f;
    float u = f * (1.0f - lo) + lo;
    u = fmaxf(u, lo);
    return 1.41421356237f * erfinvf(u);
}

#define HALF_E 147456

__global__ void h0_fill(float* __restrict__ h, u16* __restrict__ hb, int t, float h0std)
{
    int i = blockIdx.x * blockDim.x + threadIdx.x;
    int e = blockIdx.y;
    unsigned k0, k1, o0, o1;
    tf2x32(0u, 42u, 0u, (unsigned)(t * EQ + e), k0, k1);
    tf2x32(k0, k1, (unsigned)i, (unsigned)(i + HALF_E), o0, o1);
    float* he = h + (long)e * (BNN * SQ);
    u16* heb = hb + (long)e * (BNN * SQ);
    float v0 = bits_to_normal(o0) * h0std;
    float v1 = bits_to_normal(o1) * h0std;
    he[i] = v0;            heb[i] = (u16)bh(v0);
    he[i + HALF_E] = v1;   heb[i + HALF_E] = (u16)bh(v1);
}

__global__ void cbias_k(const float* __restrict__ Wih, const float* __restrict__ bih,
                        const float* __restrict__ bcomp, float* __restrict__ cbias)
{
    int g = blockIdx.x * blockDim.x + threadIdx.x;
    if (g >= G3S) return;
    const float* w = Wih + (long)g * SQ;
    float s = 0.f;
    for (int k = 0; k < SQ; k += 4) {
        float4 wv = *(const float4*)(w + k);
        float4 bv = *(const float4*)(bcomp + k);
        s += wv.x * bv.x + wv.y * bv.y + wv.z * bv.z + wv.w * bv.w;
    }
    cbias[g] = s + bih[g];
}

// ---------------- merged + amat fused ----------------
__global__ __launch_bounds__(256)
void merged_amat_k(const float* __restrict__ gs, const u16* __restrict__ msgs_b,
                   const float* __restrict__ prop, u16* __restrict__ amat_b)
{
    const int bn = blockIdx.x;   // 0..95
    const int bt = bn / 12;
    __shared__ float g[84];
    if (threadIdx.x < 84) g[threadIdx.x] = gs[bn * 84 + threadIdx.x];
    __syncthreads();
    const int s = threadIdx.x * 4;
    float4 acc = make_float4(0.f, 0.f, 0.f, 0.f);
    for (int j = 0; j < 84; ++j) {
        const ushort4 mv = *(const ushort4*)(msgs_b + ((long)(bt * 84 + j)) * SQ + s);
        float gj = g[j];
        acc.x += gj * b2f(mv.x);
        acc.y += gj * b2f(mv.y);
        acc.z += gj * b2f(mv.z);
        acc.w += gj * b2f(mv.w);
    }
    ushort4 o;
    o.x = (u16)bh(acc.x); o.y = (u16)bh(acc.y); o.z = (u16)bh(acc.z); o.w = (u16)bh(acc.w);
    *(ushort4*)(amat_b + (long)bn * 2048 + s) = o;
    float4 pv = *(const float4*)(prop + (long)bn * SQ + s);
    ushort4 o2;
    o2.x = (u16)bh(pv.x); o2.y = (u16)bh(pv.y); o2.z = (u16)bh(pv.z); o2.w = (u16)bh(pv.w);
    *(ushort4*)(amat_b + (long)bn * 2048 + 1024 + s) = o2;
}

__global__ void ahat_k(const float* __restrict__ rz, const float* __restrict__ prop,
                       u16* __restrict__ amat_b)
{
    int i = blockIdx.x * 256 + threadIdx.x;
    int rrow = i >> 10, c = i & 1023;
    float r = rz[(long)rrow * 2048 + c];
    amat_b[(long)rrow * 2048 + 1024 + c] = (u16)bh(r * prop[i]);
}

__global__ void propupd_k(const float* __restrict__ rz, const float* __restrict__ hhat,
                          float* __restrict__ prop, u16* __restrict__ prop_b)
{
    int i = blockIdx.x * 256 + threadIdx.x;
    int rrow = i >> 10, c = i & 1023;
    float z = rz[(long)rrow * 2048 + 1024 + c];
    float v = (1.f - z) * prop[i] + z * hhat[i];
    prop[i] = v;
    prop_b[i] = (u16)bh(v);
}

// ---------------- final outputs ----------------
__global__ __launch_bounds__(256)
void outputs_k(const float* __restrict__ gs, float* __restrict__ out)
{
    __shared__ float s_act[672];
    __shared__ float s_asum[96];
    int tid = threadIdx.x;
    for (int idx = tid; idx < 672; idx += 256) {
        int bn = idx / 7, e = idx % 7;
        float sum = 0.f;
        for (int m = 0; m < 12; ++m) {
            float g0 = gs[bn * 84 + m * 7];
            sum += (1.f - g0) * gs[bn * 84 + m * 7 + e];
        }
        s_act[idx] = sum;
        out[idx] = sum;
    }
    for (int idx = tid; idx < 96; idx += 256) {
        float a = 0.f;
        for (int m = 0; m < 12; ++m) a += 1.f - gs[idx * 84 + m * 7];
        s_asum[idx] = a;
    }
    for (int idx = tid; idx < 1152; idx += 256) {
        int bn = idx / 12, m = idx % 12;
        out[720 + idx] = 1.f - gs[bn * 84 + m * 7];
    }
    __syncthreads();
    if (tid < 8) {
        float tmp[6];
        float mx = -1e30f;
        for (int e = 1; e < 7; ++e) {
            float sum = 0.f;
            for (int n = 0; n < 12; ++n) {
                int bn = tid * 12 + n;
                sum += s_act[bn * 7 + e] * s_asum[bn];
            }
            tmp[e - 1] = sum;
            mx = fmaxf(mx, sum);
        }
        float den = 0.f;
        for (int e = 0; e < 6; ++e) { tmp[e] = expf(tmp[e] - mx); den += tmp[e]; }
        for (int e = 0; e < 6; ++e) out[672 + tid * 6 + e] = tmp[e] / den;
    }
}

// ---------------- host ----------------
template<int AS32, int BS32>
static void launch_gemm(const void* A, long sAb, int lda,
                        const void* B, long sBb, int ldb,
                        const float* bias, long sBiasb,
                        float* C, long sCb, int ldc,
                        u16* Cb, long sCbb, int ldcb,
                        int M, int Nn, int K, int act, int batch, int ksplit,
                        hipStream_t stream)
{
    dim3 grid((M + 63) / 64, (Nn + 127) / 128, batch * ksplit);
    gemm_mfma<AS32, BS32><<<grid, dim3(256), 0, stream>>>(
        A, sAb, lda, B, sBb, ldb, bias, sBiasb, C, sCb, ldc, Cb, sCbb, ldcb,
        M, Nn, K, act, ksplit);
}

extern "C" void kernel_launch(void* const* d_in, const int* in_sizes, int n_in,
                              void* d_out, int out_size, void* d_ws, size_t ws_size,
                              hipStream_t stream)
{
    const float* pose  = (const float*)d_in[0];
    const float* Wc    = (const float*)d_in[5];
    const float* bc    = (const float*)d_in[6];
    const float* We    = (const float*)d_in[7];
    const float* be    = (const float*)d_in[8];
    const float* Wcomp = (const float*)d_in[9];
    const float* bcomp = (const float*)d_in[10];
    const float* Wr    = (const float*)d_in[11];
    const float* br    = (const float*)d_in[12];
    const float* Wz    = (const float*)d_in[13];
    const float* bz    = (const float*)d_in[14];
    const float* Wh    = (const float*)d_in[15];
    const float* bh_   = (const float*)d_in[16];
    const float* Wih   = (const float*)d_in[17];
    const float* Whh   = (const float*)d_in[18];
    const float* bih   = (const float*)d_in[19];
    const float* bhh   = (const float*)d_in[20];
    const float* Wa    = (const float*)d_in[21];
    const float* ba    = (const float*)d_in[22];

    float* ws = (float*)d_ws;
    // fp32 region
    float* prop    = ws;                    // 98304
    float* cbias   = prop + 98304;          // 3072
    float* h       = cbias + 3072;          // 2064384
    float* Gnm     = h + 2064384;           // 4128768  (7 x 96 x 6144)
    float* scratch = Gnm + 4128768;         // 8257536  (split-K partials / W1T/W2T)
    float* gs      = scratch + 8257536;     // 8064
    float* rz      = gs + 8064;             // 196608
    float* hhat    = rz + 196608;           // 98304
    float* brz     = hhat + 98304;          // 2048
    float* gs_part = brz + 2048;            // 32768 (2048 x 16)
    float* fend    = gs_part + 32768;
    // bf16 region
    u16* Whh_b  = (u16*)fend;               // 3145728
    u16* Wnm_b  = Whh_b + 3145728;          // 6291456  (6144 x 1024)
    u16* Wrz_b  = Wnm_b + 6291456;          // 4194304
    u16* msgs_b = Wrz_b + 4194304;          // 688128
    u16* h_b0   = msgs_b + 688128;          // 2064384
    u16* h_b1   = h_b0 + 2064384;           // 2064384
    u16* prop_b = h_b1 + 2064384;           // 98304
    u16* amat_b = prop_b + 98304;           // 196608

    float* W1T = scratch;                   // transient
    float* W2T = scratch + 1048576;         // transient

    const float h0std = sqrtf(2.0f / (288.0f * 1024.0f + 1024.0f));

    // ---- once per call ----
    hipLaunchKernelGGL(cvt_bf16_k, dim3(3072), dim3(256), 0, stream, Whh, Whh_b, 786432);
    hipLaunchKernelGGL(cbias_k, dim3(12), dim3(256), 0, stream, Wih, bih, bcomp, cbias);
    hipLaunchKernelGGL(transpose_wc, dim3(32, 32), dim3(256), 0, stream, Wcomp, W1T, W2T);
    hipLaunchKernelGGL(pack_rz, dim3(4096), dim3(256), 0, stream, Wr, Wz, br, bz, Wrz_b, brz);
    // Wnm rows 0..3071 = Wih @ W1T^T ; rows 3072..6143 = Wih @ W2T^T
    gemm128_f32<<<dim3(24, 8, 1), dim3(256), 0, stream>>>(
        Wih, SQ, W1T, SQ, nullptr, 0, SQ, Wnm_b, SQ, G3S, SQ, SQ, 1);
    gemm128_f32<<<dim3(24, 8, 1), dim3(256), 0, stream>>>(
        Wih, SQ, W2T, SQ, nullptr, 0, SQ, Wnm_b + (long)G3S * SQ, SQ, G3S, SQ, SQ, 1);
    // prop = pose @ Wc^T + bc : single row-tile, ksplit=25
    gemm128_f32<<<dim3(1, 8, 25), dim3(256), 0, stream>>>(
        pose, DIN, Wc, DIN, scratch, 98304, SQ, nullptr, SQ, 96, SQ, DIN, 25);
    hipLaunchKernelGGL(reduce_k, dim3(96, 1), dim3(256), 0, stream,
                       scratch, 25, 98304, SQ, bc, 0L, 0,
                       prop, 0L, SQ, prop_b, 0L, SQ);

    for (int t = 0; t <= TSQ; ++t) {
        // msgs[bt,n,e,s] = prop @ We[e]^T + be[e] : batch 7, ksplit 2
        launch_gemm<0, 1>(prop_b, 0, SQ, We, (long)SQ * SQ, SQ, nullptr, 0,
                          scratch, 98304, SQ, nullptr, 0, 0, 96, SQ, SQ, 0, EQ, 2, stream);
        hipLaunchKernelGGL(reduce_k, dim3(96, EQ), dim3(256), 0, stream,
                           scratch, 2, 98304, SQ, be, (long)SQ, 0,
                           (float*)nullptr, 0L, 0, msgs_b, (long)SQ, EQ * SQ);
        // Gnm = msgs_e @ Wnm^T : batch 7, ksplit 2, N=6144
        launch_gemm<0, 0>(msgs_b, SQ, EQ * SQ, Wnm_b, 0, SQ, nullptr, 0,
                          scratch, 589824, 6 * SQ, nullptr, 0, 0, 96, 6 * SQ, SQ, 0, EQ, 2, stream);
        hipLaunchKernelGGL(reduce_k, dim3(576, EQ), dim3(256), 0, stream,
                           scratch, 2, 589824, 6 * SQ, (const float*)nullptr, 0L, 0,
                           Gnm, 589824L, 6 * SQ, (u16*)nullptr, 0L, 0);
        // h0
        hipLaunchKernelGGL(h0_fill, dim3(576, EQ), dim3(256), 0, stream, h, h_b0, t, h0std);
        // fused GRU scan
        for (int tt = 0; tt < TQ; ++tt) {
            const u16* hin = (tt & 1) ? h_b1 : h_b0;
            u16* hout = (tt & 1) ? h_b0 : h_b1;
            hipLaunchKernelGGL(gh_gru, dim3(32, 16), dim3(256), 0, stream,
                               hin, Whh_b, bhh, Gnm, cbias, h, hout, Wa, gs_part, tt);
            hipLaunchKernelGGL(gs_fin, dim3(8), dim3(256), 0, stream, gs_part, ba, gs, tt);
        }
        if (t < TSQ) {
            hipLaunchKernelGGL(merged_amat_k, dim3(96), dim3(256), 0, stream,
                               gs, msgs_b, prop, amat_b);
            // rz = sigmoid(amat @ [Wr;Wz]^T + brz) : ksplit=8
            launch_gemm<0, 0>(amat_b, 0, 2 * SQ, Wrz_b, 0, 2 * SQ, nullptr, 0,
                              scratch, 196608, 2 * SQ, nullptr, 0, 0, 96, 2 * SQ, 2 * SQ, 0, 1, 8, stream);
            hipLaunchKernelGGL(reduce_k, dim3(192, 1), dim3(256), 0, stream,
                               scratch, 8, 196608, 2 * SQ, brz, 0L, 1,
                               rz, 0L, 2 * SQ, (u16*)nullptr, 0L, 0);
            hipLaunchKernelGGL(ahat_k, dim3(384), dim3(256), 0, stream, rz, prop, amat_b);
            // hhat = tanh(amat @ Wh^T + bh) : ksplit=8
            launch_gemm<0, 1>(amat_b, 0, 2 * SQ, Wh, 0, 2 * SQ, nullptr, 0,
                              scratch, 98304, SQ, nullptr, 0, 0, 96, SQ, 2 * SQ, 0, 1, 8, stream);
            hipLaunchKernelGGL(reduce_k, dim3(96, 1), dim3(256), 0, stream,
                               scratch, 8, 98304, SQ, bh_, 0L, 2,
                               hhat, 0L, SQ, (u16*)nullptr, 0L, 0);
            hipLaunchKernelGGL(propupd_k, dim3(384), dim3(256), 0, stream, rz, hhat, prop, prop_b);
        }
    }

    hipLaunchKernelGGL(outputs_k, dim3(1), dim3(256), 0, stream, gs, (float*)d_out);
}

// Round 5
// 1467.909 us; speedup vs baseline: 4.0930x; 1.0201x over previous
//
#include <hip/hip_runtime.h>
#include <math.h>

// Problem constants
#define NQ 12
#define EQ 7
#define SQ 1024
#define TSQ 3
#define DIN 26400
#define BQ 2
#define TQ 4
#define BT 8          // B*T
#define BNN 288       // B*N*N
#define NROWS 2016    // E*BNN
#define G3S 3072      // 3*S
#define BK 32

typedef unsigned short u16;
typedef float f32x4 __attribute__((ext_vector_type(4)));
typedef short s16x8 __attribute__((ext_vector_type(8)));

__device__ __forceinline__ short bh(float f) {
    unsigned u = __float_as_uint(f);
    return (short)((u + 0x8000u) >> 16);
}
__device__ __forceinline__ float b2f(u16 u) {
    return __uint_as_float((unsigned)u << 16);
}
__device__ __forceinline__ s16x8 pack8(float4 a, float4 b) {
    s16x8 r;
    r[0] = bh(a.x); r[1] = bh(a.y); r[2] = bh(a.z); r[3] = bh(a.w);
    r[4] = bh(b.x); r[5] = bh(b.y); r[6] = bh(b.z); r[7] = bh(b.w);
    return r;
}
__device__ __forceinline__ void gload16(const void* g, void* l) {
    __builtin_amdgcn_global_load_lds(
        (const __attribute__((address_space(1))) unsigned*)g,
        (__attribute__((address_space(3))) unsigned*)l, 16, 0, 0);
}
__device__ inline float sigmoidf(float x) { return 1.f / (1.f + expf(-x)); }

// ================= bf16 MFMA GEMM, 64x128 tile: C = A(MxK) * B(NxK)^T =================
template<int AS32, int BS32>
__global__ __launch_bounds__(256)
void gemm_mfma(const void* __restrict__ Ap, long sAb, int lda,
               const void* __restrict__ Bp, long sBb, int ldb,
               const float* __restrict__ bias, long sBiasb,
               float* __restrict__ C, long sCb, int ldc,
               u16* __restrict__ Cb, long sCbb, int ldcb,
               int M, int Nn, int K, int act, int ksplit)
{
    __shared__ __align__(16) u16 lA[2][256][8];
    __shared__ __align__(16) u16 lB[2][512][8];

    const int z = blockIdx.z;
    const int az = z / ksplit;
    const int ks = z - az * ksplit;
    const int Ksl = K / ksplit;
    const int kbase = ks * Ksl;

    const char* Abase = (const char*)Ap + (long)az * sAb * (AS32 ? 4 : 2);
    const char* Bbase = (const char*)Bp + (long)az * sBb * (BS32 ? 4 : 2);

    const int tid = threadIdx.x;
    const int lane = tid & 63;
    const int wave = tid >> 6;
    const int row0 = blockIdx.x * 64;
    const int col0 = blockIdx.y * 128;
    const int wcol = wave * 32;

    const int akg = tid >> 6, ar_ = tid & 63;
    long arow = row0 + ar_; if (arow >= M) arow = M - 1;
    const int bkg0 = tid >> 7, br_0 = tid & 127;
    const int s1 = tid + 256;
    const int bkg1 = s1 >> 7, br_1 = s1 & 127;
    long brow0 = col0 + br_0; if (brow0 >= Nn) brow0 = Nn - 1;
    long brow1 = col0 + br_1; if (brow1 >= Nn) brow1 = Nn - 1;

    f32x4 acc[4][2] = {};

#define STAGE(b, kt) do {                                                     \
    const int k0_ = kbase + (kt) * BK;                                        \
    if constexpr (AS32) {                                                     \
        const float* A32 = (const float*)Abase;                               \
        const float* p0 = A32 + arow * lda + k0_ + akg * 8;                   \
        float4 x0 = *(const float4*)p0, x1 = *(const float4*)(p0 + 4);        \
        *(s16x8*)&lA[b][tid][0] = pack8(x0, x1);                              \
    } else {                                                                  \
        const u16* A16 = (const u16*)Abase;                                   \
        gload16(A16 + arow * lda + k0_ + akg * 8, &lA[b][tid][0]);            \
    }                                                                         \
    if constexpr (BS32) {                                                     \
        const float* B32 = (const float*)Bbase;                               \
        const float* q0 = B32 + brow0 * ldb + k0_ + bkg0 * 8;                 \
        const float* q1 = B32 + brow1 * ldb + k0_ + bkg1 * 8;                 \
        float4 x0 = *(const float4*)q0, x1 = *(const float4*)(q0 + 4);        \
        float4 y0 = *(const float4*)q1, y1 = *(const float4*)(q1 + 4);        \
        *(s16x8*)&lB[b][tid][0] = pack8(x0, x1);                              \
        *(s16x8*)&lB[b][s1][0] = pack8(y0, y1);                               \
    } else {                                                                  \
        const u16* B16 = (const u16*)Bbase;                                   \
        gload16(B16 + brow0 * ldb + k0_ + bkg0 * 8, &lB[b][tid][0]);          \
        gload16(B16 + brow1 * ldb + k0_ + bkg1 * 8, &lB[b][s1][0]);           \
    }                                                                         \
} while (0)

    const int nk = Ksl / BK;
    STAGE(0, 0);
    __syncthreads();
    int buf = 0;
    const int kg = lane >> 4;
    const int lr = lane & 15;
    for (int kt = 0; kt < nk; ++kt) {
        if (kt + 1 < nk) STAGE(buf ^ 1, kt + 1);
        s16x8 af[4], bfr[2];
#pragma unroll
        for (int m = 0; m < 4; ++m)
            af[m] = *(const s16x8*)&lA[buf][kg * 64 + m * 16 + lr][0];
#pragma unroll
        for (int n = 0; n < 2; ++n)
            bfr[n] = *(const s16x8*)&lB[buf][kg * 128 + wcol + n * 16 + lr][0];
#pragma unroll
        for (int m = 0; m < 4; ++m)
#pragma unroll
            for (int n = 0; n < 2; ++n)
                acc[m][n] = __builtin_amdgcn_mfma_f32_16x16x32_bf16(af[m], bfr[n], acc[m][n], 0, 0, 0);
        __syncthreads();
        buf ^= 1;
    }
#undef STAGE

    const int ccol = lane & 15;
    const int crow = (lane >> 4) * 4;
#pragma unroll
    for (int n = 0; n < 2; ++n) {
        const int c = col0 + wcol + n * 16 + ccol;
        const float bv = bias ? bias[(long)az * sBiasb + c] : 0.f;
#pragma unroll
        for (int m = 0; m < 4; ++m) {
            const int rb = row0 + m * 16 + crow;
#pragma unroll
            for (int q = 0; q < 4; ++q) {
                const int r = rb + q;
                if (r >= M) continue;
                float v = acc[m][n][q] + bv;
                if (act == 1) v = 1.f / (1.f + expf(-v));
                else if (act == 2) v = tanhf(v);
                if (C)  C[(long)z * sCb + (long)r * ldc + c] = v;
                if (Cb) Cb[(long)z * sCbb + (long)r * ldcb + c] = (u16)bh(v);
            }
        }
    }
}

// ============ 128x128-tile fp32-in GEMM (pose / Wnm setup) ============
__global__ __launch_bounds__(256)
void gemm128_f32(const float* __restrict__ A, int lda,
                 const float* __restrict__ Bm, int ldb,
                 float* __restrict__ C, long sCb, int ldc,
                 u16* __restrict__ Cb, int ldcb,
                 int M, int Nn, int K, int ksplit)
{
    __shared__ __align__(16) u16 lA[2][512][8];
    __shared__ __align__(16) u16 lB[2][512][8];

    const int ks = blockIdx.z;
    const int Ksl = K / ksplit;
    const int kbase = ks * Ksl;

    const int tid = threadIdx.x;
    const int lane = tid & 63;
    const int wave = tid >> 6;
    const int row0 = blockIdx.x * 128;
    const int col0 = blockIdx.y * 128;
    const int wrow = (wave >> 1) * 64;
    const int wcol = (wave & 1) * 64;

    const int s0 = tid, s1 = tid + 256;
    const int kg0 = s0 >> 7, r0 = s0 & 127;
    const int kg1 = s1 >> 7, r1 = s1 & 127;
    long ar0 = row0 + r0; if (ar0 >= M) ar0 = M - 1;
    long ar1 = row0 + r1; if (ar1 >= M) ar1 = M - 1;
    long br0 = col0 + r0; if (br0 >= Nn) br0 = Nn - 1;
    long br1 = col0 + r1; if (br1 >= Nn) br1 = Nn - 1;

    f32x4 acc[4][4] = {};

#define STAGE128(b, kt) do {                                                  \
    const int k0_ = kbase + (kt) * BK;                                        \
    const float* p0 = A + ar0 * lda + k0_ + kg0 * 8;                          \
    const float* p1 = A + ar1 * lda + k0_ + kg1 * 8;                          \
    *(s16x8*)&lA[b][s0][0] = pack8(*(const float4*)p0, *(const float4*)(p0 + 4)); \
    *(s16x8*)&lA[b][s1][0] = pack8(*(const float4*)p1, *(const float4*)(p1 + 4)); \
    const float* q0 = Bm + br0 * ldb + k0_ + kg0 * 8;                         \
    const float* q1 = Bm + br1 * ldb + k0_ + kg1 * 8;                         \
    *(s16x8*)&lB[b][s0][0] = pack8(*(const float4*)q0, *(const float4*)(q0 + 4)); \
    *(s16x8*)&lB[b][s1][0] = pack8(*(const float4*)q1, *(const float4*)(q1 + 4)); \
} while (0)

    const int nk = Ksl / BK;
    STAGE128(0, 0);
    __syncthreads();
    int buf = 0;
    const int kg = lane >> 4;
    const int lr = lane & 15;
    for (int kt = 0; kt < nk; ++kt) {
        if (kt + 1 < nk) STAGE128(buf ^ 1, kt + 1);
        s16x8 af[4], bfr[4];
#pragma unroll
        for (int m = 0; m < 4; ++m)
            af[m] = *(const s16x8*)&lA[buf][kg * 128 + wrow + m * 16 + lr][0];
#pragma unroll
        for (int n = 0; n < 4; ++n)
            bfr[n] = *(const s16x8*)&lB[buf][kg * 128 + wcol + n * 16 + lr][0];
#pragma unroll
        for (int m = 0; m < 4; ++m)
#pragma unroll
            for (int n = 0; n < 4; ++n)
                acc[m][n] = __builtin_amdgcn_mfma_f32_16x16x32_bf16(af[m], bfr[n], acc[m][n], 0, 0, 0);
        __syncthreads();
        buf ^= 1;
    }
#undef STAGE128

    const int ccol = lane & 15;
    const int crow = (lane >> 4) * 4;
#pragma unroll
    for (int n = 0; n < 4; ++n) {
        const int c = col0 + wcol + n * 16 + ccol;
#pragma unroll
        for (int m = 0; m < 4; ++m) {
            const int rb = row0 + wrow + m * 16 + crow;
#pragma unroll
            for (int q = 0; q < 4; ++q) {
                const int r = rb + q;
                if (r >= M) continue;
                float v = acc[m][n][q];
                if (C)  C[(long)ks * sCb + (long)r * ldc + c] = v;
                if (Cb) Cb[(long)r * ldcb + c] = (u16)bh(v);
            }
        }
    }
}

// ============ fused gh-GEMM + GRU update + score partial (v2: BK=64, XCD swizzle) ============
// Logical grid (32 row-tiles x 16 col-tiles); physical grid 512 flat.
// Swizzle: f%8 selects the XCD; col-pair y in {2*(f%8), 2*(f%8)+1} so each XCD's L2
// holds only 2 B-panels (768 KB of Whh) instead of all 6 MB.
__global__ __launch_bounds__(256)
void gh_gru(const u16* __restrict__ hb_in, const u16* __restrict__ Whh_b,
            const float* __restrict__ bhh, const float* __restrict__ Gnm,
            const float* __restrict__ cbias,
            float* __restrict__ h, u16* __restrict__ hb_out,
            const float* __restrict__ Wa, float* __restrict__ gs_part, int tt)
{
    __shared__ __align__(16) u16 lA[2][512][8];    // [k16 0..7][row 0..63]
    __shared__ __align__(16) u16 lB[2][1536][8];   // [k16 0..7][gate*64+row]
    __shared__ float rowdot[64];

    const int f = blockIdx.x;
    const int ly = 2 * (f & 7) + ((f >> 3) & 1);   // 0..15 col-tile
    const int lx = f >> 4;                          // 0..31 row-tile
    const int row0 = lx * 64;
    const int col0 = ly * 64;

    const int tid = threadIdx.x;
    const int lane = tid & 63;
    const int wave = tid >> 6;
    const int wr = wave >> 1;          // 0..1 : 32-row slice
    const int wc = wave & 1;           // 0..1 : 32-col slice

    // A staging: slots tid (k16=tid>>6, row=tid&63) and tid+256 (k16+4, same row)
    const int arow_l = tid & 63;
    const int ak16 = tid >> 6;
    long arow = row0 + arow_l; if (arow >= NROWS) arow = NROWS - 1;

    f32x4 acc[3][2][2] = {};

#define GSTAGE(b, kt) do {                                                    \
    const int k0_ = (kt) * 64;                                                \
    gload16(hb_in + arow * SQ + k0_ + ak16 * 8,        &lA[b][tid][0]);       \
    gload16(hb_in + arow * SQ + k0_ + (ak16 + 4) * 8,  &lA[b][tid + 256][0]); \
    _Pragma("unroll")                                                         \
    for (int j = 0; j < 6; ++j) {                                             \
        const int s = tid + j * 256;                                          \
        const int bk16 = s / 192;                                             \
        const int grow = s - bk16 * 192;                                      \
        const int g = grow >> 6;                                              \
        const int brow = grow & 63;                                           \
        gload16(Whh_b + (long)(g * SQ + col0 + brow) * SQ + k0_ + bk16 * 8,   \
                &lB[b][s][0]);                                                \
    }                                                                         \
} while (0)

    GSTAGE(0, 0);
    __syncthreads();
    int buf = 0;
    const int kg = lane >> 4;
    const int lr = lane & 15;
    for (int kt = 0; kt < 16; ++kt) {
        if (kt + 1 < 16) GSTAGE(buf ^ 1, kt + 1);
#pragma unroll
        for (int kk = 0; kk < 2; ++kk) {
            const int k16 = kk * 4 + kg;
            s16x8 af[2], bfr[3][2];
#pragma unroll
            for (int m = 0; m < 2; ++m)
                af[m] = *(const s16x8*)&lA[buf][k16 * 64 + wr * 32 + m * 16 + lr][0];
#pragma unroll
            for (int g = 0; g < 3; ++g)
#pragma unroll
                for (int n = 0; n < 2; ++n)
                    bfr[g][n] = *(const s16x8*)&lB[buf][k16 * 192 + g * 64 + wc * 32 + n * 16 + lr][0];
#pragma unroll
            for (int g = 0; g < 3; ++g)
#pragma unroll
                for (int m = 0; m < 2; ++m)
#pragma unroll
                    for (int n = 0; n < 2; ++n)
                        acc[g][m][n] = __builtin_amdgcn_mfma_f32_16x16x32_bf16(af[m], bfr[g][n], acc[g][m][n], 0, 0, 0);
        }
        __syncthreads();
        buf ^= 1;
    }
#undef GSTAGE

    if (tid < 64) rowdot[tid] = 0.f;
    __syncthreads();

    const int ccol = lane & 15;
    const int crow4 = (lane >> 4) * 4;
    int col2[2];
    float cbv[3][2], bhv[3][2];
#pragma unroll
    for (int n = 0; n < 2; ++n) {
        const int c = col0 + wc * 32 + n * 16 + ccol;
        col2[n] = c;
#pragma unroll
        for (int g = 0; g < 3; ++g) {
            cbv[g][n] = cbias[g * SQ + c];
            bhv[g][n] = bhh[g * SQ + c];
        }
    }

#pragma unroll
    for (int m = 0; m < 2; ++m) {
#pragma unroll
        for (int q = 0; q < 4; ++q) {
            const int row = row0 + wr * 32 + m * 16 + crow4 + q;
            const bool valid = (row < NROWS);
            float d = 0.f;
            if (valid) {
                const int e = row / BNN;
                const int rr = row - e * BNN;
                const int b_ = rr / 144;
                const int ni = (rr / 12) % 12;
                const int mi = rr % 12;
                const int bt = b_ * TQ + tt;
                const float* gnp = Gnm + ((long)e * 96 + bt * 12 + ni) * 6144;
                const float* gmp = Gnm + ((long)e * 96 + bt * 12 + mi) * 6144 + G3S;
                const float* wap = Wa + (long)e * SQ;
#pragma unroll
                for (int n = 0; n < 2; ++n) {
                    const int c = col2[n];
                    float gr  = acc[0][m][n][q] + bhv[0][n] + gnp[c] + gmp[c] + cbv[0][n];
                    float gz  = acc[1][m][n][q] + bhv[1][n] + gnp[SQ + c] + gmp[SQ + c] + cbv[1][n];
                    float ghn = acc[2][m][n][q] + bhv[2][n];
                    float gin = gnp[2 * SQ + c] + gmp[2 * SQ + c] + cbv[2][n];
                    float rg = sigmoidf(gr);
                    float zg = sigmoidf(gz);
                    float nn2 = tanhf(gin + rg * ghn);
                    float hp = h[(long)row * SQ + c];
                    float hn = (1.f - zg) * nn2 + zg * hp;
                    h[(long)row * SQ + c] = hn;
                    hb_out[(long)row * SQ + c] = (u16)bh(hn);
                    d += hn * wap[c];
                }
            }
            d += __shfl_xor(d, 1); d += __shfl_xor(d, 2);
            d += __shfl_xor(d, 4); d += __shfl_xor(d, 8);
            if (valid && ccol == 0)
                atomicAdd(&rowdot[wr * 32 + m * 16 + crow4 + q], d);
        }
    }
    __syncthreads();
    if (tid < 64) {
        const int row = row0 + tid;
        if (row < NROWS) gs_part[((long)tt * 2048 + row) * 16 + ly] = rowdot[tid];
    }
}

// ---------- gs finalize for ALL 4 tt: sum 16 partials + ba -> sigmoid ----------
__global__ void gs_fin_all(const float* __restrict__ gs_part, const float* __restrict__ ba,
                           float* __restrict__ gs)
{
    int idx = blockIdx.x * 256 + threadIdx.x;   // 0..8191
    if (idx >= 4 * 2048) return;
    const int tt = idx >> 11;
    const int row = idx & 2047;
    if (row >= NROWS) return;
    float s = 0.f;
#pragma unroll
    for (int j = 0; j < 16; ++j) s += gs_part[((long)tt * 2048 + row) * 16 + j];
    const int e = row / BNN;
    const int rr = row - e * BNN;
    const int b_ = rr / 144;
    const int ni = (rr / 12) % 12;
    const int mi = rr % 12;
    const int bt = b_ * TQ + tt;
    gs[((bt * 12 + ni) * 12 + mi) * EQ + e] = sigmoidf(s + ba[e]);
}

// ---------- generic split-K reduce ----------
__global__ __launch_bounds__(256)
void reduce_k(const float* __restrict__ part, int ksplit, int mn, int Nn,
              const float* __restrict__ bias, long sBiasB, int act,
              float* __restrict__ Cf, long sCfB, int ldcf,
              u16* __restrict__ Cb, long sCbB, int ldcb)
{
    int i4 = blockIdx.x * 256 + threadIdx.x;
    int total4 = mn >> 2;
    if (i4 >= total4) return;
    int b = blockIdx.y;
    const float4* p4 = (const float4*)part;
    float4 s = make_float4(0.f, 0.f, 0.f, 0.f);
    for (int ks = 0; ks < ksplit; ++ks) {
        float4 v = p4[(long)(b * ksplit + ks) * total4 + i4];
        s.x += v.x; s.y += v.y; s.z += v.z; s.w += v.w;
    }
    int i = i4 << 2;
    int r = i / Nn, c = i % Nn;
    if (bias) {
        float4 bv = *(const float4*)(bias + (long)b * sBiasB + c);
        s.x += bv.x; s.y += bv.y; s.z += bv.z; s.w += bv.w;
    }
    if (act == 1) {
        s.x = sigmoidf(s.x); s.y = sigmoidf(s.y); s.z = sigmoidf(s.z); s.w = sigmoidf(s.w);
    } else if (act == 2) {
        s.x = tanhf(s.x); s.y = tanhf(s.y); s.z = tanhf(s.z); s.w = tanhf(s.w);
    }
    if (Cf) *(float4*)(Cf + (long)b * sCfB + (long)r * ldcf + c) = s;
    if (Cb) {
        ushort4 o;
        o.x = (u16)bh(s.x); o.y = (u16)bh(s.y); o.z = (u16)bh(s.z); o.w = (u16)bh(s.w);
        *(ushort4*)(Cb + (long)b * sCbB + (long)r * ldcb + c) = o;
    }
}

__global__ void cvt_bf16_k(const float* __restrict__ src, u16* __restrict__ dst, int n4)
{
    int i = blockIdx.x * 256 + threadIdx.x;
    if (i >= n4) return;
    float4 v = ((const float4*)src)[i];
    ushort4 o;
    o.x = (u16)bh(v.x); o.y = (u16)bh(v.y); o.z = (u16)bh(v.z); o.w = (u16)bh(v.w);
    ((ushort4*)dst)[i] = o;
}

__global__ __launch_bounds__(256)
void transpose_wc(const float* __restrict__ Wcomp, float* __restrict__ W1T, float* __restrict__ W2T)
{
    __shared__ float t1[32][33];
    __shared__ float t2[32][33];
    const int tx = threadIdx.x & 31;
    const int ty = threadIdx.x >> 5;
    const int d0 = blockIdx.x * 32;
    const int s0 = blockIdx.y * 32;
#pragma unroll
    for (int k = 0; k < 4; ++k) {
        int d = d0 + ty + k * 8;
        t1[ty + k * 8][tx] = Wcomp[(long)d * 2048 + s0 + tx];
        t2[ty + k * 8][tx] = Wcomp[(long)d * 2048 + 1024 + s0 + tx];
    }
    __syncthreads();
#pragma unroll
    for (int k = 0; k < 4; ++k) {
        int s = s0 + ty + k * 8;
        W1T[(long)s * 1024 + d0 + tx] = t1[tx][ty + k * 8];
        W2T[(long)s * 1024 + d0 + tx] = t2[tx][ty + k * 8];
    }
}

__global__ void pack_rz(const float* __restrict__ Wr, const float* __restrict__ Wz,
                        const float* __restrict__ br, const float* __restrict__ bz,
                        u16* __restrict__ Wrz, float* __restrict__ brz)
{
    int i4 = blockIdx.x * 256 + threadIdx.x;
    if (i4 < 512) {
        int c = i4 * 4;
        float4 b = (c < 1024) ? *(const float4*)(br + c) : *(const float4*)(bz + c - 1024);
        *(float4*)(brz + c) = b;
    }
    if (i4 >= 1048576) return;
    int i = i4 * 4;
    int j = i >> 11;
    int c = i & 2047;
    float4 v = (j < 1024) ? *(const float4*)(Wr + (long)j * 2048 + c)
                          : *(const float4*)(Wz + (long)(j - 1024) * 2048 + c);
    ushort4 o;
    o.x = (u16)bh(v.x); o.y = (u16)bh(v.y); o.z = (u16)bh(v.z); o.w = (u16)bh(v.w);
    *(ushort4*)(Wrz + i) = o;
}

// ---------------- threefry2x32 ----------------
__device__ inline unsigned rotl32(unsigned v, int r) { return (v << r) | (v >> (32 - r)); }

__device__ inline void tf2x32(unsigned k0, unsigned k1, unsigned x0, unsigned x1,
                              unsigned& o0, unsigned& o1)
{
    unsigned ks2 = k0 ^ k1 ^ 0x1BD11BDAu;
    x0 += k0; x1 += k1;
    x0 += x1; x1 = rotl32(x1, 13); x1 ^= x0;
    x0 += x1; x1 = rotl32(x1, 15); x1 ^= x0;
    x0 += x1; x1 = rotl32(x1, 26); x1 ^= x0;
    x0 += x1; x1 = rotl32(x1,  6); x1 ^= x0;
    x0 += k1; x1 += ks2 + 1u;
    x0 += x1; x1 = rotl32(x1, 17); x1 ^= x0;
    x0 += x1; x1 = rotl32(x1, 29); x1 ^= x0;
    x0 += x1; x1 = rotl32(x1, 16); x1 ^= x0;
    x0 += x1; x1 = rotl32(x1, 24); x1 ^= x0;
    x0 += ks2; x1 += k0 + 2u;
    x0 += x1; x1 = rotl32(x1, 13); x1 ^= x0;
    x0 += x1; x1 = rotl32(x1, 15); x1 ^= x0;
    x0 += x1; x1 = rotl32(x1, 26); x1 ^= x0;
    x0 += x1; x1 = rotl32(x1,  6); x1 ^= x0;
    x0 += k0; x1 += k1 + 3u;
    x0 += x1; x1 = rotl32(x1, 17); x1 ^= x0;
    x0 += x1; x1 = rotl32(x1, 29); x1 ^= x0;
    x0 += x1; x1 = rotl32(x1, 16); x1 ^= x0;
    x0 += x1; x1 = rotl32(x1, 24); x1 ^= x0;
    x0 += k1; x1 += ks2 + 4u;
    x0 += x1; x1 = rotl32(x1, 13); x1 ^= x0;
    x0 += x1; x1 = rotl32(x1, 15); x1 ^= x0;
    x0 += x1; x1 = rotl32(x1, 26); x1 ^= x0;
    x0 += x1; x1 = rotl32(x1,  6); x1 ^= x0;
    x0 += ks2; x1 += k0 + 5u;
    o0 = x0; o1 = x1;
}

__device__ inline float bits_to_normal(unsigned bits)
{
    float f = __uint_as_float((bits >> 9) | 0x3f800000u) - 1.0f;
    const float lo = -0.99999994f;
    float u = f * (1.0f - lo) + lo;
    u = fmaxf(u, lo);
    return 1.41421356237f * erfinvf(u);
}

#define HALF_E 147456

__global__ void h0_fill(float* __restrict__ h, u16* __restrict__ hb, int t, float h0std)
{
    int i = blockIdx.x * blockDim.x + threadIdx.x;
    int e = blockIdx.y;
    unsigned k0, k1, o0, o1;
    tf2x32(0u, 42u, 0u, (unsigned)(t * EQ + e), k0, k1);
    tf2x32(k0, k1, (unsigned)i, (unsigned)(i + HALF_E), o0, o1);
    float* he = h + (long)e * (BNN * SQ);
    u16* heb = hb + (long)e * (BNN * SQ);
    float v0 = bits_to_normal(o0) * h0std;
    float v1 = bits_to_normal(o1) * h0std;
    he[i] = v0;            heb[i] = (u16)bh(v0);
    he[i + HALF_E] = v1;   heb[i + HALF_E] = (u16)bh(v1);
}

__global__ void cbias_k(const float* __restrict__ Wih, const float* __restrict__ bih,
                        const float* __restrict__ bcomp, float* __restrict__ cbias)
{
    int g = blockIdx.x * blockDim.x + threadIdx.x;
    if (g >= G3S) return;
    const float* w = Wih + (long)g * SQ;
    float s = 0.f;
    for (int k = 0; k < SQ; k += 4) {
        float4 wv = *(const float4*)(w + k);
        float4 bv = *(const float4*)(bcomp + k);
        s += wv.x * bv.x + wv.y * bv.y + wv.z * bv.z + wv.w * bv.w;
    }
    cbias[g] = s + bih[g];
}

// ---------------- merged + amat fused ----------------
__global__ __launch_bounds__(256)
void merged_amat_k(const float* __restrict__ gs, const u16* __restrict__ msgs_b,
                   const float* __restrict__ prop, u16* __restrict__ amat_b)
{
    const int bn = blockIdx.x;   // 0..95
    const int bt = bn / 12;
    __shared__ float g[84];
    if (threadIdx.x < 84) g[threadIdx.x] = gs[bn * 84 + threadIdx.x];
    __syncthreads();
    const int s = threadIdx.x * 4;
    float4 acc = make_float4(0.f, 0.f, 0.f, 0.f);
    for (int j = 0; j < 84; ++j) {
        const ushort4 mv = *(const ushort4*)(msgs_b + ((long)(bt * 84 + j)) * SQ + s);
        float gj = g[j];
        acc.x += gj * b2f(mv.x);
        acc.y += gj * b2f(mv.y);
        acc.z += gj * b2f(mv.z);
        acc.w += gj * b2f(mv.w);
    }
    ushort4 o;
    o.x = (u16)bh(acc.x); o.y = (u16)bh(acc.y); o.z = (u16)bh(acc.z); o.w = (u16)bh(acc.w);
    *(ushort4*)(amat_b + (long)bn * 2048 + s) = o;
    float4 pv = *(const float4*)(prop + (long)bn * SQ + s);
    ushort4 o2;
    o2.x = (u16)bh(pv.x); o2.y = (u16)bh(pv.y); o2.z = (u16)bh(pv.z); o2.w = (u16)bh(pv.w);
    *(ushort4*)(amat_b + (long)bn * 2048 + 1024 + s) = o2;
}

__global__ void ahat_k(const float* __restrict__ rz, const float* __restrict__ prop,
                       u16* __restrict__ amat_b)
{
    int i = blockIdx.x * 256 + threadIdx.x;
    int rrow = i >> 10, c = i & 1023;
    float r = rz[(long)rrow * 2048 + c];
    amat_b[(long)rrow * 2048 + 1024 + c] = (u16)bh(r * prop[i]);
}

__global__ void propupd_k(const float* __restrict__ rz, const float* __restrict__ hhat,
                          float* __restrict__ prop, u16* __restrict__ prop_b)
{
    int i = blockIdx.x * 256 + threadIdx.x;
    int rrow = i >> 10, c = i & 1023;
    float z = rz[(long)rrow * 2048 + 1024 + c];
    float v = (1.f - z) * prop[i] + z * hhat[i];
    prop[i] = v;
    prop_b[i] = (u16)bh(v);
}

// ---------------- final outputs ----------------
__global__ __launch_bounds__(256)
void outputs_k(const float* __restrict__ gs, float* __restrict__ out)
{
    __shared__ float s_act[672];
    __shared__ float s_asum[96];
    int tid = threadIdx.x;
    for (int idx = tid; idx < 672; idx += 256) {
        int bn = idx / 7, e = idx % 7;
        float sum = 0.f;
        for (int m = 0; m < 12; ++m) {
            float g0 = gs[bn * 84 + m * 7];
            sum += (1.f - g0) * gs[bn * 84 + m * 7 + e];
        }
        s_act[idx] = sum;
        out[idx] = sum;
    }
    for (int idx = tid; idx < 96; idx += 256) {
        float a = 0.f;
        for (int m = 0; m < 12; ++m) a += 1.f - gs[idx * 84 + m * 7];
        s_asum[idx] = a;
    }
    for (int idx = tid; idx < 1152; idx += 256) {
        int bn = idx / 12, m = idx % 12;
        out[720 + idx] = 1.f - gs[bn * 84 + m * 7];
    }
    __syncthreads();
    if (tid < 8) {
        float tmp[6];
        float mx = -1e30f;
        for (int e = 1; e < 7; ++e) {
            float sum = 0.f;
            for (int n = 0; n < 12; ++n) {
                int bn = tid * 12 + n;
                sum += s_act[bn * 7 + e] * s_asum[bn];
            }
            tmp[e - 1] = sum;
            mx = fmaxf(mx, sum);
        }
        float den = 0.f;
        for (int e = 0; e < 6; ++e) { tmp[e] = expf(tmp[e] - mx); den += tmp[e]; }
        for (int e = 0; e < 6; ++e) out[672 + tid * 6 + e] = tmp[e] / den;
    }
}

// ---------------- host ----------------
template<int AS32, int BS32>
static void launch_gemm(const void* A, long sAb, int lda,
                        const void* B, long sBb, int ldb,
                        const float* bias, long sBiasb,
                        float* C, long sCb, int ldc,
                        u16* Cb, long sCbb, int ldcb,
                        int M, int Nn, int K, int act, int batch, int ksplit,
                        hipStream_t stream)
{
    dim3 grid((M + 63) / 64, (Nn + 127) / 128, batch * ksplit);
    gemm_mfma<AS32, BS32><<<grid, dim3(256), 0, stream>>>(
        A, sAb, lda, B, sBb, ldb, bias, sBiasb, C, sCb, ldc, Cb, sCbb, ldcb,
        M, Nn, K, act, ksplit);
}

extern "C" void kernel_launch(void* const* d_in, const int* in_sizes, int n_in,
                              void* d_out, int out_size, void* d_ws, size_t ws_size,
                              hipStream_t stream)
{
    const float* pose  = (const float*)d_in[0];
    const float* Wc    = (const float*)d_in[5];
    const float* bc    = (const float*)d_in[6];
    const float* We    = (const float*)d_in[7];
    const float* be    = (const float*)d_in[8];
    const float* Wcomp = (const float*)d_in[9];
    const float* bcomp = (const float*)d_in[10];
    const float* Wr    = (const float*)d_in[11];
    const float* br    = (const float*)d_in[12];
    const float* Wz    = (const float*)d_in[13];
    const float* bz    = (const float*)d_in[14];
    const float* Wh    = (const float*)d_in[15];
    const float* bh_   = (const float*)d_in[16];
    const float* Wih   = (const float*)d_in[17];
    const float* Whh   = (const float*)d_in[18];
    const float* bih   = (const float*)d_in[19];
    const float* bhh   = (const float*)d_in[20];
    const float* Wa    = (const float*)d_in[21];
    const float* ba    = (const float*)d_in[22];

    float* ws = (float*)d_ws;
    // fp32 region
    float* prop    = ws;                    // 98304
    float* cbias   = prop + 98304;          // 3072
    float* h       = cbias + 3072;          // 2064384
    float* Gnm     = h + 2064384;           // 4128768  (7 x 96 x 6144)
    float* scratch = Gnm + 4128768;         // 8257536  (split-K partials / W1T/W2T)
    float* gs      = scratch + 8257536;     // 8064
    float* rz      = gs + 8064;             // 196608
    float* hhat    = rz + 196608;           // 98304
    float* brz     = hhat + 98304;          // 2048
    float* gs_part = brz + 2048;            // 131072 (4 x 2048 x 16)
    float* fend    = gs_part + 131072;
    // bf16 region
    u16* Whh_b  = (u16*)fend;               // 3145728
    u16* Wnm_b  = Whh_b + 3145728;          // 6291456  (6144 x 1024)
    u16* Wrz_b  = Wnm_b + 6291456;          // 4194304
    u16* msgs_b = Wrz_b + 4194304;          // 688128
    u16* h_b0   = msgs_b + 688128;          // 2064384
    u16* h_b1   = h_b0 + 2064384;           // 2064384
    u16* prop_b = h_b1 + 2064384;           // 98304
    u16* amat_b = prop_b + 98304;           // 196608

    float* W1T = scratch;                   // transient
    float* W2T = scratch + 1048576;         // transient

    const float h0std = sqrtf(2.0f / (288.0f * 1024.0f + 1024.0f));

    // ---- once per call ----
    hipLaunchKernelGGL(cvt_bf16_k, dim3(3072), dim3(256), 0, stream, Whh, Whh_b, 786432);
    hipLaunchKernelGGL(cbias_k, dim3(12), dim3(256), 0, stream, Wih, bih, bcomp, cbias);
    hipLaunchKernelGGL(transpose_wc, dim3(32, 32), dim3(256), 0, stream, Wcomp, W1T, W2T);
    hipLaunchKernelGGL(pack_rz, dim3(4096), dim3(256), 0, stream, Wr, Wz, br, bz, Wrz_b, brz);
    // Wnm rows 0..3071 = Wih @ W1T^T ; rows 3072..6143 = Wih @ W2T^T
    gemm128_f32<<<dim3(24, 8, 1), dim3(256), 0, stream>>>(
        Wih, SQ, W1T, SQ, nullptr, 0, SQ, Wnm_b, SQ, G3S, SQ, SQ, 1);
    gemm128_f32<<<dim3(24, 8, 1), dim3(256), 0, stream>>>(
        Wih, SQ, W2T, SQ, nullptr, 0, SQ, Wnm_b + (long)G3S * SQ, SQ, G3S, SQ, SQ, 1);
    // prop = pose @ Wc^T + bc : ksplit=75 (Ksl=352, 600 blocks)
    gemm128_f32<<<dim3(1, 8, 75), dim3(256), 0, stream>>>(
        pose, DIN, Wc, DIN, scratch, 98304, SQ, nullptr, SQ, 96, SQ, DIN, 75);
    hipLaunchKernelGGL(reduce_k, dim3(96, 1), dim3(256), 0, stream,
                       scratch, 75, 98304, SQ, bc, 0L, 0,
                       prop, 0L, SQ, prop_b, 0L, SQ);

    for (int t = 0; t <= TSQ; ++t) {
        // msgs[bt,n,e,s] = prop @ We[e]^T + be[e] : batch 7, ksplit 4
        launch_gemm<0, 1>(prop_b, 0, SQ, We, (long)SQ * SQ, SQ, nullptr, 0,
                          scratch, 98304, SQ, nullptr, 0, 0, 96, SQ, SQ, 0, EQ, 4, stream);
        hipLaunchKernelGGL(reduce_k, dim3(96, EQ), dim3(256), 0, stream,
                           scratch, 4, 98304, SQ, be, (long)SQ, 0,
                           (float*)nullptr, 0L, 0, msgs_b, (long)SQ, EQ * SQ);
        // Gnm = msgs_e @ Wnm^T : batch 7, direct write (no split-K)
        launch_gemm<0, 0>(msgs_b, SQ, EQ * SQ, Wnm_b, 0, SQ, nullptr, 0,
                          Gnm, 589824, 6 * SQ, nullptr, 0, 0, 96, 6 * SQ, SQ, 0, EQ, 1, stream);
        // h0
        hipLaunchKernelGGL(h0_fill, dim3(576, EQ), dim3(256), 0, stream, h, h_b0, t, h0std);
        // fused GRU scan
        for (int tt = 0; tt < TQ; ++tt) {
            const u16* hin = (tt & 1) ? h_b1 : h_b0;
            u16* hout = (tt & 1) ? h_b0 : h_b1;
            hipLaunchKernelGGL(gh_gru, dim3(512), dim3(256), 0, stream,
                               hin, Whh_b, bhh, Gnm, cbias, h, hout, Wa, gs_part, tt);
        }
        hipLaunchKernelGGL(gs_fin_all, dim3(32), dim3(256), 0, stream, gs_part, ba, gs);
        if (t < TSQ) {
            hipLaunchKernelGGL(merged_amat_k, dim3(96), dim3(256), 0, stream,
                               gs, msgs_b, prop, amat_b);
            // rz = sigmoid(amat @ [Wr;Wz]^T + brz) : ksplit=8
            launch_gemm<0, 0>(amat_b, 0, 2 * SQ, Wrz_b, 0, 2 * SQ, nullptr, 0,
                              scratch, 196608, 2 * SQ, nullptr, 0, 0, 96, 2 * SQ, 2 * SQ, 0, 1, 8, stream);
            hipLaunchKernelGGL(reduce_k, dim3(192, 1), dim3(256), 0, stream,
                               scratch, 8, 196608, 2 * SQ, brz, 0L, 1,
                               rz, 0L, 2 * SQ, (u16*)nullptr, 0L, 0);
            hipLaunchKernelGGL(ahat_k, dim3(384), dim3(256), 0, stream, rz, prop, amat_b);
            // hhat = tanh(amat @ Wh^T + bh) : ksplit=8
            launch_gemm<0, 1>(amat_b, 0, 2 * SQ, Wh, 0, 2 * SQ, nullptr, 0,
                              scratch, 98304, SQ, nullptr, 0, 0, 96, SQ, 2 * SQ, 0, 1, 8, stream);
            hipLaunchKernelGGL(reduce_k, dim3(96, 1), dim3(256), 0, stream,
                               scratch, 8, 98304, SQ, bh_, 0L, 2,
                               hhat, 0L, SQ, (u16*)nullptr, 0L, 0);
            hipLaunchKernelGGL(propupd_k, dim3(384), dim3(256), 0, stream, rz, hhat, prop, prop_b);
        }
    }

    hipLaunchKernelGGL(outputs_k, dim3(1), dim3(256), 0, stream, gs, (float*)d_out);
}

// Round 6
// 1251.809 us; speedup vs baseline: 4.7995x; 1.1726x over previous
//
#include <hip/hip_runtime.h>
#include <math.h>

// Problem constants
#define NQ 12
#define EQ 7
#define SQ 1024
#define TSQ 3
#define DIN 26400
#define BQ 2
#define TQ 4
#define BT 8          // B*T
#define BNN 288       // B*N*N
#define NROWS 2016    // E*BNN
#define G3S 3072      // 3*S
#define BK 32

typedef unsigned short u16;
typedef float f32x4 __attribute__((ext_vector_type(4)));
typedef short s16x8 __attribute__((ext_vector_type(8)));

__device__ __forceinline__ short bh(float f) {
    unsigned u = __float_as_uint(f);
    return (short)((u + 0x8000u) >> 16);
}
__device__ __forceinline__ float b2f(u16 u) {
    return __uint_as_float((unsigned)u << 16);
}
__device__ __forceinline__ s16x8 pack8(float4 a, float4 b) {
    s16x8 r;
    r[0] = bh(a.x); r[1] = bh(a.y); r[2] = bh(a.z); r[3] = bh(a.w);
    r[4] = bh(b.x); r[5] = bh(b.y); r[6] = bh(b.z); r[7] = bh(b.w);
    return r;
}
__device__ __forceinline__ void gload16(const void* g, void* l) {
    __builtin_amdgcn_global_load_lds(
        (const __attribute__((address_space(1))) unsigned*)g,
        (__attribute__((address_space(3))) unsigned*)l, 16, 0, 0);
}
__device__ inline float sigmoidf(float x) { return 1.f / (1.f + expf(-x)); }

// ================= bf16 MFMA GEMM, 64x128 tile: C = A(MxK) * B(NxK)^T =================
template<int AS32, int BS32>
__global__ __launch_bounds__(256)
void gemm_mfma(const void* __restrict__ Ap, long sAb, int lda,
               const void* __restrict__ Bp, long sBb, int ldb,
               const float* __restrict__ bias, long sBiasb,
               float* __restrict__ C, long sCb, int ldc,
               u16* __restrict__ Cb, long sCbb, int ldcb,
               int M, int Nn, int K, int act, int ksplit)
{
    __shared__ __align__(16) u16 lA[2][256][8];
    __shared__ __align__(16) u16 lB[2][512][8];

    const int z = blockIdx.z;
    const int az = z / ksplit;
    const int ks = z - az * ksplit;
    const int Ksl = K / ksplit;
    const int kbase = ks * Ksl;

    const char* Abase = (const char*)Ap + (long)az * sAb * (AS32 ? 4 : 2);
    const char* Bbase = (const char*)Bp + (long)az * sBb * (BS32 ? 4 : 2);

    const int tid = threadIdx.x;
    const int lane = tid & 63;
    const int wave = tid >> 6;
    const int row0 = blockIdx.x * 64;
    const int col0 = blockIdx.y * 128;
    const int wcol = wave * 32;

    // bf16 staging indices (16B/lane, wave-uniform LDS dest)
    const int akg = tid >> 6;
    long arow = row0 + (tid & 63); if (arow >= M) arow = M - 1;
    const int bkg0 = tid >> 7;
    const int s1 = tid + 256;
    const int bkg1 = s1 >> 7;
    long brow0 = col0 + (tid & 127); if (brow0 >= Nn) brow0 = Nn - 1;
    long brow1 = col0 + (s1 & 127);  if (brow1 >= Nn) brow1 = Nn - 1;

    // fp32 staging indices (contiguous 32B/64B per row for DRAM bursts)
    const int arw32 = tid >> 2, akg32 = tid & 3;
    long ar32 = row0 + arw32; if (ar32 >= M) ar32 = M - 1;
    const int brw32 = tid >> 1, bh32 = tid & 1;
    long br32 = col0 + brw32; if (br32 >= Nn) br32 = Nn - 1;

    f32x4 acc[4][2] = {};

#define STAGE(b, kt) do {                                                     \
    const int k0_ = kbase + (kt) * BK;                                        \
    if constexpr (AS32) {                                                     \
        const float* A32 = (const float*)Abase;                               \
        const float* p0 = A32 + ar32 * lda + k0_ + akg32 * 8;                 \
        *(s16x8*)&lA[b][akg32 * 64 + arw32][0] =                              \
            pack8(*(const float4*)p0, *(const float4*)(p0 + 4));              \
    } else {                                                                  \
        const u16* A16 = (const u16*)Abase;                                   \
        gload16(A16 + arow * lda + k0_ + akg * 8, &lA[b][tid][0]);            \
    }                                                                         \
    if constexpr (BS32) {                                                     \
        const float* B32 = (const float*)Bbase;                               \
        const float* q0 = B32 + br32 * ldb + k0_ + bh32 * 16;                 \
        *(s16x8*)&lB[b][(bh32 * 2) * 128 + brw32][0] =                        \
            pack8(*(const float4*)q0, *(const float4*)(q0 + 4));              \
        *(s16x8*)&lB[b][(bh32 * 2 + 1) * 128 + brw32][0] =                    \
            pack8(*(const float4*)(q0 + 8), *(const float4*)(q0 + 12));       \
    } else {                                                                  \
        const u16* B16 = (const u16*)Bbase;                                   \
        gload16(B16 + brow0 * ldb + k0_ + bkg0 * 8, &lB[b][tid][0]);          \
        gload16(B16 + brow1 * ldb + k0_ + bkg1 * 8, &lB[b][s1][0]);           \
    }                                                                         \
} while (0)

    const int nk = Ksl / BK;
    STAGE(0, 0);
    __syncthreads();
    int buf = 0;
    const int kg = lane >> 4;
    const int lr = lane & 15;
    for (int kt = 0; kt < nk; ++kt) {
        if (kt + 1 < nk) STAGE(buf ^ 1, kt + 1);
        s16x8 af[4], bfr[2];
#pragma unroll
        for (int m = 0; m < 4; ++m)
            af[m] = *(const s16x8*)&lA[buf][kg * 64 + m * 16 + lr][0];
#pragma unroll
        for (int n = 0; n < 2; ++n)
            bfr[n] = *(const s16x8*)&lB[buf][kg * 128 + wcol + n * 16 + lr][0];
#pragma unroll
        for (int m = 0; m < 4; ++m)
#pragma unroll
            for (int n = 0; n < 2; ++n)
                acc[m][n] = __builtin_amdgcn_mfma_f32_16x16x32_bf16(af[m], bfr[n], acc[m][n], 0, 0, 0);
        __syncthreads();
        buf ^= 1;
    }
#undef STAGE

    const int ccol = lane & 15;
    const int crow = (lane >> 4) * 4;
#pragma unroll
    for (int n = 0; n < 2; ++n) {
        const int c = col0 + wcol + n * 16 + ccol;
        const float bv = bias ? bias[(long)az * sBiasb + c] : 0.f;
#pragma unroll
        for (int m = 0; m < 4; ++m) {
            const int rb = row0 + m * 16 + crow;
#pragma unroll
            for (int q = 0; q < 4; ++q) {
                const int r = rb + q;
                if (r >= M) continue;
                float v = acc[m][n][q] + bv;
                if (act == 1) v = 1.f / (1.f + expf(-v));
                else if (act == 2) v = tanhf(v);
                if (C)  C[(long)z * sCb + (long)r * ldc + c] = v;
                if (Cb) Cb[(long)z * sCbb + (long)r * ldcb + c] = (u16)bh(v);
            }
        }
    }
}

// ============ 128x128-tile fp32-in GEMM (pose / Wnm setup) ============
__global__ __launch_bounds__(256)
void gemm128_f32(const float* __restrict__ A, int lda,
                 const float* __restrict__ Bm, int ldb,
                 float* __restrict__ C, long sCb, int ldc,
                 u16* __restrict__ Cb, int ldcb,
                 int M, int Nn, int K, int ksplit)
{
    __shared__ __align__(16) u16 lA[2][512][8];
    __shared__ __align__(16) u16 lB[2][512][8];

    const int ks = blockIdx.z;
    const int Ksl = K / ksplit;
    const int kbase = ks * Ksl;

    const int tid = threadIdx.x;
    const int lane = tid & 63;
    const int wave = tid >> 6;
    const int row0 = blockIdx.x * 128;
    const int col0 = blockIdx.y * 128;
    const int wrow = (wave >> 1) * 64;
    const int wcol = (wave & 1) * 64;

    // contiguous staging: thread t covers row = t>>1, 64B (16 floats) per step
    const int rw = tid >> 1, hf = tid & 1;
    long ar = row0 + rw; if (ar >= M) ar = M - 1;
    long br = col0 + rw; if (br >= Nn) br = Nn - 1;

    f32x4 acc[4][4] = {};

#define STAGE128(b, kt) do {                                                  \
    const int k0_ = kbase + (kt) * BK;                                        \
    const float* p = A + ar * lda + k0_ + hf * 16;                            \
    *(s16x8*)&lA[b][(hf * 2) * 128 + rw][0] =                                 \
        pack8(*(const float4*)p, *(const float4*)(p + 4));                    \
    *(s16x8*)&lA[b][(hf * 2 + 1) * 128 + rw][0] =                             \
        pack8(*(const float4*)(p + 8), *(const float4*)(p + 12));             \
    const float* q = Bm + br * ldb + k0_ + hf * 16;                           \
    *(s16x8*)&lB[b][(hf * 2) * 128 + rw][0] =                                 \
        pack8(*(const float4*)q, *(const float4*)(q + 4));                    \
    *(s16x8*)&lB[b][(hf * 2 + 1) * 128 + rw][0] =                             \
        pack8(*(const float4*)(q + 8), *(const float4*)(q + 12));             \
} while (0)

    const int nk = Ksl / BK;
    STAGE128(0, 0);
    __syncthreads();
    int buf = 0;
    const int kg = lane >> 4;
    const int lr = lane & 15;
    for (int kt = 0; kt < nk; ++kt) {
        if (kt + 1 < nk) STAGE128(buf ^ 1, kt + 1);
        s16x8 af[4], bfr[4];
#pragma unroll
        for (int m = 0; m < 4; ++m)
            af[m] = *(const s16x8*)&lA[buf][kg * 128 + wrow + m * 16 + lr][0];
#pragma unroll
        for (int n = 0; n < 4; ++n)
            bfr[n] = *(const s16x8*)&lB[buf][kg * 128 + wcol + n * 16 + lr][0];
#pragma unroll
        for (int m = 0; m < 4; ++m)
#pragma unroll
            for (int n = 0; n < 4; ++n)
                acc[m][n] = __builtin_amdgcn_mfma_f32_16x16x32_bf16(af[m], bfr[n], acc[m][n], 0, 0, 0);
        __syncthreads();
        buf ^= 1;
    }
#undef STAGE128

    const int ccol = lane & 15;
    const int crow = (lane >> 4) * 4;
#pragma unroll
    for (int n = 0; n < 4; ++n) {
        const int c = col0 + wcol + n * 16 + ccol;
#pragma unroll
        for (int m = 0; m < 4; ++m) {
            const int rb = row0 + wrow + m * 16 + crow;
#pragma unroll
            for (int q = 0; q < 4; ++q) {
                const int r = rb + q;
                if (r >= M) continue;
                float v = acc[m][n][q];
                if (C)  C[(long)ks * sCb + (long)r * ldc + c] = v;
                if (Cb) Cb[(long)r * ldcb + c] = (u16)bh(v);
            }
        }
    }
}

// ============ fused gh-GEMM + GRU update + score partial (BK=64, XCD swizzle) ============
__global__ __launch_bounds__(256)
void gh_gru(const u16* __restrict__ hb_in, const u16* __restrict__ Whh_b,
            const float* __restrict__ bhh, const float* __restrict__ Gnm,
            const float* __restrict__ cbias,
            float* __restrict__ h, u16* __restrict__ hb_out,
            const float* __restrict__ Wa, float* __restrict__ gs_part, int tt)
{
    __shared__ __align__(16) u16 lA[2][512][8];    // [k16 0..7][row 0..63]
    __shared__ __align__(16) u16 lB[2][1536][8];   // [k16 0..7][gate*64+row]
    __shared__ float rowdot[64];

    const int f = blockIdx.x;
    const int ly = 2 * (f & 7) + ((f >> 3) & 1);   // 0..15 col-tile
    const int lx = f >> 4;                          // 0..31 row-tile
    const int row0 = lx * 64;
    const int col0 = ly * 64;

    const int tid = threadIdx.x;
    const int lane = tid & 63;
    const int wave = tid >> 6;
    const int wr = wave >> 1;
    const int wc = wave & 1;

    long arow = row0 + (tid & 63); if (arow >= NROWS) arow = NROWS - 1;

    // hoisted staging pointers (constant across K-loop; only +64 per step)
    const u16* aP0 = hb_in + arow * SQ + (tid >> 6) * 8;
    const u16* aP1 = aP0 + 32;
    const u16* bP[6];
#pragma unroll
    for (int j = 0; j < 6; ++j) {
        const int s = tid + j * 256;
        const int bk16 = s / 192;
        const int grow = s - bk16 * 192;
        bP[j] = Whh_b + (long)((grow >> 6) * SQ + col0 + (grow & 63)) * SQ + bk16 * 8;
    }

    f32x4 acc[3][2][2] = {};

#define GSTAGE(b, kt) do {                                                    \
    const int k0_ = (kt) * 64;                                                \
    gload16(aP0 + k0_, &lA[b][tid][0]);                                       \
    gload16(aP1 + k0_, &lA[b][tid + 256][0]);                                 \
    _Pragma("unroll")                                                         \
    for (int j = 0; j < 6; ++j)                                               \
        gload16(bP[j] + k0_, &lB[b][tid + j * 256][0]);                       \
} while (0)

    GSTAGE(0, 0);
    __syncthreads();
    int buf = 0;
    const int kg = lane >> 4;
    const int lr = lane & 15;
    for (int kt = 0; kt < 16; ++kt) {
        if (kt + 1 < 16) GSTAGE(buf ^ 1, kt + 1);
#pragma unroll
        for (int kk = 0; kk < 2; ++kk) {
            const int k16 = kk * 4 + kg;
            s16x8 af[2], bfr[3][2];
#pragma unroll
            for (int m = 0; m < 2; ++m)
                af[m] = *(const s16x8*)&lA[buf][k16 * 64 + wr * 32 + m * 16 + lr][0];
#pragma unroll
            for (int g = 0; g < 3; ++g)
#pragma unroll
                for (int n = 0; n < 2; ++n)
                    bfr[g][n] = *(const s16x8*)&lB[buf][k16 * 192 + g * 64 + wc * 32 + n * 16 + lr][0];
#pragma unroll
            for (int g = 0; g < 3; ++g)
#pragma unroll
                for (int m = 0; m < 2; ++m)
#pragma unroll
                    for (int n = 0; n < 2; ++n)
                        acc[g][m][n] = __builtin_amdgcn_mfma_f32_16x16x32_bf16(af[m], bfr[g][n], acc[g][m][n], 0, 0, 0);
        }
        __syncthreads();
        buf ^= 1;
    }
#undef GSTAGE

    if (tid < 64) rowdot[tid] = 0.f;
    __syncthreads();

    const int ccol = lane & 15;
    const int crow4 = (lane >> 4) * 4;
    int col2[2];
    float cbv[3][2], bhv[3][2];
#pragma unroll
    for (int n = 0; n < 2; ++n) {
        const int c = col0 + wc * 32 + n * 16 + ccol;
        col2[n] = c;
#pragma unroll
        for (int g = 0; g < 3; ++g) {
            cbv[g][n] = cbias[g * SQ + c];
            bhv[g][n] = bhh[g * SQ + c];
        }
    }

#pragma unroll
    for (int m = 0; m < 2; ++m) {
#pragma unroll
        for (int q = 0; q < 4; ++q) {
            const int row = row0 + wr * 32 + m * 16 + crow4 + q;
            const bool valid = (row < NROWS);
            float d = 0.f;
            if (valid) {
                const int e = row / BNN;
                const int rr = row - e * BNN;
                const int b_ = rr / 144;
                const int ni = (rr / 12) % 12;
                const int mi = rr % 12;
                const int bt = b_ * TQ + tt;
                const float* gnp = Gnm + ((long)e * 96 + bt * 12 + ni) * 6144;
                const float* gmp = Gnm + ((long)e * 96 + bt * 12 + mi) * 6144 + G3S;
                const float* wap = Wa + (long)e * SQ;
#pragma unroll
                for (int n = 0; n < 2; ++n) {
                    const int c = col2[n];
                    float gr  = acc[0][m][n][q] + bhv[0][n] + gnp[c] + gmp[c] + cbv[0][n];
                    float gz  = acc[1][m][n][q] + bhv[1][n] + gnp[SQ + c] + gmp[SQ + c] + cbv[1][n];
                    float ghn = acc[2][m][n][q] + bhv[2][n];
                    float gin = gnp[2 * SQ + c] + gmp[2 * SQ + c] + cbv[2][n];
                    float rg = sigmoidf(gr);
                    float zg = sigmoidf(gz);
                    float nn2 = tanhf(gin + rg * ghn);
                    float hp = h[(long)row * SQ + c];
                    float hn = (1.f - zg) * nn2 + zg * hp;
                    h[(long)row * SQ + c] = hn;
                    hb_out[(long)row * SQ + c] = (u16)bh(hn);
                    d += hn * wap[c];
                }
            }
            d += __shfl_xor(d, 1); d += __shfl_xor(d, 2);
            d += __shfl_xor(d, 4); d += __shfl_xor(d, 8);
            if (valid && ccol == 0)
                atomicAdd(&rowdot[wr * 32 + m * 16 + crow4 + q], d);
        }
    }
    __syncthreads();
    if (tid < 64) {
        const int row = row0 + tid;
        if (row < NROWS) gs_part[((long)tt * 2048 + row) * 16 + ly] = rowdot[tid];
    }
}

// ============ GRU step tt=0, elementwise (h0 ~ 0: gh0 = bhh; h1 = (1-z)*n) ============
__global__ __launch_bounds__(256)
void gru0(const float* __restrict__ Gnm, const float* __restrict__ cbias,
          const float* __restrict__ bhh,
          float* __restrict__ h, u16* __restrict__ hb_out,
          const float* __restrict__ Wa, const float* __restrict__ ba,
          float* __restrict__ gs)
{
    const int row = blockIdx.x;            // 0..2015 : e*288 + b*144 + n*12 + m
    const int e = row / BNN;
    const int r = row % BNN;
    const int b_ = r / 144;
    const int ni = (r / 12) % 12;
    const int mi = r % 12;
    const int bt = b_ * TQ;                // tt = 0

    const float* gnp = Gnm + ((long)e * 96 + bt * 12 + ni) * 6144;
    const float* gmp = Gnm + ((long)e * 96 + bt * 12 + mi) * 6144 + G3S;
    float* hp = h + (long)row * SQ;
    u16* hpb = hb_out + (long)row * SQ;

    const int s = threadIdx.x * 4;

    float4 gnR = *(const float4*)(gnp + s);
    float4 gnZ = *(const float4*)(gnp + SQ + s);
    float4 gnN = *(const float4*)(gnp + 2 * SQ + s);
    float4 gmR = *(const float4*)(gmp + s);
    float4 gmZ = *(const float4*)(gmp + SQ + s);
    float4 gmN = *(const float4*)(gmp + 2 * SQ + s);
    float4 cbR = *(const float4*)(cbias + s);
    float4 cbZ = *(const float4*)(cbias + SQ + s);
    float4 cbN = *(const float4*)(cbias + 2 * SQ + s);
    float4 bhR = *(const float4*)(bhh + s);
    float4 bhZ = *(const float4*)(bhh + SQ + s);
    float4 bhN = *(const float4*)(bhh + 2 * SQ + s);
    float4 wv  = *(const float4*)(Wa + (long)e * SQ + s);

    float4 hn4;
    float dot = 0.f;

#define GRU0_COMP(c)                                                \
    {                                                               \
        float rg = sigmoidf(gnR.c + gmR.c + cbR.c + bhR.c);         \
        float zg = sigmoidf(gnZ.c + gmZ.c + cbZ.c + bhZ.c);         \
        float nn = tanhf(gnN.c + gmN.c + cbN.c + rg * bhN.c);       \
        float hn = (1.f - zg) * nn;                                 \
        hn4.c = hn;                                                 \
        dot += hn * wv.c;                                           \
    }
    GRU0_COMP(x) GRU0_COMP(y) GRU0_COMP(z) GRU0_COMP(w)
#undef GRU0_COMP

    *(float4*)(hp + s) = hn4;
    ushort4 hb4;
    hb4.x = (u16)bh(hn4.x); hb4.y = (u16)bh(hn4.y);
    hb4.z = (u16)bh(hn4.z); hb4.w = (u16)bh(hn4.w);
    *(ushort4*)(hpb + s) = hb4;

    for (int off = 32; off > 0; off >>= 1) dot += __shfl_down(dot, off);
    __shared__ float red[4];
    if ((threadIdx.x & 63) == 0) red[threadIdx.x >> 6] = dot;
    __syncthreads();
    if (threadIdx.x == 0) {
        float tot = red[0] + red[1] + red[2] + red[3] + ba[e];
        gs[((bt * 12 + ni) * 12 + mi) * EQ + e] = sigmoidf(tot);
    }
}

// ---------- gs finalize for tt=1..3: sum 16 partials + ba -> sigmoid ----------
__global__ void gs_fin_all(const float* __restrict__ gs_part, const float* __restrict__ ba,
                           float* __restrict__ gs)
{
    int idx = blockIdx.x * 256 + threadIdx.x;   // 0..6143
    if (idx >= 3 * 2048) return;
    const int tt = 1 + (idx >> 11);
    const int row = idx & 2047;
    if (row >= NROWS) return;
    float s = 0.f;
#pragma unroll
    for (int j = 0; j < 16; ++j) s += gs_part[((long)tt * 2048 + row) * 16 + j];
    const int e = row / BNN;
    const int rr = row - e * BNN;
    const int b_ = rr / 144;
    const int ni = (rr / 12) % 12;
    const int mi = rr % 12;
    const int bt = b_ * TQ + tt;
    gs[((bt * 12 + ni) * 12 + mi) * EQ + e] = sigmoidf(s + ba[e]);
}

// ---------- generic split-K reduce ----------
__global__ __launch_bounds__(256)
void reduce_k(const float* __restrict__ part, int ksplit, int mn, int Nn,
              const float* __restrict__ bias, long sBiasB, int act,
              float* __restrict__ Cf, long sCfB, int ldcf,
              u16* __restrict__ Cb, long sCbB, int ldcb)
{
    int i4 = blockIdx.x * 256 + threadIdx.x;
    int total4 = mn >> 2;
    if (i4 >= total4) return;
    int b = blockIdx.y;
    const float4* p4 = (const float4*)part;
    float4 s = make_float4(0.f, 0.f, 0.f, 0.f);
    for (int ks = 0; ks < ksplit; ++ks) {
        float4 v = p4[(long)(b * ksplit + ks) * total4 + i4];
        s.x += v.x; s.y += v.y; s.z += v.z; s.w += v.w;
    }
    int i = i4 << 2;
    int r = i / Nn, c = i % Nn;
    if (bias) {
        float4 bv = *(const float4*)(bias + (long)b * sBiasB + c);
        s.x += bv.x; s.y += bv.y; s.z += bv.z; s.w += bv.w;
    }
    if (act == 1) {
        s.x = sigmoidf(s.x); s.y = sigmoidf(s.y); s.z = sigmoidf(s.z); s.w = sigmoidf(s.w);
    } else if (act == 2) {
        s.x = tanhf(s.x); s.y = tanhf(s.y); s.z = tanhf(s.z); s.w = tanhf(s.w);
    }
    if (Cf) *(float4*)(Cf + (long)b * sCfB + (long)r * ldcf + c) = s;
    if (Cb) {
        ushort4 o;
        o.x = (u16)bh(s.x); o.y = (u16)bh(s.y); o.z = (u16)bh(s.z); o.w = (u16)bh(s.w);
        *(ushort4*)(Cb + (long)b * sCbB + (long)r * ldcb + c) = o;
    }
}

__global__ void cvt_bf16_k(const float* __restrict__ src, u16* __restrict__ dst, int n4)
{
    int i = blockIdx.x * 256 + threadIdx.x;
    if (i >= n4) return;
    float4 v = ((const float4*)src)[i];
    ushort4 o;
    o.x = (u16)bh(v.x); o.y = (u16)bh(v.y); o.z = (u16)bh(v.z); o.w = (u16)bh(v.w);
    ((ushort4*)dst)[i] = o;
}

__global__ __launch_bounds__(256)
void transpose_wc(const float* __restrict__ Wcomp, float* __restrict__ W1T, float* __restrict__ W2T)
{
    __shared__ float t1[32][33];
    __shared__ float t2[32][33];
    const int tx = threadIdx.x & 31;
    const int ty = threadIdx.x >> 5;
    const int d0 = blockIdx.x * 32;
    const int s0 = blockIdx.y * 32;
#pragma unroll
    for (int k = 0; k < 4; ++k) {
        int d = d0 + ty + k * 8;
        t1[ty + k * 8][tx] = Wcomp[(long)d * 2048 + s0 + tx];
        t2[ty + k * 8][tx] = Wcomp[(long)d * 2048 + 1024 + s0 + tx];
    }
    __syncthreads();
#pragma unroll
    for (int k = 0; k < 4; ++k) {
        int s = s0 + ty + k * 8;
        W1T[(long)s * 1024 + d0 + tx] = t1[tx][ty + k * 8];
        W2T[(long)s * 1024 + d0 + tx] = t2[tx][ty + k * 8];
    }
}

__global__ void pack_rz(const float* __restrict__ Wr, const float* __restrict__ Wz,
                        const float* __restrict__ br, const float* __restrict__ bz,
                        u16* __restrict__ Wrz, float* __restrict__ brz)
{
    int i4 = blockIdx.x * 256 + threadIdx.x;
    if (i4 < 512) {
        int c = i4 * 4;
        float4 b = (c < 1024) ? *(const float4*)(br + c) : *(const float4*)(bz + c - 1024);
        *(float4*)(brz + c) = b;
    }
    if (i4 >= 1048576) return;
    int i = i4 * 4;
    int j = i >> 11;
    int c = i & 2047;
    float4 v = (j < 1024) ? *(const float4*)(Wr + (long)j * 2048 + c)
                          : *(const float4*)(Wz + (long)(j - 1024) * 2048 + c);
    ushort4 o;
    o.x = (u16)bh(v.x); o.y = (u16)bh(v.y); o.z = (u16)bh(v.z); o.w = (u16)bh(v.w);
    *(ushort4*)(Wrz + i) = o;
}

__global__ void cbias_k(const float* __restrict__ Wih, const float* __restrict__ bih,
                        const float* __restrict__ bcomp, float* __restrict__ cbias)
{
    int g = blockIdx.x * blockDim.x + threadIdx.x;
    if (g >= G3S) return;
    const float* w = Wih + (long)g * SQ;
    float s = 0.f;
    for (int k = 0; k < SQ; k += 4) {
        float4 wv = *(const float4*)(w + k);
        float4 bv = *(const float4*)(bcomp + k);
        s += wv.x * bv.x + wv.y * bv.y + wv.z * bv.z + wv.w * bv.w;
    }
    cbias[g] = s + bih[g];
}

// ---------------- merged + amat fused ----------------
__global__ __launch_bounds__(256)
void merged_amat_k(const float* __restrict__ gs, const u16* __restrict__ msgs_b,
                   const float* __restrict__ prop, u16* __restrict__ amat_b)
{
    const int bn = blockIdx.x;   // 0..95
    const int bt = bn / 12;
    __shared__ float g[84];
    if (threadIdx.x < 84) g[threadIdx.x] = gs[bn * 84 + threadIdx.x];
    __syncthreads();
    const int s = threadIdx.x * 4;
    float4 acc = make_float4(0.f, 0.f, 0.f, 0.f);
    for (int j = 0; j < 84; ++j) {
        const ushort4 mv = *(const ushort4*)(msgs_b + ((long)(bt * 84 + j)) * SQ + s);
        float gj = g[j];
        acc.x += gj * b2f(mv.x);
        acc.y += gj * b2f(mv.y);
        acc.z += gj * b2f(mv.z);
        acc.w += gj * b2f(mv.w);
    }
    ushort4 o;
    o.x = (u16)bh(acc.x); o.y = (u16)bh(acc.y); o.z = (u16)bh(acc.z); o.w = (u16)bh(acc.w);
    *(ushort4*)(amat_b + (long)bn * 2048 + s) = o;
    float4 pv = *(const float4*)(prop + (long)bn * SQ + s);
    ushort4 o2;
    o2.x = (u16)bh(pv.x); o2.y = (u16)bh(pv.y); o2.z = (u16)bh(pv.z); o2.w = (u16)bh(pv.w);
    *(ushort4*)(amat_b + (long)bn * 2048 + 1024 + s) = o2;
}

__global__ void ahat_k(const float* __restrict__ rz, const float* __restrict__ prop,
                       u16* __restrict__ amat_b)
{
    int i = blockIdx.x * 256 + threadIdx.x;
    int rrow = i >> 10, c = i & 1023;
    float r = rz[(long)rrow * 2048 + c];
    amat_b[(long)rrow * 2048 + 1024 + c] = (u16)bh(r * prop[i]);
}

__global__ void propupd_k(const float* __restrict__ rz, const float* __restrict__ hhat,
                          float* __restrict__ prop, u16* __restrict__ prop_b)
{
    int i = blockIdx.x * 256 + threadIdx.x;
    int rrow = i >> 10, c = i & 1023;
    float z = rz[(long)rrow * 2048 + 1024 + c];
    float v = (1.f - z) * prop[i] + z * hhat[i];
    prop[i] = v;
    prop_b[i] = (u16)bh(v);
}

// ---------------- final outputs ----------------
__global__ __launch_bounds__(256)
void outputs_k(const float* __restrict__ gs, float* __restrict__ out)
{
    __shared__ float s_act[672];
    __shared__ float s_asum[96];
    int tid = threadIdx.x;
    for (int idx = tid; idx < 672; idx += 256) {
        int bn = idx / 7, e = idx % 7;
        float sum = 0.f;
        for (int m = 0; m < 12; ++m) {
            float g0 = gs[bn * 84 + m * 7];
            sum += (1.f - g0) * gs[bn * 84 + m * 7 + e];
        }
        s_act[idx] = sum;
        out[idx] = sum;
    }
    for (int idx = tid; idx < 96; idx += 256) {
        float a = 0.f;
        for (int m = 0; m < 12; ++m) a += 1.f - gs[idx * 84 + m * 7];
        s_asum[idx] = a;
    }
    for (int idx = tid; idx < 1152; idx += 256) {
        int bn = idx / 12, m = idx % 12;
        out[720 + idx] = 1.f - gs[bn * 84 + m * 7];
    }
    __syncthreads();
    if (tid < 8) {
        float tmp[6];
        float mx = -1e30f;
        for (int e = 1; e < 7; ++e) {
            float sum = 0.f;
            for (int n = 0; n < 12; ++n) {
                int bn = tid * 12 + n;
                sum += s_act[bn * 7 + e] * s_asum[bn];
            }
            tmp[e - 1] = sum;
            mx = fmaxf(mx, sum);
        }
        float den = 0.f;
        for (int e = 0; e < 6; ++e) { tmp[e] = expf(tmp[e] - mx); den += tmp[e]; }
        for (int e = 0; e < 6; ++e) out[672 + tid * 6 + e] = tmp[e] / den;
    }
}

// ---------------- host ----------------
template<int AS32, int BS32>
static void launch_gemm(const void* A, long sAb, int lda,
                        const void* B, long sBb, int ldb,
                        const float* bias, long sBiasb,
                        float* C, long sCb, int ldc,
                        u16* Cb, long sCbb, int ldcb,
                        int M, int Nn, int K, int act, int batch, int ksplit,
                        hipStream_t stream)
{
    dim3 grid((M + 63) / 64, (Nn + 127) / 128, batch * ksplit);
    gemm_mfma<AS32, BS32><<<grid, dim3(256), 0, stream>>>(
        A, sAb, lda, B, sBb, ldb, bias, sBiasb, C, sCb, ldc, Cb, sCbb, ldcb,
        M, Nn, K, act, ksplit);
}

extern "C" void kernel_launch(void* const* d_in, const int* in_sizes, int n_in,
                              void* d_out, int out_size, void* d_ws, size_t ws_size,
                              hipStream_t stream)
{
    const float* pose  = (const float*)d_in[0];
    const float* Wc    = (const float*)d_in[5];
    const float* bc    = (const float*)d_in[6];
    const float* We    = (const float*)d_in[7];
    const float* be    = (const float*)d_in[8];
    const float* Wcomp = (const float*)d_in[9];
    const float* bcomp = (const float*)d_in[10];
    const float* Wr    = (const float*)d_in[11];
    const float* br    = (const float*)d_in[12];
    const float* Wz    = (const float*)d_in[13];
    const float* bz    = (const float*)d_in[14];
    const float* Wh    = (const float*)d_in[15];
    const float* bh_   = (const float*)d_in[16];
    const float* Wih   = (const float*)d_in[17];
    const float* Whh   = (const float*)d_in[18];
    const float* bih   = (const float*)d_in[19];
    const float* bhh   = (const float*)d_in[20];
    const float* Wa    = (const float*)d_in[21];
    const float* ba    = (const float*)d_in[22];

    float* ws = (float*)d_ws;
    // fp32 region
    float* prop    = ws;                    // 98304
    float* cbias   = prop + 98304;          // 3072
    float* h       = cbias + 3072;          // 2064384
    float* Gnm     = h + 2064384;           // 4128768  (7 x 96 x 6144)
    float* scratch = Gnm + 4128768;         // 8257536  (split-K partials / W1T/W2T)
    float* gs      = scratch + 8257536;     // 8064
    float* rz      = gs + 8064;             // 196608
    float* hhat    = rz + 196608;           // 98304
    float* brz     = hhat + 98304;          // 2048
    float* gs_part = brz + 2048;            // 131072 (4 x 2048 x 16)
    float* fend    = gs_part + 131072;
    // bf16 region
    u16* Whh_b  = (u16*)fend;               // 3145728
    u16* Wnm_b  = Whh_b + 3145728;          // 6291456  (6144 x 1024)
    u16* Wrz_b  = Wnm_b + 6291456;          // 4194304
    u16* msgs_b = Wrz_b + 4194304;          // 688128
    u16* h_b0   = msgs_b + 688128;          // 2064384
    u16* h_b1   = h_b0 + 2064384;           // 2064384
    u16* prop_b = h_b1 + 2064384;           // 98304
    u16* amat_b = prop_b + 98304;           // 196608

    float* W1T = scratch;                   // transient
    float* W2T = scratch + 1048576;         // transient

    // ---- once per call ----
    hipLaunchKernelGGL(cvt_bf16_k, dim3(3072), dim3(256), 0, stream, Whh, Whh_b, 786432);
    hipLaunchKernelGGL(cbias_k, dim3(12), dim3(256), 0, stream, Wih, bih, bcomp, cbias);
    hipLaunchKernelGGL(transpose_wc, dim3(32, 32), dim3(256), 0, stream, Wcomp, W1T, W2T);
    hipLaunchKernelGGL(pack_rz, dim3(4096), dim3(256), 0, stream, Wr, Wz, br, bz, Wrz_b, brz);
    // Wnm rows 0..3071 = Wih @ W1T^T ; rows 3072..6143 = Wih @ W2T^T
    gemm128_f32<<<dim3(24, 8, 1), dim3(256), 0, stream>>>(
        Wih, SQ, W1T, SQ, nullptr, 0, SQ, Wnm_b, SQ, G3S, SQ, SQ, 1);
    gemm128_f32<<<dim3(24, 8, 1), dim3(256), 0, stream>>>(
        Wih, SQ, W2T, SQ, nullptr, 0, SQ, Wnm_b + (long)G3S * SQ, SQ, G3S, SQ, SQ, 1);
    // prop = pose @ Wc^T + bc : ksplit=75 (Ksl=352, 600 blocks)
    gemm128_f32<<<dim3(1, 8, 75), dim3(256), 0, stream>>>(
        pose, DIN, Wc, DIN, scratch, 98304, SQ, nullptr, SQ, 96, SQ, DIN, 75);
    hipLaunchKernelGGL(reduce_k, dim3(96, 1), dim3(256), 0, stream,
                       scratch, 75, 98304, SQ, bc, 0L, 0,
                       prop, 0L, SQ, prop_b, 0L, SQ);

    for (int t = 0; t <= TSQ; ++t) {
        // msgs[bt,n,e,s] = prop @ We[e]^T + be[e] : batch 7, ksplit 4
        launch_gemm<0, 1>(prop_b, 0, SQ, We, (long)SQ * SQ, SQ, nullptr, 0,
                          scratch, 98304, SQ, nullptr, 0, 0, 96, SQ, SQ, 0, EQ, 4, stream);
        hipLaunchKernelGGL(reduce_k, dim3(96, EQ), dim3(256), 0, stream,
                           scratch, 4, 98304, SQ, be, (long)SQ, 0,
                           (float*)nullptr, 0L, 0, msgs_b, (long)SQ, EQ * SQ);
        // Gnm = msgs_e @ Wnm^T : batch 7, direct write
        launch_gemm<0, 0>(msgs_b, SQ, EQ * SQ, Wnm_b, 0, SQ, nullptr, 0,
                          Gnm, 589824, 6 * SQ, nullptr, 0, 0, 96, 6 * SQ, SQ, 0, EQ, 1, stream);
        // GRU scan: tt=0 is pure elementwise (h0 ~ 0), then 3 fused GEMM steps
        hipLaunchKernelGGL(gru0, dim3(NROWS), dim3(256), 0, stream,
                           Gnm, cbias, bhh, h, h_b0, Wa, ba, gs);
        for (int tt = 1; tt < TQ; ++tt) {
            const u16* hin = (tt & 1) ? h_b0 : h_b1;
            u16* hout = (tt & 1) ? h_b1 : h_b0;
            hipLaunchKernelGGL(gh_gru, dim3(512), dim3(256), 0, stream,
                               hin, Whh_b, bhh, Gnm, cbias, h, hout, Wa, gs_part, tt);
        }
        hipLaunchKernelGGL(gs_fin_all, dim3(24), dim3(256), 0, stream, gs_part, ba, gs);
        if (t < TSQ) {
            hipLaunchKernelGGL(merged_amat_k, dim3(96), dim3(256), 0, stream,
                               gs, msgs_b, prop, amat_b);
            // rz = sigmoid(amat @ [Wr;Wz]^T + brz) : ksplit=8
            launch_gemm<0, 0>(amat_b, 0, 2 * SQ, Wrz_b, 0, 2 * SQ, nullptr, 0,
                              scratch, 196608, 2 * SQ, nullptr, 0, 0, 96, 2 * SQ, 2 * SQ, 0, 1, 8, stream);
            hipLaunchKernelGGL(reduce_k, dim3(192, 1), dim3(256), 0, stream,
                               scratch, 8, 196608, 2 * SQ, brz, 0L, 1,
                               rz, 0L, 2 * SQ, (u16*)nullptr, 0L, 0);
            hipLaunchKernelGGL(ahat_k, dim3(384), dim3(256), 0, stream, rz, prop, amat_b);
            // hhat = tanh(amat @ Wh^T + bh) : ksplit=8
            launch_gemm<0, 1>(amat_b, 0, 2 * SQ, Wh, 0, 2 * SQ, nullptr, 0,
                              scratch, 98304, SQ, nullptr, 0, 0, 96, SQ, 2 * SQ, 0, 1, 8, stream);
            hipLaunchKernelGGL(reduce_k, dim3(96, 1), dim3(256), 0, stream,
                               scratch, 8, 98304, SQ, bh_, 0L, 2,
                               hhat, 0L, SQ, (u16*)nullptr, 0L, 0);
            hipLaunchKernelGGL(propupd_k, dim3(384), dim3(256), 0, stream, rz, hhat, prop, prop_b);
        }
    }

    hipLaunchKernelGGL(outputs_k, dim3(1), dim3(256), 0, stream, gs, (float*)d_out);
}

// Round 7
// 1180.858 us; speedup vs baseline: 5.0879x; 1.0601x over previous
//
#include <hip/hip_runtime.h>
#include <math.h>

// Problem constants
#define NQ 12
#define EQ 7
#define SQ 1024
#define TSQ 3
#define DIN 26400
#define BQ 2
#define TQ 4
#define BT 8          // B*T
#define BNN 288       // B*N*N
#define NROWS 2016    // E*BNN
#define G3S 3072      // 3*S
#define BK 32

typedef unsigned short u16;
typedef float f32x4 __attribute__((ext_vector_type(4)));
typedef short s16x8 __attribute__((ext_vector_type(8)));

__device__ __forceinline__ short bh(float f) {
    unsigned u = __float_as_uint(f);
    return (short)((u + 0x8000u) >> 16);
}
__device__ __forceinline__ float b2f(u16 u) {
    return __uint_as_float((unsigned)u << 16);
}
__device__ __forceinline__ s16x8 pack8(float4 a, float4 b) {
    s16x8 r;
    r[0] = bh(a.x); r[1] = bh(a.y); r[2] = bh(a.z); r[3] = bh(a.w);
    r[4] = bh(b.x); r[5] = bh(b.y); r[6] = bh(b.z); r[7] = bh(b.w);
    return r;
}
__device__ __forceinline__ void gload16(const void* g, void* l) {
    __builtin_amdgcn_global_load_lds(
        (const __attribute__((address_space(1))) unsigned*)g,
        (__attribute__((address_space(3))) unsigned*)l, 16, 0, 0);
}
__device__ inline float sigmoidf(float x) { return 1.f / (1.f + expf(-x)); }

// ================= bf16 MFMA GEMM, 64x128 tile: C = A(MxK) * B(NxK)^T =================
template<int AS32, int BS32>
__global__ __launch_bounds__(256)
void gemm_mfma(const void* __restrict__ Ap, long sAb, int lda,
               const void* __restrict__ Bp, long sBb, int ldb,
               const float* __restrict__ bias, long sBiasb,
               float* __restrict__ C, long sCb, int ldc,
               u16* __restrict__ Cb, long sCbb, int ldcb,
               int M, int Nn, int K, int act, int ksplit)
{
    __shared__ __align__(16) u16 lA[2][256][8];
    __shared__ __align__(16) u16 lB[2][512][8];

    const int z = blockIdx.z;
    const int az = z / ksplit;
    const int ks = z - az * ksplit;
    const int Ksl = K / ksplit;
    const int kbase = ks * Ksl;

    const char* Abase = (const char*)Ap + (long)az * sAb * (AS32 ? 4 : 2);
    const char* Bbase = (const char*)Bp + (long)az * sBb * (BS32 ? 4 : 2);

    const int tid = threadIdx.x;
    const int lane = tid & 63;
    const int wave = tid >> 6;
    const int row0 = blockIdx.x * 64;
    const int col0 = blockIdx.y * 128;
    const int wcol = wave * 32;

    // bf16 staging indices (16B/lane, wave-uniform LDS dest)
    const int akg = tid >> 6;
    long arow = row0 + (tid & 63); if (arow >= M) arow = M - 1;
    const int bkg0 = tid >> 7;
    const int s1 = tid + 256;
    const int bkg1 = s1 >> 7;
    long brow0 = col0 + (tid & 127); if (brow0 >= Nn) brow0 = Nn - 1;
    long brow1 = col0 + (s1 & 127);  if (brow1 >= Nn) brow1 = Nn - 1;

    // fp32 staging indices (contiguous bursts)
    const int arw32 = tid >> 2, akg32 = tid & 3;
    long ar32 = row0 + arw32; if (ar32 >= M) ar32 = M - 1;
    const int brw32 = tid >> 1, bh32 = tid & 1;
    long br32 = col0 + brw32; if (br32 >= Nn) br32 = Nn - 1;

    f32x4 acc[4][2] = {};

#define STAGE(b, kt) do {                                                     \
    const int k0_ = kbase + (kt) * BK;                                        \
    if constexpr (AS32) {                                                     \
        const float* A32 = (const float*)Abase;                               \
        const float* p0 = A32 + ar32 * lda + k0_ + akg32 * 8;                 \
        *(s16x8*)&lA[b][akg32 * 64 + arw32][0] =                              \
            pack8(*(const float4*)p0, *(const float4*)(p0 + 4));              \
    } else {                                                                  \
        const u16* A16 = (const u16*)Abase;                                   \
        gload16(A16 + arow * lda + k0_ + akg * 8, &lA[b][tid][0]);            \
    }                                                                         \
    if constexpr (BS32) {                                                     \
        const float* B32 = (const float*)Bbase;                               \
        const float* q0 = B32 + br32 * ldb + k0_ + bh32 * 16;                 \
        *(s16x8*)&lB[b][(bh32 * 2) * 128 + brw32][0] =                        \
            pack8(*(const float4*)q0, *(const float4*)(q0 + 4));              \
        *(s16x8*)&lB[b][(bh32 * 2 + 1) * 128 + brw32][0] =                    \
            pack8(*(const float4*)(q0 + 8), *(const float4*)(q0 + 12));       \
    } else {                                                                  \
        const u16* B16 = (const u16*)Bbase;                                   \
        gload16(B16 + brow0 * ldb + k0_ + bkg0 * 8, &lB[b][tid][0]);          \
        gload16(B16 + brow1 * ldb + k0_ + bkg1 * 8, &lB[b][s1][0]);           \
    }                                                                         \
} while (0)

    const int nk = Ksl / BK;
    STAGE(0, 0);
    __syncthreads();
    int buf = 0;
    const int kg = lane >> 4;
    const int lr = lane & 15;
    for (int kt = 0; kt < nk; ++kt) {
        if (kt + 1 < nk) STAGE(buf ^ 1, kt + 1);
        s16x8 af[4], bfr[2];
#pragma unroll
        for (int m = 0; m < 4; ++m)
            af[m] = *(const s16x8*)&lA[buf][kg * 64 + m * 16 + lr][0];
#pragma unroll
        for (int n = 0; n < 2; ++n)
            bfr[n] = *(const s16x8*)&lB[buf][kg * 128 + wcol + n * 16 + lr][0];
#pragma unroll
        for (int m = 0; m < 4; ++m)
#pragma unroll
            for (int n = 0; n < 2; ++n)
                acc[m][n] = __builtin_amdgcn_mfma_f32_16x16x32_bf16(af[m], bfr[n], acc[m][n], 0, 0, 0);
        __syncthreads();
        buf ^= 1;
    }
#undef STAGE

    const int ccol = lane & 15;
    const int crow = (lane >> 4) * 4;
#pragma unroll
    for (int n = 0; n < 2; ++n) {
        const int c = col0 + wcol + n * 16 + ccol;
        const float bv = bias ? bias[(long)az * sBiasb + c] : 0.f;
#pragma unroll
        for (int m = 0; m < 4; ++m) {
            const int rb = row0 + m * 16 + crow;
#pragma unroll
            for (int q = 0; q < 4; ++q) {
                const int r = rb + q;
                if (r >= M) continue;
                float v = acc[m][n][q] + bv;
                if (act == 1) v = 1.f / (1.f + expf(-v));
                else if (act == 2) v = tanhf(v);
                if (C)  C[(long)z * sCb + (long)r * ldc + c] = v;
                if (Cb) Cb[(long)z * sCbb + (long)r * ldcb + c] = (u16)bh(v);
            }
        }
    }
}

// ============ 128x128-tile fp32-in GEMM (Wnm setup) ============
__global__ __launch_bounds__(256)
void gemm128_f32(const float* __restrict__ A, int lda,
                 const float* __restrict__ Bm, int ldb,
                 float* __restrict__ C, long sCb, int ldc,
                 u16* __restrict__ Cb, int ldcb,
                 int M, int Nn, int K, int ksplit)
{
    __shared__ __align__(16) u16 lA[2][512][8];
    __shared__ __align__(16) u16 lB[2][512][8];

    const int ks = blockIdx.z;
    const int Ksl = K / ksplit;
    const int kbase = ks * Ksl;

    const int tid = threadIdx.x;
    const int lane = tid & 63;
    const int wave = tid >> 6;
    const int row0 = blockIdx.x * 128;
    const int col0 = blockIdx.y * 128;
    const int wrow = (wave >> 1) * 64;
    const int wcol = (wave & 1) * 64;

    const int rw = tid >> 1, hf = tid & 1;
    long ar = row0 + rw; if (ar >= M) ar = M - 1;
    long br = col0 + rw; if (br >= Nn) br = Nn - 1;

    f32x4 acc[4][4] = {};

#define STAGE128(b, kt) do {                                                  \
    const int k0_ = kbase + (kt) * BK;                                        \
    const float* p = A + ar * lda + k0_ + hf * 16;                            \
    *(s16x8*)&lA[b][(hf * 2) * 128 + rw][0] =                                 \
        pack8(*(const float4*)p, *(const float4*)(p + 4));                    \
    *(s16x8*)&lA[b][(hf * 2 + 1) * 128 + rw][0] =                             \
        pack8(*(const float4*)(p + 8), *(const float4*)(p + 12));             \
    const float* q = Bm + br * ldb + k0_ + hf * 16;                           \
    *(s16x8*)&lB[b][(hf * 2) * 128 + rw][0] =                                 \
        pack8(*(const float4*)q, *(const float4*)(q + 4));                    \
    *(s16x8*)&lB[b][(hf * 2 + 1) * 128 + rw][0] =                             \
        pack8(*(const float4*)(q + 8), *(const float4*)(q + 12));             \
} while (0)

    const int nk = Ksl / BK;
    STAGE128(0, 0);
    __syncthreads();
    int buf = 0;
    const int kg = lane >> 4;
    const int lr = lane & 15;
    for (int kt = 0; kt < nk; ++kt) {
        if (kt + 1 < nk) STAGE128(buf ^ 1, kt + 1);
        s16x8 af[4], bfr[4];
#pragma unroll
        for (int m = 0; m < 4; ++m)
            af[m] = *(const s16x8*)&lA[buf][kg * 128 + wrow + m * 16 + lr][0];
#pragma unroll
        for (int n = 0; n < 4; ++n)
            bfr[n] = *(const s16x8*)&lB[buf][kg * 128 + wcol + n * 16 + lr][0];
#pragma unroll
        for (int m = 0; m < 4; ++m)
#pragma unroll
            for (int n = 0; n < 4; ++n)
                acc[m][n] = __builtin_amdgcn_mfma_f32_16x16x32_bf16(af[m], bfr[n], acc[m][n], 0, 0, 0);
        __syncthreads();
        buf ^= 1;
    }
#undef STAGE128

    const int ccol = lane & 15;
    const int crow = (lane >> 4) * 4;
#pragma unroll
    for (int n = 0; n < 4; ++n) {
        const int c = col0 + wcol + n * 16 + ccol;
#pragma unroll
        for (int m = 0; m < 4; ++m) {
            const int rb = row0 + wrow + m * 16 + crow;
#pragma unroll
            for (int q = 0; q < 4; ++q) {
                const int r = rb + q;
                if (r >= M) continue;
                float v = acc[m][n][q];
                if (C)  C[(long)ks * sCb + (long)r * ldc + c] = v;
                if (Cb) Cb[(long)r * ldcb + c] = (u16)bh(v);
            }
        }
    }
}

// ============ fused gh-GEMM + GRU update + score partial (v3: 128x64, 8 waves) ============
// Grid 256 flat: lx = f>>4 (16 row-tiles of 128), ly = swizzled 0..15 (64-col tiles).
// XCD f%8 sees only col-pair {2x,2x+1} -> 768 KB of Whh L2-resident.
__global__ __launch_bounds__(512)
void gh_gru(const u16* __restrict__ hb_in, const u16* __restrict__ Whh_b,
            const float* __restrict__ bhh, const u16* __restrict__ Gnm_b,
            const float* __restrict__ cbias,
            float* __restrict__ h, u16* __restrict__ hb_out,
            const float* __restrict__ Wa, float* __restrict__ gs_part, int tt)
{
    __shared__ __align__(16) u16 lA[2][1024][8];   // 32KB: [k16 0..7][row 0..127]
    __shared__ __align__(16) u16 lB[2][1536][8];   // 48KB: [k16 0..7][g*64+row]
    __shared__ float rowdot[128];

    const int f = blockIdx.x;
    const int ly = 2 * (f & 7) + ((f >> 3) & 1);   // 0..15 col-tile
    const int lx = f >> 4;                          // 0..15 row-tile
    const int row0 = lx * 128;
    const int col0 = ly * 64;

    const int tid = threadIdx.x;
    const int lane = tid & 63;
    const int wave = tid >> 6;     // 0..7
    const int wr = wave >> 1;      // 0..3 : 32-row slice
    const int wc = wave & 1;       // 0..1 : 32-col slice

    long arow = row0 + (tid & 127); if (arow >= NROWS) arow = NROWS - 1;

    // hoisted staging pointers
    const u16* aP0 = hb_in + arow * SQ + (tid >> 7) * 8;   // k16 = tid>>7 (0..3)
    const u16* aP1 = aP0 + 32;                             // k16 + 4
    const u16* bP[3];
#pragma unroll
    for (int j = 0; j < 3; ++j) {
        const int s = tid + j * 512;
        const int bk16 = s / 192;
        const int grow = s - bk16 * 192;
        bP[j] = Whh_b + (long)((grow >> 6) * SQ + col0 + (grow & 63)) * SQ + bk16 * 8;
    }

    f32x4 acc[3][2][2] = {};

#define GSTAGE(b, kt) do {                                                    \
    const int k0_ = (kt) * 64;                                                \
    gload16(aP0 + k0_, &lA[b][tid][0]);                                       \
    gload16(aP1 + k0_, &lA[b][tid + 512][0]);                                 \
    _Pragma("unroll")                                                         \
    for (int j = 0; j < 3; ++j)                                               \
        gload16(bP[j] + k0_, &lB[b][tid + j * 512][0]);                       \
} while (0)

    GSTAGE(0, 0);
    __syncthreads();
    int buf = 0;
    const int kg = lane >> 4;
    const int lr = lane & 15;
    for (int kt = 0; kt < 16; ++kt) {
        if (kt + 1 < 16) GSTAGE(buf ^ 1, kt + 1);
#pragma unroll
        for (int kk = 0; kk < 2; ++kk) {
            const int k16 = kk * 4 + kg;
            s16x8 af[2], bfr[3][2];
#pragma unroll
            for (int m = 0; m < 2; ++m)
                af[m] = *(const s16x8*)&lA[buf][k16 * 128 + wr * 32 + m * 16 + lr][0];
#pragma unroll
            for (int g = 0; g < 3; ++g)
#pragma unroll
                for (int n = 0; n < 2; ++n)
                    bfr[g][n] = *(const s16x8*)&lB[buf][k16 * 192 + g * 64 + wc * 32 + n * 16 + lr][0];
#pragma unroll
            for (int g = 0; g < 3; ++g)
#pragma unroll
                for (int m = 0; m < 2; ++m)
#pragma unroll
                    for (int n = 0; n < 2; ++n)
                        acc[g][m][n] = __builtin_amdgcn_mfma_f32_16x16x32_bf16(af[m], bfr[g][n], acc[g][m][n], 0, 0, 0);
        }
        __syncthreads();
        buf ^= 1;
    }
#undef GSTAGE

    if (tid < 128) rowdot[tid] = 0.f;
    __syncthreads();

    const int ccol = lane & 15;
    const int crow4 = (lane >> 4) * 4;
    int col2[2];
    float cbv[3][2], bhv[3][2];
#pragma unroll
    for (int n = 0; n < 2; ++n) {
        const int c = col0 + wc * 32 + n * 16 + ccol;
        col2[n] = c;
#pragma unroll
        for (int g = 0; g < 3; ++g) {
            cbv[g][n] = cbias[g * SQ + c];
            bhv[g][n] = bhh[g * SQ + c];
        }
    }

#pragma unroll
    for (int m = 0; m < 2; ++m) {
#pragma unroll
        for (int q = 0; q < 4; ++q) {
            const int row = row0 + wr * 32 + m * 16 + crow4 + q;
            const bool valid = (row < NROWS);
            float d = 0.f;
            if (valid) {
                const int e = row / BNN;
                const int rr = row - e * BNN;
                const int b_ = rr / 144;
                const int ni = (rr / 12) % 12;
                const int mi = rr % 12;
                const int bt = b_ * TQ + tt;
                const u16* gnp = Gnm_b + ((long)e * 96 + bt * 12 + ni) * 6144;
                const u16* gmp = Gnm_b + ((long)e * 96 + bt * 12 + mi) * 6144 + G3S;
                const float* wap = Wa + (long)e * SQ;
#pragma unroll
                for (int n = 0; n < 2; ++n) {
                    const int c = col2[n];
                    float gr  = acc[0][m][n][q] + bhv[0][n] + b2f(gnp[c]) + b2f(gmp[c]) + cbv[0][n];
                    float gz  = acc[1][m][n][q] + bhv[1][n] + b2f(gnp[SQ + c]) + b2f(gmp[SQ + c]) + cbv[1][n];
                    float ghn = acc[2][m][n][q] + bhv[2][n];
                    float gin = b2f(gnp[2 * SQ + c]) + b2f(gmp[2 * SQ + c]) + cbv[2][n];
                    float rg = sigmoidf(gr);
                    float zg = sigmoidf(gz);
                    float nn2 = tanhf(gin + rg * ghn);
                    float hp = h[(long)row * SQ + c];
                    float hn = (1.f - zg) * nn2 + zg * hp;
                    h[(long)row * SQ + c] = hn;
                    hb_out[(long)row * SQ + c] = (u16)bh(hn);
                    d += hn * wap[c];
                }
            }
            d += __shfl_xor(d, 1); d += __shfl_xor(d, 2);
            d += __shfl_xor(d, 4); d += __shfl_xor(d, 8);
            if (valid && ccol == 0)
                atomicAdd(&rowdot[wr * 32 + m * 16 + crow4 + q], d);
        }
    }
    __syncthreads();
    if (tid < 128) {
        const int row = row0 + tid;
        if (row < NROWS) gs_part[((long)tt * 2048 + row) * 16 + ly] = rowdot[tid];
    }
}

// ============ GRU step tt=0, elementwise (h0 ~ 0: gh0 = bhh; h1 = (1-z)*n) ============
__global__ __launch_bounds__(256)
void gru0(const u16* __restrict__ Gnm_b, const float* __restrict__ cbias,
          const float* __restrict__ bhh,
          float* __restrict__ h, u16* __restrict__ hb_out,
          const float* __restrict__ Wa, const float* __restrict__ ba,
          float* __restrict__ gs)
{
    const int row = blockIdx.x;
    const int e = row / BNN;
    const int r = row % BNN;
    const int b_ = r / 144;
    const int ni = (r / 12) % 12;
    const int mi = r % 12;
    const int bt = b_ * TQ;

    const u16* gnp = Gnm_b + ((long)e * 96 + bt * 12 + ni) * 6144;
    const u16* gmp = Gnm_b + ((long)e * 96 + bt * 12 + mi) * 6144 + G3S;
    float* hp = h + (long)row * SQ;
    u16* hpb = hb_out + (long)row * SQ;

    const int s = threadIdx.x * 4;

    ushort4 nR = *(const ushort4*)(gnp + s);
    ushort4 nZ = *(const ushort4*)(gnp + SQ + s);
    ushort4 nN = *(const ushort4*)(gnp + 2 * SQ + s);
    ushort4 mR = *(const ushort4*)(gmp + s);
    ushort4 mZ = *(const ushort4*)(gmp + SQ + s);
    ushort4 mN = *(const ushort4*)(gmp + 2 * SQ + s);
    float4 cbR = *(const float4*)(cbias + s);
    float4 cbZ = *(const float4*)(cbias + SQ + s);
    float4 cbN = *(const float4*)(cbias + 2 * SQ + s);
    float4 bhR = *(const float4*)(bhh + s);
    float4 bhZ = *(const float4*)(bhh + SQ + s);
    float4 bhN = *(const float4*)(bhh + 2 * SQ + s);
    float4 wv  = *(const float4*)(Wa + (long)e * SQ + s);

    float4 hn4;
    float dot = 0.f;

#define GRU0_COMP(c, u)                                                       \
    {                                                                         \
        float rg = sigmoidf(b2f(nR.u) + b2f(mR.u) + cbR.c + bhR.c);           \
        float zg = sigmoidf(b2f(nZ.u) + b2f(mZ.u) + cbZ.c + bhZ.c);           \
        float nn = tanhf(b2f(nN.u) + b2f(mN.u) + cbN.c + rg * bhN.c);         \
        float hn = (1.f - zg) * nn;                                           \
        hn4.c = hn;                                                           \
        dot += hn * wv.c;                                                     \
    }
    GRU0_COMP(x, x) GRU0_COMP(y, y) GRU0_COMP(z, z) GRU0_COMP(w, w)
#undef GRU0_COMP

    *(float4*)(hp + s) = hn4;
    ushort4 hb4;
    hb4.x = (u16)bh(hn4.x); hb4.y = (u16)bh(hn4.y);
    hb4.z = (u16)bh(hn4.z); hb4.w = (u16)bh(hn4.w);
    *(ushort4*)(hpb + s) = hb4;

    for (int off = 32; off > 0; off >>= 1) dot += __shfl_down(dot, off);
    __shared__ float red[4];
    if ((threadIdx.x & 63) == 0) red[threadIdx.x >> 6] = dot;
    __syncthreads();
    if (threadIdx.x == 0) {
        float tot = red[0] + red[1] + red[2] + red[3] + ba[e];
        gs[((bt * 12 + ni) * 12 + mi) * EQ + e] = sigmoidf(tot);
    }
}

// ---------- gs finalize for tt=1..3 ----------
__global__ void gs_fin_all(const float* __restrict__ gs_part, const float* __restrict__ ba,
                           float* __restrict__ gs)
{
    int idx = blockIdx.x * 256 + threadIdx.x;
    if (idx >= 3 * 2048) return;
    const int tt = 1 + (idx >> 11);
    const int row = idx & 2047;
    if (row >= NROWS) return;
    float s = 0.f;
#pragma unroll
    for (int j = 0; j < 16; ++j) s += gs_part[((long)tt * 2048 + row) * 16 + j];
    const int e = row / BNN;
    const int rr = row - e * BNN;
    const int b_ = rr / 144;
    const int ni = (rr / 12) % 12;
    const int mi = rr % 12;
    const int bt = b_ * TQ + tt;
    gs[((bt * 12 + ni) * 12 + mi) * EQ + e] = sigmoidf(s + ba[e]);
}

// ---------- generic split-K reduce ----------
__global__ __launch_bounds__(256)
void reduce_k(const float* __restrict__ part, int ksplit, int mn, int Nn,
              const float* __restrict__ bias, long sBiasB, int act,
              float* __restrict__ Cf, long sCfB, int ldcf,
              u16* __restrict__ Cb, long sCbB, int ldcb)
{
    int i4 = blockIdx.x * 256 + threadIdx.x;
    int total4 = mn >> 2;
    if (i4 >= total4) return;
    int b = blockIdx.y;
    const float4* p4 = (const float4*)part;
    float4 s = make_float4(0.f, 0.f, 0.f, 0.f);
    for (int ks = 0; ks < ksplit; ++ks) {
        float4 v = p4[(long)(b * ksplit + ks) * total4 + i4];
        s.x += v.x; s.y += v.y; s.z += v.z; s.w += v.w;
    }
    int i = i4 << 2;
    int r = i / Nn, c = i % Nn;
    if (bias) {
        float4 bv = *(const float4*)(bias + (long)b * sBiasB + c);
        s.x += bv.x; s.y += bv.y; s.z += bv.z; s.w += bv.w;
    }
    if (act == 1) {
        s.x = sigmoidf(s.x); s.y = sigmoidf(s.y); s.z = sigmoidf(s.z); s.w = sigmoidf(s.w);
    } else if (act == 2) {
        s.x = tanhf(s.x); s.y = tanhf(s.y); s.z = tanhf(s.z); s.w = tanhf(s.w);
    }
    if (Cf) *(float4*)(Cf + (long)b * sCfB + (long)r * ldcf + c) = s;
    if (Cb) {
        ushort4 o;
        o.x = (u16)bh(s.x); o.y = (u16)bh(s.y); o.z = (u16)bh(s.z); o.w = (u16)bh(s.w);
        *(ushort4*)(Cb + (long)b * sCbB + (long)r * ldcb + c) = o;
    }
}

__global__ void cvt_bf16_k(const float* __restrict__ src, u16* __restrict__ dst, int n4)
{
    int i = blockIdx.x * 256 + threadIdx.x;
    if (i >= n4) return;
    float4 v = ((const float4*)src)[i];
    ushort4 o;
    o.x = (u16)bh(v.x); o.y = (u16)bh(v.y); o.z = (u16)bh(v.z); o.w = (u16)bh(v.w);
    ((ushort4*)dst)[i] = o;
}

__global__ __launch_bounds__(256)
void transpose_wc(const float* __restrict__ Wcomp, float* __restrict__ W1T, float* __restrict__ W2T)
{
    __shared__ float t1[32][33];
    __shared__ float t2[32][33];
    const int tx = threadIdx.x & 31;
    const int ty = threadIdx.x >> 5;
    const int d0 = blockIdx.x * 32;
    const int s0 = blockIdx.y * 32;
#pragma unroll
    for (int k = 0; k < 4; ++k) {
        int d = d0 + ty + k * 8;
        t1[ty + k * 8][tx] = Wcomp[(long)d * 2048 + s0 + tx];
        t2[ty + k * 8][tx] = Wcomp[(long)d * 2048 + 1024 + s0 + tx];
    }
    __syncthreads();
#pragma unroll
    for (int k = 0; k < 4; ++k) {
        int s = s0 + ty + k * 8;
        W1T[(long)s * 1024 + d0 + tx] = t1[tx][ty + k * 8];
        W2T[(long)s * 1024 + d0 + tx] = t2[tx][ty + k * 8];
    }
}

__global__ void pack_rz(const float* __restrict__ Wr, const float* __restrict__ Wz,
                        const float* __restrict__ br, const float* __restrict__ bz,
                        u16* __restrict__ Wrz, float* __restrict__ brz)
{
    int i4 = blockIdx.x * 256 + threadIdx.x;
    if (i4 < 512) {
        int c = i4 * 4;
        float4 b = (c < 1024) ? *(const float4*)(br + c) : *(const float4*)(bz + c - 1024);
        *(float4*)(brz + c) = b;
    }
    if (i4 >= 1048576) return;
    int i = i4 * 4;
    int j = i >> 11;
    int c = i & 2047;
    float4 v = (j < 1024) ? *(const float4*)(Wr + (long)j * 2048 + c)
                          : *(const float4*)(Wz + (long)(j - 1024) * 2048 + c);
    ushort4 o;
    o.x = (u16)bh(v.x); o.y = (u16)bh(v.y); o.z = (u16)bh(v.z); o.w = (u16)bh(v.w);
    *(ushort4*)(Wrz + i) = o;
}

__global__ void cbias_k(const float* __restrict__ Wih, const float* __restrict__ bih,
                        const float* __restrict__ bcomp, float* __restrict__ cbias)
{
    int g = blockIdx.x * blockDim.x + threadIdx.x;
    if (g >= G3S) return;
    const float* w = Wih + (long)g * SQ;
    float s = 0.f;
    for (int k = 0; k < SQ; k += 4) {
        float4 wv = *(const float4*)(w + k);
        float4 bv = *(const float4*)(bcomp + k);
        s += wv.x * bv.x + wv.y * bv.y + wv.z * bv.z + wv.w * bv.w;
    }
    cbias[g] = s + bih[g];
}

// ---------------- merged + amat fused ----------------
__global__ __launch_bounds__(256)
void merged_amat_k(const float* __restrict__ gs, const u16* __restrict__ msgs_b,
                   const float* __restrict__ prop, u16* __restrict__ amat_b)
{
    const int bn = blockIdx.x;
    const int bt = bn / 12;
    __shared__ float g[84];
    if (threadIdx.x < 84) g[threadIdx.x] = gs[bn * 84 + threadIdx.x];
    __syncthreads();
    const int s = threadIdx.x * 4;
    float4 acc = make_float4(0.f, 0.f, 0.f, 0.f);
    for (int j = 0; j < 84; ++j) {
        const ushort4 mv = *(const ushort4*)(msgs_b + ((long)(bt * 84 + j)) * SQ + s);
        float gj = g[j];
        acc.x += gj * b2f(mv.x);
        acc.y += gj * b2f(mv.y);
        acc.z += gj * b2f(mv.z);
        acc.w += gj * b2f(mv.w);
    }
    ushort4 o;
    o.x = (u16)bh(acc.x); o.y = (u16)bh(acc.y); o.z = (u16)bh(acc.z); o.w = (u16)bh(acc.w);
    *(ushort4*)(amat_b + (long)bn * 2048 + s) = o;
    float4 pv = *(const float4*)(prop + (long)bn * SQ + s);
    ushort4 o2;
    o2.x = (u16)bh(pv.x); o2.y = (u16)bh(pv.y); o2.z = (u16)bh(pv.z); o2.w = (u16)bh(pv.w);
    *(ushort4*)(amat_b + (long)bn * 2048 + 1024 + s) = o2;
}

__global__ void ahat_k(const float* __restrict__ rz, const float* __restrict__ prop,
                       u16* __restrict__ amat_b)
{
    int i = blockIdx.x * 256 + threadIdx.x;
    int rrow = i >> 10, c = i & 1023;
    float r = rz[(long)rrow * 2048 + c];
    amat_b[(long)rrow * 2048 + 1024 + c] = (u16)bh(r * prop[i]);
}

__global__ void propupd_k(const float* __restrict__ rz, const float* __restrict__ hhat,
                          float* __restrict__ prop, u16* __restrict__ prop_b)
{
    int i = blockIdx.x * 256 + threadIdx.x;
    int rrow = i >> 10, c = i & 1023;
    float z = rz[(long)rrow * 2048 + 1024 + c];
    float v = (1.f - z) * prop[i] + z * hhat[i];
    prop[i] = v;
    prop_b[i] = (u16)bh(v);
}

// ---------------- final outputs ----------------
__global__ __launch_bounds__(256)
void outputs_k(const float* __restrict__ gs, float* __restrict__ out)
{
    __shared__ float s_act[672];
    __shared__ float s_asum[96];
    int tid = threadIdx.x;
    for (int idx = tid; idx < 672; idx += 256) {
        int bn = idx / 7, e = idx % 7;
        float sum = 0.f;
        for (int m = 0; m < 12; ++m) {
            float g0 = gs[bn * 84 + m * 7];
            sum += (1.f - g0) * gs[bn * 84 + m * 7 + e];
        }
        s_act[idx] = sum;
        out[idx] = sum;
    }
    for (int idx = tid; idx < 96; idx += 256) {
        float a = 0.f;
        for (int m = 0; m < 12; ++m) a += 1.f - gs[idx * 84 + m * 7];
        s_asum[idx] = a;
    }
    for (int idx = tid; idx < 1152; idx += 256) {
        int bn = idx / 12, m = idx % 12;
        out[720 + idx] = 1.f - gs[bn * 84 + m * 7];
    }
    __syncthreads();
    if (tid < 8) {
        float tmp[6];
        float mx = -1e30f;
        for (int e = 1; e < 7; ++e) {
            float sum = 0.f;
            for (int n = 0; n < 12; ++n) {
                int bn = tid * 12 + n;
                sum += s_act[bn * 7 + e] * s_asum[bn];
            }
            tmp[e - 1] = sum;
            mx = fmaxf(mx, sum);
        }
        float den = 0.f;
        for (int e = 0; e < 6; ++e) { tmp[e] = expf(tmp[e] - mx); den += tmp[e]; }
        for (int e = 0; e < 6; ++e) out[672 + tid * 6 + e] = tmp[e] / den;
    }
}

// ---------------- host ----------------
template<int AS32, int BS32>
static void launch_gemm(const void* A, long sAb, int lda,
                        const void* B, long sBb, int ldb,
                        const float* bias, long sBiasb,
                        float* C, long sCb, int ldc,
                        u16* Cb, long sCbb, int ldcb,
                        int M, int Nn, int K, int act, int batch, int ksplit,
                        hipStream_t stream)
{
    dim3 grid((M + 63) / 64, (Nn + 127) / 128, batch * ksplit);
    gemm_mfma<AS32, BS32><<<grid, dim3(256), 0, stream>>>(
        A, sAb, lda, B, sBb, ldb, bias, sBiasb, C, sCb, ldc, Cb, sCbb, ldcb,
        M, Nn, K, act, ksplit);
}

extern "C" void kernel_launch(void* const* d_in, const int* in_sizes, int n_in,
                              void* d_out, int out_size, void* d_ws, size_t ws_size,
                              hipStream_t stream)
{
    const float* pose  = (const float*)d_in[0];
    const float* Wc    = (const float*)d_in[5];
    const float* bc    = (const float*)d_in[6];
    const float* We    = (const float*)d_in[7];
    const float* be    = (const float*)d_in[8];
    const float* Wcomp = (const float*)d_in[9];
    const float* bcomp = (const float*)d_in[10];
    const float* Wr    = (const float*)d_in[11];
    const float* br    = (const float*)d_in[12];
    const float* Wz    = (const float*)d_in[13];
    const float* bz    = (const float*)d_in[14];
    const float* Wh    = (const float*)d_in[15];
    const float* bh_   = (const float*)d_in[16];
    const float* Wih   = (const float*)d_in[17];
    const float* Whh   = (const float*)d_in[18];
    const float* bih   = (const float*)d_in[19];
    const float* bhh   = (const float*)d_in[20];
    const float* Wa    = (const float*)d_in[21];
    const float* ba    = (const float*)d_in[22];

    float* ws = (float*)d_ws;
    // fp32 region
    float* prop    = ws;                    // 98304
    float* cbias   = prop + 98304;          // 3072
    float* h       = cbias + 3072;          // 2064384
    float* scratch = h + 2064384;           // 8257536  (split-K partials / W1T/W2T)
    float* gs      = scratch + 8257536;     // 8064
    float* rz      = gs + 8064;             // 196608
    float* hhat    = rz + 196608;           // 98304
    float* brz     = hhat + 98304;          // 2048
    float* gs_part = brz + 2048;            // 131072 (4 x 2048 x 16)
    float* fend    = gs_part + 131072;
    // bf16 region
    u16* Whh_b  = (u16*)fend;               // 3145728
    u16* Wnm_b  = Whh_b + 3145728;          // 6291456  (6144 x 1024)
    u16* Wrz_b  = Wnm_b + 6291456;          // 4194304
    u16* Gnm_b  = Wrz_b + 4194304;          // 4128768  (7 x 96 x 6144)
    u16* msgs_b = Gnm_b + 4128768;          // 688128
    u16* h_b0   = msgs_b + 688128;          // 2064384
    u16* h_b1   = h_b0 + 2064384;           // 2064384
    u16* prop_b = h_b1 + 2064384;           // 98304
    u16* amat_b = prop_b + 98304;           // 196608
    u16* pose_b = amat_b + 196608;          // 2534400
    u16* Wc_b   = pose_b + 2534400;         // 27033600

    float* W1T = scratch;                   // transient
    float* W2T = scratch + 1048576;         // transient

    // ---- once per call ----
    hipLaunchKernelGGL(cvt_bf16_k, dim3(3072), dim3(256), 0, stream, Whh, Whh_b, 786432);
    hipLaunchKernelGGL(cvt_bf16_k, dim3(2475), dim3(256), 0, stream, pose, pose_b, 633600);
    hipLaunchKernelGGL(cvt_bf16_k, dim3(26400), dim3(256), 0, stream, Wc, Wc_b, 6758400);
    hipLaunchKernelGGL(cbias_k, dim3(12), dim3(256), 0, stream, Wih, bih, bcomp, cbias);
    hipLaunchKernelGGL(transpose_wc, dim3(32, 32), dim3(256), 0, stream, Wcomp, W1T, W2T);
    hipLaunchKernelGGL(pack_rz, dim3(4096), dim3(256), 0, stream, Wr, Wz, br, bz, Wrz_b, brz);
    // Wnm rows 0..3071 = Wih @ W1T^T ; rows 3072..6143 = Wih @ W2T^T
    gemm128_f32<<<dim3(24, 8, 1), dim3(256), 0, stream>>>(
        Wih, SQ, W1T, SQ, nullptr, 0, SQ, Wnm_b, SQ, G3S, SQ, SQ, 1);
    gemm128_f32<<<dim3(24, 8, 1), dim3(256), 0, stream>>>(
        Wih, SQ, W2T, SQ, nullptr, 0, SQ, Wnm_b + (long)G3S * SQ, SQ, G3S, SQ, SQ, 1);
    // prop = pose @ Wc^T + bc : bf16 operands, ksplit=55 (Ksl=480, 880 blocks)
    launch_gemm<0, 0>(pose_b, 0, DIN, Wc_b, 0, DIN, nullptr, 0,
                      scratch, 98304, SQ, nullptr, 0, 0, 96, SQ, DIN, 0, 1, 55, stream);
    hipLaunchKernelGGL(reduce_k, dim3(96, 1), dim3(256), 0, stream,
                       scratch, 55, 98304, SQ, bc, 0L, 0,
                       prop, 0L, SQ, prop_b, 0L, SQ);

    for (int t = 0; t <= TSQ; ++t) {
        // msgs[bt,n,e,s] = prop @ We[e]^T + be[e] : batch 7, ksplit 4
        launch_gemm<0, 1>(prop_b, 0, SQ, We, (long)SQ * SQ, SQ, nullptr, 0,
                          scratch, 98304, SQ, nullptr, 0, 0, 96, SQ, SQ, 0, EQ, 4, stream);
        hipLaunchKernelGGL(reduce_k, dim3(96, EQ), dim3(256), 0, stream,
                           scratch, 4, 98304, SQ, be, (long)SQ, 0,
                           (float*)nullptr, 0L, 0, msgs_b, (long)SQ, EQ * SQ);
        // Gnm = msgs_e @ Wnm^T : batch 7, direct bf16 write
        launch_gemm<0, 0>(msgs_b, SQ, EQ * SQ, Wnm_b, 0, SQ, nullptr, 0,
                          nullptr, 0, 0, Gnm_b, 589824, 6 * SQ, 96, 6 * SQ, SQ, 0, EQ, 1, stream);
        // GRU scan: tt=0 elementwise, then 3 fused GEMM steps
        hipLaunchKernelGGL(gru0, dim3(NROWS), dim3(256), 0, stream,
                           Gnm_b, cbias, bhh, h, h_b0, Wa, ba, gs);
        for (int tt = 1; tt < TQ; ++tt) {
            const u16* hin = (tt & 1) ? h_b0 : h_b1;
            u16* hout = (tt & 1) ? h_b1 : h_b0;
            hipLaunchKernelGGL(gh_gru, dim3(256), dim3(512), 0, stream,
                               hin, Whh_b, bhh, Gnm_b, cbias, h, hout, Wa, gs_part, tt);
        }
        hipLaunchKernelGGL(gs_fin_all, dim3(24), dim3(256), 0, stream, gs_part, ba, gs);
        if (t < TSQ) {
            hipLaunchKernelGGL(merged_amat_k, dim3(96), dim3(256), 0, stream,
                               gs, msgs_b, prop, amat_b);
            // rz = sigmoid(amat @ [Wr;Wz]^T + brz) : ksplit=8
            launch_gemm<0, 0>(amat_b, 0, 2 * SQ, Wrz_b, 0, 2 * SQ, nullptr, 0,
                              scratch, 196608, 2 * SQ, nullptr, 0, 0, 96, 2 * SQ, 2 * SQ, 0, 1, 8, stream);
            hipLaunchKernelGGL(reduce_k, dim3(192, 1), dim3(256), 0, stream,
                               scratch, 8, 196608, 2 * SQ, brz, 0L, 1,
                               rz, 0L, 2 * SQ, (u16*)nullptr, 0L, 0);
            hipLaunchKernelGGL(ahat_k, dim3(384), dim3(256), 0, stream, rz, prop, amat_b);
            // hhat = tanh(amat @ Wh^T + bh) : ksplit=8
            launch_gemm<0, 1>(amat_b, 0, 2 * SQ, Wh, 0, 2 * SQ, nullptr, 0,
                              scratch, 98304, SQ, nullptr, 0, 0, 96, SQ, 2 * SQ, 0, 1, 8, stream);
            hipLaunchKernelGGL(reduce_k, dim3(96, 1), dim3(256), 0, stream,
                               scratch, 8, 98304, SQ, bh_, 0L, 2,
                               hhat, 0L, SQ, (u16*)nullptr, 0L, 0);
            hipLaunchKernelGGL(propupd_k, dim3(384), dim3(256), 0, stream, rz, hhat, prop, prop_b);
        }
    }

    hipLaunchKernelGGL(outputs_k, dim3(1), dim3(256), 0, stream, gs, (float*)d_out);
}

// Round 8
// 1135.230 us; speedup vs baseline: 5.2924x; 1.0402x over previous
//
#include <hip/hip_runtime.h>
#include <math.h>

// Problem constants
#define NQ 12
#define EQ 7
#define SQ 1024
#define TSQ 3
#define DIN 26400
#define BQ 2
#define TQ 4
#define BT 8          // B*T
#define BNN 288       // B*N*N
#define NROWS 2016    // E*BNN
#define G3S 3072      // 3*S
#define BK 32

typedef unsigned short u16;
typedef float f32x4 __attribute__((ext_vector_type(4)));
typedef short s16x8 __attribute__((ext_vector_type(8)));

__device__ __forceinline__ short bh(float f) {
    unsigned u = __float_as_uint(f);
    return (short)((u + 0x8000u) >> 16);
}
__device__ __forceinline__ float b2f(u16 u) {
    return __uint_as_float((unsigned)u << 16);
}
__device__ __forceinline__ s16x8 pack8(float4 a, float4 b) {
    s16x8 r;
    r[0] = bh(a.x); r[1] = bh(a.y); r[2] = bh(a.z); r[3] = bh(a.w);
    r[4] = bh(b.x); r[5] = bh(b.y); r[6] = bh(b.z); r[7] = bh(b.w);
    return r;
}
__device__ __forceinline__ void gload16(const void* g, void* l) {
    __builtin_amdgcn_global_load_lds(
        (const __attribute__((address_space(1))) unsigned*)g,
        (__attribute__((address_space(3))) unsigned*)l, 16, 0, 0);
}
__device__ inline float sigmoidf(float x) { return 1.f / (1.f + expf(-x)); }

// ================= bf16 MFMA GEMM, 64x128 tile: C = A(MxK) * B(NxK)^T =================
template<int AS32, int BS32>
__global__ __launch_bounds__(256)
void gemm_mfma(const void* __restrict__ Ap, long sAb, int lda,
               const void* __restrict__ Bp, long sBb, int ldb,
               const float* __restrict__ bias, long sBiasb,
               float* __restrict__ C, long sCb, int ldc,
               u16* __restrict__ Cb, long sCbb, int ldcb,
               int M, int Nn, int K, int act, int ksplit)
{
    __shared__ __align__(16) u16 lA[2][256][8];
    __shared__ __align__(16) u16 lB[2][512][8];

    const int z = blockIdx.z;
    const int az = z / ksplit;
    const int ks = z - az * ksplit;
    const int Ksl = K / ksplit;
    const int kbase = ks * Ksl;

    const char* Abase = (const char*)Ap + (long)az * sAb * (AS32 ? 4 : 2);
    const char* Bbase = (const char*)Bp + (long)az * sBb * (BS32 ? 4 : 2);

    const int tid = threadIdx.x;
    const int lane = tid & 63;
    const int wave = tid >> 6;
    const int row0 = blockIdx.x * 64;
    const int col0 = blockIdx.y * 128;
    const int wcol = wave * 32;

    const int akg = tid >> 6;
    long arow = row0 + (tid & 63); if (arow >= M) arow = M - 1;
    const int bkg0 = tid >> 7;
    const int s1 = tid + 256;
    const int bkg1 = s1 >> 7;
    long brow0 = col0 + (tid & 127); if (brow0 >= Nn) brow0 = Nn - 1;
    long brow1 = col0 + (s1 & 127);  if (brow1 >= Nn) brow1 = Nn - 1;

    const int arw32 = tid >> 2, akg32 = tid & 3;
    long ar32 = row0 + arw32; if (ar32 >= M) ar32 = M - 1;
    const int brw32 = tid >> 1, bh32 = tid & 1;
    long br32 = col0 + brw32; if (br32 >= Nn) br32 = Nn - 1;

    f32x4 acc[4][2] = {};

#define STAGE(b, kt) do {                                                     \
    const int k0_ = kbase + (kt) * BK;                                        \
    if constexpr (AS32) {                                                     \
        const float* A32 = (const float*)Abase;                               \
        const float* p0 = A32 + ar32 * lda + k0_ + akg32 * 8;                 \
        *(s16x8*)&lA[b][akg32 * 64 + arw32][0] =                              \
            pack8(*(const float4*)p0, *(const float4*)(p0 + 4));              \
    } else {                                                                  \
        const u16* A16 = (const u16*)Abase;                                   \
        gload16(A16 + arow * lda + k0_ + akg * 8, &lA[b][tid][0]);            \
    }                                                                         \
    if constexpr (BS32) {                                                     \
        const float* B32 = (const float*)Bbase;                               \
        const float* q0 = B32 + br32 * ldb + k0_ + bh32 * 16;                 \
        *(s16x8*)&lB[b][(bh32 * 2) * 128 + brw32][0] =                        \
            pack8(*(const float4*)q0, *(const float4*)(q0 + 4));              \
        *(s16x8*)&lB[b][(bh32 * 2 + 1) * 128 + brw32][0] =                    \
            pack8(*(const float4*)(q0 + 8), *(const float4*)(q0 + 12));       \
    } else {                                                                  \
        const u16* B16 = (const u16*)Bbase;                                   \
        gload16(B16 + brow0 * ldb + k0_ + bkg0 * 8, &lB[b][tid][0]);          \
        gload16(B16 + brow1 * ldb + k0_ + bkg1 * 8, &lB[b][s1][0]);           \
    }                                                                         \
} while (0)

    const int nk = Ksl / BK;
    STAGE(0, 0);
    __syncthreads();
    int buf = 0;
    const int kg = lane >> 4;
    const int lr = lane & 15;
    for (int kt = 0; kt < nk; ++kt) {
        if (kt + 1 < nk) STAGE(buf ^ 1, kt + 1);
        s16x8 af[4], bfr[2];
#pragma unroll
        for (int m = 0; m < 4; ++m)
            af[m] = *(const s16x8*)&lA[buf][kg * 64 + m * 16 + lr][0];
#pragma unroll
        for (int n = 0; n < 2; ++n)
            bfr[n] = *(const s16x8*)&lB[buf][kg * 128 + wcol + n * 16 + lr][0];
#pragma unroll
        for (int m = 0; m < 4; ++m)
#pragma unroll
            for (int n = 0; n < 2; ++n)
                acc[m][n] = __builtin_amdgcn_mfma_f32_16x16x32_bf16(af[m], bfr[n], acc[m][n], 0, 0, 0);
        __syncthreads();
        buf ^= 1;
    }
#undef STAGE

    const int ccol = lane & 15;
    const int crow = (lane >> 4) * 4;
#pragma unroll
    for (int n = 0; n < 2; ++n) {
        const int c = col0 + wcol + n * 16 + ccol;
        const float bv = bias ? bias[(long)az * sBiasb + c] : 0.f;
#pragma unroll
        for (int m = 0; m < 4; ++m) {
            const int rb = row0 + m * 16 + crow;
#pragma unroll
            for (int q = 0; q < 4; ++q) {
                const int r = rb + q;
                if (r >= M) continue;
                float v = acc[m][n][q] + bv;
                if (act == 1) v = 1.f / (1.f + expf(-v));
                else if (act == 2) v = tanhf(v);
                if (C)  C[(long)z * sCb + (long)r * ldc + c] = v;
                if (Cb) Cb[(long)z * sCbb + (long)r * ldcb + c] = (u16)bh(v);
            }
        }
    }
}

// ============ 128x128-tile fp32-in GEMM (Wnm setup) ============
__global__ __launch_bounds__(256)
void gemm128_f32(const float* __restrict__ A, int lda,
                 const float* __restrict__ Bm, int ldb,
                 float* __restrict__ C, long sCb, int ldc,
                 u16* __restrict__ Cb, int ldcb,
                 int M, int Nn, int K, int ksplit)
{
    __shared__ __align__(16) u16 lA[2][512][8];
    __shared__ __align__(16) u16 lB[2][512][8];

    const int ks = blockIdx.z;
    const int Ksl = K / ksplit;
    const int kbase = ks * Ksl;

    const int tid = threadIdx.x;
    const int lane = tid & 63;
    const int wave = tid >> 6;
    const int row0 = blockIdx.x * 128;
    const int col0 = blockIdx.y * 128;
    const int wrow = (wave >> 1) * 64;
    const int wcol = (wave & 1) * 64;

    const int rw = tid >> 1, hf = tid & 1;
    long ar = row0 + rw; if (ar >= M) ar = M - 1;
    long br = col0 + rw; if (br >= Nn) br = Nn - 1;

    f32x4 acc[4][4] = {};

#define STAGE128(b, kt) do {                                                  \
    const int k0_ = kbase + (kt) * BK;                                        \
    const float* p = A + ar * lda + k0_ + hf * 16;                            \
    *(s16x8*)&lA[b][(hf * 2) * 128 + rw][0] =                                 \
        pack8(*(const float4*)p, *(const float4*)(p + 4));                    \
    *(s16x8*)&lA[b][(hf * 2 + 1) * 128 + rw][0] =                             \
        pack8(*(const float4*)(p + 8), *(const float4*)(p + 12));             \
    const float* q = Bm + br * ldb + k0_ + hf * 16;                           \
    *(s16x8*)&lB[b][(hf * 2) * 128 + rw][0] =                                 \
        pack8(*(const float4*)q, *(const float4*)(q + 4));                    \
    *(s16x8*)&lB[b][(hf * 2 + 1) * 128 + rw][0] =                             \
        pack8(*(const float4*)(q + 8), *(const float4*)(q + 12));             \
} while (0)

    const int nk = Ksl / BK;
    STAGE128(0, 0);
    __syncthreads();
    int buf = 0;
    const int kg = lane >> 4;
    const int lr = lane & 15;
    for (int kt = 0; kt < nk; ++kt) {
        if (kt + 1 < nk) STAGE128(buf ^ 1, kt + 1);
        s16x8 af[4], bfr[4];
#pragma unroll
        for (int m = 0; m < 4; ++m)
            af[m] = *(const s16x8*)&lA[buf][kg * 128 + wrow + m * 16 + lr][0];
#pragma unroll
        for (int n = 0; n < 4; ++n)
            bfr[n] = *(const s16x8*)&lB[buf][kg * 128 + wcol + n * 16 + lr][0];
#pragma unroll
        for (int m = 0; m < 4; ++m)
#pragma unroll
            for (int n = 0; n < 4; ++n)
                acc[m][n] = __builtin_amdgcn_mfma_f32_16x16x32_bf16(af[m], bfr[n], acc[m][n], 0, 0, 0);
        __syncthreads();
        buf ^= 1;
    }
#undef STAGE128

    const int ccol = lane & 15;
    const int crow = (lane >> 4) * 4;
#pragma unroll
    for (int n = 0; n < 4; ++n) {
        const int c = col0 + wcol + n * 16 + ccol;
#pragma unroll
        for (int m = 0; m < 4; ++m) {
            const int rb = row0 + wrow + m * 16 + crow;
#pragma unroll
            for (int q = 0; q < 4; ++q) {
                const int r = rb + q;
                if (r >= M) continue;
                float v = acc[m][n][q];
                if (C)  C[(long)ks * sCb + (long)r * ldc + c] = v;
                if (Cb) Cb[(long)r * ldcb + c] = (u16)bh(v);
            }
        }
    }
}

// ============ fused gh-GEMM + GRU update + score partial (v4: bf16-carried h) ============
// Grid 256 flat: lx = f>>4 (16 row-tiles of 128), ly = swizzled 0..15 (64-col tiles).
// h state lives only in bf16 ping-pong buffers; epilogue re-reads h_old from hb_in.
__global__ __launch_bounds__(512)
void gh_gru(const u16* __restrict__ hb_in, const u16* __restrict__ Whh_b,
            const float* __restrict__ bhh, const u16* __restrict__ Gnm_b,
            const float* __restrict__ cbias,
            u16* __restrict__ hb_out,
            const float* __restrict__ Wa, float* __restrict__ gs_part, int tt)
{
    __shared__ __align__(16) u16 lA[2][1024][8];   // 32KB: [k16 0..7][row 0..127]
    __shared__ __align__(16) u16 lB[2][1536][8];   // 48KB: [k16 0..7][g*64+row]
    __shared__ float rowdot[128];

    const int f = blockIdx.x;
    const int ly = 2 * (f & 7) + ((f >> 3) & 1);   // 0..15 col-tile
    const int lx = f >> 4;                          // 0..15 row-tile
    const int row0 = lx * 128;
    const int col0 = ly * 64;

    const int tid = threadIdx.x;
    const int lane = tid & 63;
    const int wave = tid >> 6;     // 0..7
    const int wr = wave >> 1;      // 0..3 : 32-row slice
    const int wc = wave & 1;       // 0..1 : 32-col slice

    long arow = row0 + (tid & 127); if (arow >= NROWS) arow = NROWS - 1;

    const u16* aP0 = hb_in + arow * SQ + (tid >> 7) * 8;
    const u16* aP1 = aP0 + 32;
    const u16* bP[3];
#pragma unroll
    for (int j = 0; j < 3; ++j) {
        const int s = tid + j * 512;
        const int bk16 = s / 192;
        const int grow = s - bk16 * 192;
        bP[j] = Whh_b + (long)((grow >> 6) * SQ + col0 + (grow & 63)) * SQ + bk16 * 8;
    }

    f32x4 acc[3][2][2] = {};

#define GSTAGE(b, kt) do {                                                    \
    const int k0_ = (kt) * 64;                                                \
    gload16(aP0 + k0_, &lA[b][tid][0]);                                       \
    gload16(aP1 + k0_, &lA[b][tid + 512][0]);                                 \
    _Pragma("unroll")                                                         \
    for (int j = 0; j < 3; ++j)                                               \
        gload16(bP[j] + k0_, &lB[b][tid + j * 512][0]);                       \
} while (0)

    GSTAGE(0, 0);
    __syncthreads();
    int buf = 0;
    const int kg = lane >> 4;
    const int lr = lane & 15;
    for (int kt = 0; kt < 16; ++kt) {
        if (kt + 1 < 16) GSTAGE(buf ^ 1, kt + 1);
#pragma unroll
        for (int kk = 0; kk < 2; ++kk) {
            const int k16 = kk * 4 + kg;
            s16x8 af[2], bfr[3][2];
#pragma unroll
            for (int m = 0; m < 2; ++m)
                af[m] = *(const s16x8*)&lA[buf][k16 * 128 + wr * 32 + m * 16 + lr][0];
#pragma unroll
            for (int g = 0; g < 3; ++g)
#pragma unroll
                for (int n = 0; n < 2; ++n)
                    bfr[g][n] = *(const s16x8*)&lB[buf][k16 * 192 + g * 64 + wc * 32 + n * 16 + lr][0];
#pragma unroll
            for (int g = 0; g < 3; ++g)
#pragma unroll
                for (int m = 0; m < 2; ++m)
#pragma unroll
                    for (int n = 0; n < 2; ++n)
                        acc[g][m][n] = __builtin_amdgcn_mfma_f32_16x16x32_bf16(af[m], bfr[g][n], acc[g][m][n], 0, 0, 0);
        }
        __syncthreads();
        buf ^= 1;
    }
#undef GSTAGE

    if (tid < 128) rowdot[tid] = 0.f;
    __syncthreads();

    const int ccol = lane & 15;
    const int crow4 = (lane >> 4) * 4;
    int col2[2];
    float cbv[3][2], bhv[3][2];
#pragma unroll
    for (int n = 0; n < 2; ++n) {
        const int c = col0 + wc * 32 + n * 16 + ccol;
        col2[n] = c;
#pragma unroll
        for (int g = 0; g < 3; ++g) {
            cbv[g][n] = cbias[g * SQ + c];
            bhv[g][n] = bhh[g * SQ + c];
        }
    }

#pragma unroll
    for (int m = 0; m < 2; ++m) {
#pragma unroll
        for (int q = 0; q < 4; ++q) {
            const int row = row0 + wr * 32 + m * 16 + crow4 + q;
            const bool valid = (row < NROWS);
            float d = 0.f;
            if (valid) {
                const int e = row / BNN;
                const int rr = row - e * BNN;
                const int b_ = rr / 144;
                const int ni = (rr / 12) % 12;
                const int mi = rr % 12;
                const int bt = b_ * TQ + tt;
                const u16* gnp = Gnm_b + ((long)e * 96 + bt * 12 + ni) * 6144;
                const u16* gmp = Gnm_b + ((long)e * 96 + bt * 12 + mi) * 6144 + G3S;
                const float* wap = Wa + (long)e * SQ;
#pragma unroll
                for (int n = 0; n < 2; ++n) {
                    const int c = col2[n];
                    float gr  = acc[0][m][n][q] + bhv[0][n] + b2f(gnp[c]) + b2f(gmp[c]) + cbv[0][n];
                    float gz  = acc[1][m][n][q] + bhv[1][n] + b2f(gnp[SQ + c]) + b2f(gmp[SQ + c]) + cbv[1][n];
                    float ghn = acc[2][m][n][q] + bhv[2][n];
                    float gin = b2f(gnp[2 * SQ + c]) + b2f(gmp[2 * SQ + c]) + cbv[2][n];
                    float rg = sigmoidf(gr);
                    float zg = sigmoidf(gz);
                    float nn2 = tanhf(gin + rg * ghn);
                    float hp = b2f(hb_in[(long)row * SQ + c]);
                    float hn = (1.f - zg) * nn2 + zg * hp;
                    hb_out[(long)row * SQ + c] = (u16)bh(hn);
                    d += hn * wap[c];
                }
            }
            d += __shfl_xor(d, 1); d += __shfl_xor(d, 2);
            d += __shfl_xor(d, 4); d += __shfl_xor(d, 8);
            if (valid && ccol == 0)
                atomicAdd(&rowdot[wr * 32 + m * 16 + crow4 + q], d);
        }
    }
    __syncthreads();
    if (tid < 128) {
        const int row = row0 + tid;
        if (row < NROWS) gs_part[((long)tt * 2048 + row) * 16 + ly] = rowdot[tid];
    }
}

// ============ GRU step tt=0, elementwise (h0 ~ 0: gh0 = bhh; h1 = (1-z)*n) ============
__global__ __launch_bounds__(256)
void gru0(const u16* __restrict__ Gnm_b, const float* __restrict__ cbias,
          const float* __restrict__ bhh,
          u16* __restrict__ hb_out,
          const float* __restrict__ Wa, const float* __restrict__ ba,
          float* __restrict__ gs)
{
    const int row = blockIdx.x;
    const int e = row / BNN;
    const int r = row % BNN;
    const int b_ = r / 144;
    const int ni = (r / 12) % 12;
    const int mi = r % 12;
    const int bt = b_ * TQ;

    const u16* gnp = Gnm_b + ((long)e * 96 + bt * 12 + ni) * 6144;
    const u16* gmp = Gnm_b + ((long)e * 96 + bt * 12 + mi) * 6144 + G3S;
    u16* hpb = hb_out + (long)row * SQ;

    const int s = threadIdx.x * 4;

    ushort4 nR = *(const ushort4*)(gnp + s);
    ushort4 nZ = *(const ushort4*)(gnp + SQ + s);
    ushort4 nN = *(const ushort4*)(gnp + 2 * SQ + s);
    ushort4 mR = *(const ushort4*)(gmp + s);
    ushort4 mZ = *(const ushort4*)(gmp + SQ + s);
    ushort4 mN = *(const ushort4*)(gmp + 2 * SQ + s);
    float4 cbR = *(const float4*)(cbias + s);
    float4 cbZ = *(const float4*)(cbias + SQ + s);
    float4 cbN = *(const float4*)(cbias + 2 * SQ + s);
    float4 bhR = *(const float4*)(bhh + s);
    float4 bhZ = *(const float4*)(bhh + SQ + s);
    float4 bhN = *(const float4*)(bhh + 2 * SQ + s);
    float4 wv  = *(const float4*)(Wa + (long)e * SQ + s);

    float4 hn4;
    float dot = 0.f;

#define GRU0_COMP(c, u)                                                       \
    {                                                                         \
        float rg = sigmoidf(b2f(nR.u) + b2f(mR.u) + cbR.c + bhR.c);           \
        float zg = sigmoidf(b2f(nZ.u) + b2f(mZ.u) + cbZ.c + bhZ.c);           \
        float nn = tanhf(b2f(nN.u) + b2f(mN.u) + cbN.c + rg * bhN.c);         \
        float hn = (1.f - zg) * nn;                                           \
        hn4.c = hn;                                                           \
        dot += hn * wv.c;                                                     \
    }
    GRU0_COMP(x, x) GRU0_COMP(y, y) GRU0_COMP(z, z) GRU0_COMP(w, w)
#undef GRU0_COMP

    ushort4 hb4;
    hb4.x = (u16)bh(hn4.x); hb4.y = (u16)bh(hn4.y);
    hb4.z = (u16)bh(hn4.z); hb4.w = (u16)bh(hn4.w);
    *(ushort4*)(hpb + s) = hb4;

    for (int off = 32; off > 0; off >>= 1) dot += __shfl_down(dot, off);
    __shared__ float red[4];
    if ((threadIdx.x & 63) == 0) red[threadIdx.x >> 6] = dot;
    __syncthreads();
    if (threadIdx.x == 0) {
        float tot = red[0] + red[1] + red[2] + red[3] + ba[e];
        gs[((bt * 12 + ni) * 12 + mi) * EQ + e] = sigmoidf(tot);
    }
}

// ---------- gs finalize for tt=1..3 ----------
__global__ void gs_fin_all(const float* __restrict__ gs_part, const float* __restrict__ ba,
                           float* __restrict__ gs)
{
    int idx = blockIdx.x * 256 + threadIdx.x;
    if (idx >= 3 * 2048) return;
    const int tt = 1 + (idx >> 11);
    const int row = idx & 2047;
    if (row >= NROWS) return;
    float s = 0.f;
#pragma unroll
    for (int j = 0; j < 16; ++j) s += gs_part[((long)tt * 2048 + row) * 16 + j];
    const int e = row / BNN;
    const int rr = row - e * BNN;
    const int b_ = rr / 144;
    const int ni = (rr / 12) % 12;
    const int mi = rr % 12;
    const int bt = b_ * TQ + tt;
    gs[((bt * 12 + ni) * 12 + mi) * EQ + e] = sigmoidf(s + ba[e]);
}

// ---------- generic split-K reduce ----------
__global__ __launch_bounds__(256)
void reduce_k(const float* __restrict__ part, int ksplit, int mn, int Nn,
              const float* __restrict__ bias, long sBiasB, int act,
              float* __restrict__ Cf, long sCfB, int ldcf,
              u16* __restrict__ Cb, long sCbB, int ldcb)
{
    int i4 = blockIdx.x * 256 + threadIdx.x;
    int total4 = mn >> 2;
    if (i4 >= total4) return;
    int b = blockIdx.y;
    const float4* p4 = (const float4*)part;
    float4 s = make_float4(0.f, 0.f, 0.f, 0.f);
    for (int ks = 0; ks < ksplit; ++ks) {
        float4 v = p4[(long)(b * ksplit + ks) * total4 + i4];
        s.x += v.x; s.y += v.y; s.z += v.z; s.w += v.w;
    }
    int i = i4 << 2;
    int r = i / Nn, c = i % Nn;
    if (bias) {
        float4 bv = *(const float4*)(bias + (long)b * sBiasB + c);
        s.x += bv.x; s.y += bv.y; s.z += bv.z; s.w += bv.w;
    }
    if (act == 1) {
        s.x = sigmoidf(s.x); s.y = sigmoidf(s.y); s.z = sigmoidf(s.z); s.w = sigmoidf(s.w);
    } else if (act == 2) {
        s.x = tanhf(s.x); s.y = tanhf(s.y); s.z = tanhf(s.z); s.w = tanhf(s.w);
    }
    if (Cf) *(float4*)(Cf + (long)b * sCfB + (long)r * ldcf + c) = s;
    if (Cb) {
        ushort4 o;
        o.x = (u16)bh(s.x); o.y = (u16)bh(s.y); o.z = (u16)bh(s.z); o.w = (u16)bh(s.w);
        *(ushort4*)(Cb + (long)b * sCbB + (long)r * ldcb + c) = o;
    }
}

// ---------- fused rz split-K reduce + sigmoid + ahat + zbuf ----------
__global__ __launch_bounds__(256)
void rz_ahat_k(const float* __restrict__ part, const float* __restrict__ brz,
               const float* __restrict__ prop, u16* __restrict__ amat_b,
               float* __restrict__ zbuf)
{
    int i = blockIdx.x * 256 + threadIdx.x;   // 0..98303
    int rrow = i >> 10, c = i & 1023;
    float sr = 0.f, sz = 0.f;
#pragma unroll
    for (int ks = 0; ks < 8; ++ks) {
        const float* p = part + (long)ks * 196608 + (long)rrow * 2048;
        sr += p[c]; sz += p[1024 + c];
    }
    float r = sigmoidf(sr + brz[c]);
    float z = sigmoidf(sz + brz[1024 + c]);
    amat_b[(long)rrow * 2048 + 1024 + c] = (u16)bh(r * prop[i]);
    zbuf[i] = z;
}

// ---------- fused hhat split-K reduce + tanh + prop update ----------
__global__ __launch_bounds__(256)
void hhat_prop_k(const float* __restrict__ part, const float* __restrict__ bh_,
                 const float* __restrict__ zbuf,
                 float* __restrict__ prop, u16* __restrict__ prop_b)
{
    int i = blockIdx.x * 256 + threadIdx.x;   // 0..98303
    float s = 0.f;
#pragma unroll
    for (int ks = 0; ks < 8; ++ks) s += part[(long)ks * 98304 + i];
    float hhat = tanhf(s + bh_[i & 1023]);
    float z = zbuf[i];
    float v = (1.f - z) * prop[i] + z * hhat;
    prop[i] = v;
    prop_b[i] = (u16)bh(v);
}

__global__ void cvt_bf16_k(const float* __restrict__ src, u16* __restrict__ dst, int n4)
{
    int i = blockIdx.x * 256 + threadIdx.x;
    if (i >= n4) return;
    float4 v = ((const float4*)src)[i];
    ushort4 o;
    o.x = (u16)bh(v.x); o.y = (u16)bh(v.y); o.z = (u16)bh(v.z); o.w = (u16)bh(v.w);
    ((ushort4*)dst)[i] = o;
}

__global__ __launch_bounds__(256)
void transpose_wc(const float* __restrict__ Wcomp, float* __restrict__ W1T, float* __restrict__ W2T)
{
    __shared__ float t1[32][33];
    __shared__ float t2[32][33];
    const int tx = threadIdx.x & 31;
    const int ty = threadIdx.x >> 5;
    const int d0 = blockIdx.x * 32;
    const int s0 = blockIdx.y * 32;
#pragma unroll
    for (int k = 0; k < 4; ++k) {
        int d = d0 + ty + k * 8;
        t1[ty + k * 8][tx] = Wcomp[(long)d * 2048 + s0 + tx];
        t2[ty + k * 8][tx] = Wcomp[(long)d * 2048 + 1024 + s0 + tx];
    }
    __syncthreads();
#pragma unroll
    for (int k = 0; k < 4; ++k) {
        int s = s0 + ty + k * 8;
        W1T[(long)s * 1024 + d0 + tx] = t1[tx][ty + k * 8];
        W2T[(long)s * 1024 + d0 + tx] = t2[tx][ty + k * 8];
    }
}

__global__ void pack_rz(const float* __restrict__ Wr, const float* __restrict__ Wz,
                        const float* __restrict__ br, const float* __restrict__ bz,
                        u16* __restrict__ Wrz, float* __restrict__ brz)
{
    int i4 = blockIdx.x * 256 + threadIdx.x;
    if (i4 < 512) {
        int c = i4 * 4;
        float4 b = (c < 1024) ? *(const float4*)(br + c) : *(const float4*)(bz + c - 1024);
        *(float4*)(brz + c) = b;
    }
    if (i4 >= 1048576) return;
    int i = i4 * 4;
    int j = i >> 11;
    int c = i & 2047;
    float4 v = (j < 1024) ? *(const float4*)(Wr + (long)j * 2048 + c)
                          : *(const float4*)(Wz + (long)(j - 1024) * 2048 + c);
    ushort4 o;
    o.x = (u16)bh(v.x); o.y = (u16)bh(v.y); o.z = (u16)bh(v.z); o.w = (u16)bh(v.w);
    *(ushort4*)(Wrz + i) = o;
}

__global__ void cbias_k(const float* __restrict__ Wih, const float* __restrict__ bih,
                        const float* __restrict__ bcomp, float* __restrict__ cbias)
{
    int g = blockIdx.x * blockDim.x + threadIdx.x;
    if (g >= G3S) return;
    const float* w = Wih + (long)g * SQ;
    float s = 0.f;
    for (int k = 0; k < SQ; k += 4) {
        float4 wv = *(const float4*)(w + k);
        float4 bv = *(const float4*)(bcomp + k);
        s += wv.x * bv.x + wv.y * bv.y + wv.z * bv.z + wv.w * bv.w;
    }
    cbias[g] = s + bih[g];
}

// ---------------- merged + amat fused ----------------
__global__ __launch_bounds__(256)
void merged_amat_k(const float* __restrict__ gs, const u16* __restrict__ msgs_b,
                   const float* __restrict__ prop, u16* __restrict__ amat_b)
{
    const int bn = blockIdx.x;
    const int bt = bn / 12;
    __shared__ float g[84];
    if (threadIdx.x < 84) g[threadIdx.x] = gs[bn * 84 + threadIdx.x];
    __syncthreads();
    const int s = threadIdx.x * 4;
    float4 acc = make_float4(0.f, 0.f, 0.f, 0.f);
    for (int j = 0; j < 84; ++j) {
        const ushort4 mv = *(const ushort4*)(msgs_b + ((long)(bt * 84 + j)) * SQ + s);
        float gj = g[j];
        acc.x += gj * b2f(mv.x);
        acc.y += gj * b2f(mv.y);
        acc.z += gj * b2f(mv.z);
        acc.w += gj * b2f(mv.w);
    }
    ushort4 o;
    o.x = (u16)bh(acc.x); o.y = (u16)bh(acc.y); o.z = (u16)bh(acc.z); o.w = (u16)bh(acc.w);
    *(ushort4*)(amat_b + (long)bn * 2048 + s) = o;
    float4 pv = *(const float4*)(prop + (long)bn * SQ + s);
    ushort4 o2;
    o2.x = (u16)bh(pv.x); o2.y = (u16)bh(pv.y); o2.z = (u16)bh(pv.z); o2.w = (u16)bh(pv.w);
    *(ushort4*)(amat_b + (long)bn * 2048 + 1024 + s) = o2;
}

// ---------------- final outputs ----------------
__global__ __launch_bounds__(256)
void outputs_k(const float* __restrict__ gs, float* __restrict__ out)
{
    __shared__ float s_act[672];
    __shared__ float s_asum[96];
    int tid = threadIdx.x;
    for (int idx = tid; idx < 672; idx += 256) {
        int bn = idx / 7, e = idx % 7;
        float sum = 0.f;
        for (int m = 0; m < 12; ++m) {
            float g0 = gs[bn * 84 + m * 7];
            sum += (1.f - g0) * gs[bn * 84 + m * 7 + e];
        }
        s_act[idx] = sum;
        out[idx] = sum;
    }
    for (int idx = tid; idx < 96; idx += 256) {
        float a = 0.f;
        for (int m = 0; m < 12; ++m) a += 1.f - gs[idx * 84 + m * 7];
        s_asum[idx] = a;
    }
    for (int idx = tid; idx < 1152; idx += 256) {
        int bn = idx / 12, m = idx % 12;
        out[720 + idx] = 1.f - gs[bn * 84 + m * 7];
    }
    __syncthreads();
    if (tid < 8) {
        float tmp[6];
        float mx = -1e30f;
        for (int e = 1; e < 7; ++e) {
            float sum = 0.f;
            for (int n = 0; n < 12; ++n) {
                int bn = tid * 12 + n;
                sum += s_act[bn * 7 + e] * s_asum[bn];
            }
            tmp[e - 1] = sum;
            mx = fmaxf(mx, sum);
        }
        float den = 0.f;
        for (int e = 0; e < 6; ++e) { tmp[e] = expf(tmp[e] - mx); den += tmp[e]; }
        for (int e = 0; e < 6; ++e) out[672 + tid * 6 + e] = tmp[e] / den;
    }
}

// ---------------- host ----------------
template<int AS32, int BS32>
static void launch_gemm(const void* A, long sAb, int lda,
                        const void* B, long sBb, int ldb,
                        const float* bias, long sBiasb,
                        float* C, long sCb, int ldc,
                        u16* Cb, long sCbb, int ldcb,
                        int M, int Nn, int K, int act, int batch, int ksplit,
                        hipStream_t stream)
{
    dim3 grid((M + 63) / 64, (Nn + 127) / 128, batch * ksplit);
    gemm_mfma<AS32, BS32><<<grid, dim3(256), 0, stream>>>(
        A, sAb, lda, B, sBb, ldb, bias, sBiasb, C, sCb, ldc, Cb, sCbb, ldcb,
        M, Nn, K, act, ksplit);
}

extern "C" void kernel_launch(void* const* d_in, const int* in_sizes, int n_in,
                              void* d_out, int out_size, void* d_ws, size_t ws_size,
                              hipStream_t stream)
{
    const float* pose  = (const float*)d_in[0];
    const float* Wc    = (const float*)d_in[5];
    const float* bc    = (const float*)d_in[6];
    const float* We    = (const float*)d_in[7];
    const float* be    = (const float*)d_in[8];
    const float* Wcomp = (const float*)d_in[9];
    const float* bcomp = (const float*)d_in[10];
    const float* Wr    = (const float*)d_in[11];
    const float* br    = (const float*)d_in[12];
    const float* Wz    = (const float*)d_in[13];
    const float* bz    = (const float*)d_in[14];
    const float* Wh    = (const float*)d_in[15];
    const float* bh_   = (const float*)d_in[16];
    const float* Wih   = (const float*)d_in[17];
    const float* Whh   = (const float*)d_in[18];
    const float* bih   = (const float*)d_in[19];
    const float* bhh   = (const float*)d_in[20];
    const float* Wa    = (const float*)d_in[21];
    const float* ba    = (const float*)d_in[22];

    float* ws = (float*)d_ws;
    // fp32 region
    float* prop    = ws;                    // 98304
    float* cbias   = prop + 98304;          // 3072
    float* scratch = cbias + 3072;          // 8257536  (split-K partials / W1T/W2T)
    float* gs      = scratch + 8257536;     // 8064
    float* zbuf    = gs + 8064;             // 98304
    float* brz     = zbuf + 98304;          // 2048
    float* gs_part = brz + 2048;            // 131072 (4 x 2048 x 16)
    float* fend    = gs_part + 131072;
    // bf16 region
    u16* Whh_b  = (u16*)fend;               // 3145728
    u16* Wnm_b  = Whh_b + 3145728;          // 6291456  (6144 x 1024)
    u16* Wrz_b  = Wnm_b + 6291456;          // 4194304
    u16* Gnm_b  = Wrz_b + 4194304;          // 4128768  (7 x 96 x 6144)
    u16* msgs_b = Gnm_b + 4128768;          // 688128
    u16* h_b0   = msgs_b + 688128;          // 2064384
    u16* h_b1   = h_b0 + 2064384;           // 2064384
    u16* prop_b = h_b1 + 2064384;           // 98304
    u16* amat_b = prop_b + 98304;           // 196608
    u16* pose_b = amat_b + 196608;          // 2534400
    u16* Wc_b   = pose_b + 2534400;         // 27033600

    float* W1T = scratch;                   // transient
    float* W2T = scratch + 1048576;         // transient

    // ---- once per call ----
    hipLaunchKernelGGL(cvt_bf16_k, dim3(3072), dim3(256), 0, stream, Whh, Whh_b, 786432);
    hipLaunchKernelGGL(cvt_bf16_k, dim3(2475), dim3(256), 0, stream, pose, pose_b, 633600);
    hipLaunchKernelGGL(cvt_bf16_k, dim3(26400), dim3(256), 0, stream, Wc, Wc_b, 6758400);
    hipLaunchKernelGGL(cbias_k, dim3(12), dim3(256), 0, stream, Wih, bih, bcomp, cbias);
    hipLaunchKernelGGL(transpose_wc, dim3(32, 32), dim3(256), 0, stream, Wcomp, W1T, W2T);
    hipLaunchKernelGGL(pack_rz, dim3(4096), dim3(256), 0, stream, Wr, Wz, br, bz, Wrz_b, brz);
    // Wnm rows 0..3071 = Wih @ W1T^T ; rows 3072..6143 = Wih @ W2T^T
    gemm128_f32<<<dim3(24, 8, 1), dim3(256), 0, stream>>>(
        Wih, SQ, W1T, SQ, nullptr, 0, SQ, Wnm_b, SQ, G3S, SQ, SQ, 1);
    gemm128_f32<<<dim3(24, 8, 1), dim3(256), 0, stream>>>(
        Wih, SQ, W2T, SQ, nullptr, 0, SQ, Wnm_b + (long)G3S * SQ, SQ, G3S, SQ, SQ, 1);
    // prop = pose @ Wc^T + bc : bf16 operands, ksplit=55
    launch_gemm<0, 0>(pose_b, 0, DIN, Wc_b, 0, DIN, nullptr, 0,
                      scratch, 98304, SQ, nullptr, 0, 0, 96, SQ, DIN, 0, 1, 55, stream);
    hipLaunchKernelGGL(reduce_k, dim3(96, 1), dim3(256), 0, stream,
                       scratch, 55, 98304, SQ, bc, 0L, 0,
                       prop, 0L, SQ, prop_b, 0L, SQ);

    for (int t = 0; t <= TSQ; ++t) {
        // msgs[bt,n,e,s] = prop @ We[e]^T + be[e] : batch 7, ksplit 4
        launch_gemm<0, 1>(prop_b, 0, SQ, We, (long)SQ * SQ, SQ, nullptr, 0,
                          scratch, 98304, SQ, nullptr, 0, 0, 96, SQ, SQ, 0, EQ, 4, stream);
        hipLaunchKernelGGL(reduce_k, dim3(96, EQ), dim3(256), 0, stream,
                           scratch, 4, 98304, SQ, be, (long)SQ, 0,
                           (float*)nullptr, 0L, 0, msgs_b, (long)SQ, EQ * SQ);
        // Gnm = msgs_e @ Wnm^T : batch 7, direct bf16 write
        launch_gemm<0, 0>(msgs_b, SQ, EQ * SQ, Wnm_b, 0, SQ, nullptr, 0,
                          nullptr, 0, 0, Gnm_b, 589824, 6 * SQ, 96, 6 * SQ, SQ, 0, EQ, 1, stream);
        // GRU scan: tt=0 elementwise, then 3 fused GEMM steps (bf16-carried h)
        hipLaunchKernelGGL(gru0, dim3(NROWS), dim3(256), 0, stream,
                           Gnm_b, cbias, bhh, h_b0, Wa, ba, gs);
        for (int tt = 1; tt < TQ; ++tt) {
            const u16* hin = (tt & 1) ? h_b0 : h_b1;
            u16* hout = (tt & 1) ? h_b1 : h_b0;
            hipLaunchKernelGGL(gh_gru, dim3(256), dim3(512), 0, stream,
                               hin, Whh_b, bhh, Gnm_b, cbias, hout, Wa, gs_part, tt);
        }
        hipLaunchKernelGGL(gs_fin_all, dim3(24), dim3(256), 0, stream, gs_part, ba, gs);
        if (t < TSQ) {
            hipLaunchKernelGGL(merged_amat_k, dim3(96), dim3(256), 0, stream,
                               gs, msgs_b, prop, amat_b);
            // rz partials : ksplit=8
            launch_gemm<0, 0>(amat_b, 0, 2 * SQ, Wrz_b, 0, 2 * SQ, nullptr, 0,
                              scratch, 196608, 2 * SQ, nullptr, 0, 0, 96, 2 * SQ, 2 * SQ, 0, 1, 8, stream);
            hipLaunchKernelGGL(rz_ahat_k, dim3(384), dim3(256), 0, stream,
                               scratch, brz, prop, amat_b, zbuf);
            // hhat partials : ksplit=8
            launch_gemm<0, 1>(amat_b, 0, 2 * SQ, Wh, 0, 2 * SQ, nullptr, 0,
                              scratch, 98304, SQ, nullptr, 0, 0, 96, SQ, 2 * SQ, 0, 1, 8, stream);
            hipLaunchKernelGGL(hhat_prop_k, dim3(384), dim3(256), 0, stream,
                               scratch, bh_, zbuf, prop, prop_b);
        }
    }

    hipLaunchKernelGGL(outputs_k, dim3(1), dim3(256), 0, stream, gs, (float*)d_out);
}

// Round 9
// 1131.100 us; speedup vs baseline: 5.3117x; 1.0037x over previous
//
#include <hip/hip_runtime.h>
#include <math.h>

// Problem constants
#define NQ 12
#define EQ 7
#define SQ 1024
#define TSQ 3
#define DIN 26400
#define BQ 2
#define TQ 4
#define BT 8          // B*T
#define BNN 288       // B*N*N
#define NROWS 2016    // E*BNN
#define G3S 3072      // 3*S
#define BK 32

typedef unsigned short u16;
typedef float f32x4 __attribute__((ext_vector_type(4)));
typedef short s16x8 __attribute__((ext_vector_type(8)));

__device__ __forceinline__ short bh(float f) {
    unsigned u = __float_as_uint(f);
    return (short)((u + 0x8000u) >> 16);
}
__device__ __forceinline__ float b2f(u16 u) {
    return __uint_as_float((unsigned)u << 16);
}
__device__ __forceinline__ s16x8 pack8(float4 a, float4 b) {
    s16x8 r;
    r[0] = bh(a.x); r[1] = bh(a.y); r[2] = bh(a.z); r[3] = bh(a.w);
    r[4] = bh(b.x); r[5] = bh(b.y); r[6] = bh(b.z); r[7] = bh(b.w);
    return r;
}
__device__ __forceinline__ void gload16(const void* g, void* l) {
    __builtin_amdgcn_global_load_lds(
        (const __attribute__((address_space(1))) unsigned*)g,
        (__attribute__((address_space(3))) unsigned*)l, 16, 0, 0);
}
__device__ inline float sigmoidf(float x) { return 1.f / (1.f + expf(-x)); }

// ================= bf16 MFMA GEMM, 64x128 tile: C = A(MxK) * B(NxK)^T =================
template<int AS32, int BS32>
__global__ __launch_bounds__(256)
void gemm_mfma(const void* __restrict__ Ap, long sAb, int lda,
               const void* __restrict__ Bp, long sBb, int ldb,
               const float* __restrict__ bias, long sBiasb,
               float* __restrict__ C, long sCb, int ldc,
               u16* __restrict__ Cb, long sCbb, int ldcb,
               int M, int Nn, int K, int act, int ksplit)
{
    __shared__ __align__(16) u16 lA[2][256][8];
    __shared__ __align__(16) u16 lB[2][512][8];

    const int z = blockIdx.z;
    const int az = z / ksplit;
    const int ks = z - az * ksplit;
    const int Ksl = K / ksplit;
    const int kbase = ks * Ksl;

    const char* Abase = (const char*)Ap + (long)az * sAb * (AS32 ? 4 : 2);
    const char* Bbase = (const char*)Bp + (long)az * sBb * (BS32 ? 4 : 2);

    const int tid = threadIdx.x;
    const int lane = tid & 63;
    const int wave = tid >> 6;
    const int row0 = blockIdx.x * 64;
    const int col0 = blockIdx.y * 128;
    const int wcol = wave * 32;

    const int akg = tid >> 6;
    long arow = row0 + (tid & 63); if (arow >= M) arow = M - 1;
    const int bkg0 = tid >> 7;
    const int s1 = tid + 256;
    const int bkg1 = s1 >> 7;
    long brow0 = col0 + (tid & 127); if (brow0 >= Nn) brow0 = Nn - 1;
    long brow1 = col0 + (s1 & 127);  if (brow1 >= Nn) brow1 = Nn - 1;

    const int arw32 = tid >> 2, akg32 = tid & 3;
    long ar32 = row0 + arw32; if (ar32 >= M) ar32 = M - 1;
    const int brw32 = tid >> 1, bh32 = tid & 1;
    long br32 = col0 + brw32; if (br32 >= Nn) br32 = Nn - 1;

    f32x4 acc[4][2] = {};

#define STAGE(b, kt) do {                                                     \
    const int k0_ = kbase + (kt) * BK;                                        \
    if constexpr (AS32) {                                                     \
        const float* A32 = (const float*)Abase;                               \
        const float* p0 = A32 + ar32 * lda + k0_ + akg32 * 8;                 \
        *(s16x8*)&lA[b][akg32 * 64 + arw32][0] =                              \
            pack8(*(const float4*)p0, *(const float4*)(p0 + 4));              \
    } else {                                                                  \
        const u16* A16 = (const u16*)Abase;                                   \
        gload16(A16 + arow * lda + k0_ + akg * 8, &lA[b][tid][0]);            \
    }                                                                         \
    if constexpr (BS32) {                                                     \
        const float* B32 = (const float*)Bbase;                               \
        const float* q0 = B32 + br32 * ldb + k0_ + bh32 * 16;                 \
        *(s16x8*)&lB[b][(bh32 * 2) * 128 + brw32][0] =                        \
            pack8(*(const float4*)q0, *(const float4*)(q0 + 4));              \
        *(s16x8*)&lB[b][(bh32 * 2 + 1) * 128 + brw32][0] =                    \
            pack8(*(const float4*)(q0 + 8), *(const float4*)(q0 + 12));       \
    } else {                                                                  \
        const u16* B16 = (const u16*)Bbase;                                   \
        gload16(B16 + brow0 * ldb + k0_ + bkg0 * 8, &lB[b][tid][0]);          \
        gload16(B16 + brow1 * ldb + k0_ + bkg1 * 8, &lB[b][s1][0]);           \
    }                                                                         \
} while (0)

    const int nk = Ksl / BK;
    STAGE(0, 0);
    __syncthreads();
    int buf = 0;
    const int kg = lane >> 4;
    const int lr = lane & 15;
    for (int kt = 0; kt < nk; ++kt) {
        if (kt + 1 < nk) STAGE(buf ^ 1, kt + 1);
        s16x8 af[4], bfr[2];
#pragma unroll
        for (int m = 0; m < 4; ++m)
            af[m] = *(const s16x8*)&lA[buf][kg * 64 + m * 16 + lr][0];
#pragma unroll
        for (int n = 0; n < 2; ++n)
            bfr[n] = *(const s16x8*)&lB[buf][kg * 128 + wcol + n * 16 + lr][0];
#pragma unroll
        for (int m = 0; m < 4; ++m)
#pragma unroll
            for (int n = 0; n < 2; ++n)
                acc[m][n] = __builtin_amdgcn_mfma_f32_16x16x32_bf16(af[m], bfr[n], acc[m][n], 0, 0, 0);
        __syncthreads();
        buf ^= 1;
    }
#undef STAGE

    const int ccol = lane & 15;
    const int crow = (lane >> 4) * 4;
#pragma unroll
    for (int n = 0; n < 2; ++n) {
        const int c = col0 + wcol + n * 16 + ccol;
        const float bv = bias ? bias[(long)az * sBiasb + c] : 0.f;
#pragma unroll
        for (int m = 0; m < 4; ++m) {
            const int rb = row0 + m * 16 + crow;
#pragma unroll
            for (int q = 0; q < 4; ++q) {
                const int r = rb + q;
                if (r >= M) continue;
                float v = acc[m][n][q] + bv;
                if (act == 1) v = 1.f / (1.f + expf(-v));
                else if (act == 2) v = tanhf(v);
                if (C)  C[(long)z * sCb + (long)r * ldc + c] = v;
                if (Cb) Cb[(long)z * sCbb + (long)r * ldcb + c] = (u16)bh(v);
            }
        }
    }
}

// ============ 128x128-tile fp32-in GEMM (Wnm setup) ============
__global__ __launch_bounds__(256)
void gemm128_f32(const float* __restrict__ A, int lda,
                 const float* __restrict__ Bm, int ldb,
                 float* __restrict__ C, long sCb, int ldc,
                 u16* __restrict__ Cb, int ldcb,
                 int M, int Nn, int K, int ksplit)
{
    __shared__ __align__(16) u16 lA[2][512][8];
    __shared__ __align__(16) u16 lB[2][512][8];

    const int ks = blockIdx.z;
    const int Ksl = K / ksplit;
    const int kbase = ks * Ksl;

    const int tid = threadIdx.x;
    const int lane = tid & 63;
    const int wave = tid >> 6;
    const int row0 = blockIdx.x * 128;
    const int col0 = blockIdx.y * 128;
    const int wrow = (wave >> 1) * 64;
    const int wcol = (wave & 1) * 64;

    const int rw = tid >> 1, hf = tid & 1;
    long ar = row0 + rw; if (ar >= M) ar = M - 1;
    long br = col0 + rw; if (br >= Nn) br = Nn - 1;

    f32x4 acc[4][4] = {};

#define STAGE128(b, kt) do {                                                  \
    const int k0_ = kbase + (kt) * BK;                                        \
    const float* p = A + ar * lda + k0_ + hf * 16;                            \
    *(s16x8*)&lA[b][(hf * 2) * 128 + rw][0] =                                 \
        pack8(*(const float4*)p, *(const float4*)(p + 4));                    \
    *(s16x8*)&lA[b][(hf * 2 + 1) * 128 + rw][0] =                             \
        pack8(*(const float4*)(p + 8), *(const float4*)(p + 12));             \
    const float* q = Bm + br * ldb + k0_ + hf * 16;                           \
    *(s16x8*)&lB[b][(hf * 2) * 128 + rw][0] =                                 \
        pack8(*(const float4*)q, *(const float4*)(q + 4));                    \
    *(s16x8*)&lB[b][(hf * 2 + 1) * 128 + rw][0] =                             \
        pack8(*(const float4*)(q + 8), *(const float4*)(q + 12));             \
} while (0)

    const int nk = Ksl / BK;
    STAGE128(0, 0);
    __syncthreads();
    int buf = 0;
    const int kg = lane >> 4;
    const int lr = lane & 15;
    for (int kt = 0; kt < nk; ++kt) {
        if (kt + 1 < nk) STAGE128(buf ^ 1, kt + 1);
        s16x8 af[4], bfr[4];
#pragma unroll
        for (int m = 0; m < 4; ++m)
            af[m] = *(const s16x8*)&lA[buf][kg * 128 + wrow + m * 16 + lr][0];
#pragma unroll
        for (int n = 0; n < 4; ++n)
            bfr[n] = *(const s16x8*)&lB[buf][kg * 128 + wcol + n * 16 + lr][0];
#pragma unroll
        for (int m = 0; m < 4; ++m)
#pragma unroll
            for (int n = 0; n < 4; ++n)
                acc[m][n] = __builtin_amdgcn_mfma_f32_16x16x32_bf16(af[m], bfr[n], acc[m][n], 0, 0, 0);
        __syncthreads();
        buf ^= 1;
    }
#undef STAGE128

    const int ccol = lane & 15;
    const int crow = (lane >> 4) * 4;
#pragma unroll
    for (int n = 0; n < 4; ++n) {
        const int c = col0 + wcol + n * 16 + ccol;
#pragma unroll
        for (int m = 0; m < 4; ++m) {
            const int rb = row0 + wrow + m * 16 + crow;
#pragma unroll
            for (int q = 0; q < 4; ++q) {
                const int r = rb + q;
                if (r >= M) continue;
                float v = acc[m][n][q];
                if (C)  C[(long)ks * sCb + (long)r * ldc + c] = v;
                if (Cb) Cb[(long)r * ldcb + c] = (u16)bh(v);
            }
        }
    }
}

// ============ fused gh-GEMM + GRU update + score partial (v5: 128x32 tile, 512 blocks) ============
// Grid 512 flat: lx = f>>5 (16 row-tiles of 128), ly = 4*(f&7)+((f>>3)&3) (32 col-tiles of 32).
// XCD f%8 sees 4 col-panels (768 KB of Whh). 56 KB LDS -> 2 blocks/CU, 4 waves/SIMD.
__global__ __launch_bounds__(512)
void gh_gru(const u16* __restrict__ hb_in, const u16* __restrict__ Whh_b,
            const float* __restrict__ bhh, const u16* __restrict__ Gnm_b,
            const float* __restrict__ cbias,
            u16* __restrict__ hb_out,
            const float* __restrict__ Wa, float* __restrict__ gs_part, int tt)
{
    __shared__ __align__(16) u16 lA[2][1024][8];   // 32KB: [k16 0..7][row 0..127]
    __shared__ __align__(16) u16 lB[2][768][8];    // 24KB: [k16 0..7][g*32+row 0..95]
    __shared__ float rowdot[128];

    const int f = blockIdx.x;
    const int ly = 4 * (f & 7) + ((f >> 3) & 3);   // 0..31 col-tile
    const int lx = f >> 5;                          // 0..15 row-tile
    const int row0 = lx * 128;
    const int col0 = ly * 32;

    const int tid = threadIdx.x;
    const int lane = tid & 63;
    const int wave = tid >> 6;     // 0..7
    const int wr = wave >> 1;      // 0..3 : 32-row slice
    const int wc = wave & 1;       // 0..1 : 16-col slice

    long arow = row0 + (tid & 127); if (arow >= NROWS) arow = NROWS - 1;

    // staging pointers (hoisted; +64 per K-step)
    const u16* aP0 = hb_in + arow * SQ + (tid >> 7) * 8;   // k16 = tid>>7 (0..3)
    const u16* aP1 = aP0 + 32;                              // k16 + 4
    const int s0b = tid;
    const int bk0 = s0b / 96, g0r = s0b - bk0 * 96;
    const u16* bP0 = Whh_b + (long)((g0r >> 5) * SQ + col0 + (g0r & 31)) * SQ + bk0 * 8;
    const int s1b = tid + 512;
    const int bk1 = s1b / 96, g1r = s1b - bk1 * 96;
    const u16* bP1 = Whh_b + (long)((g1r >> 5) * SQ + col0 + (g1r & 31)) * SQ + bk1 * 8;

    f32x4 acc[3][2] = {};    // [gate][m-frag], single n-frag of 16 cols

#define GSTAGE(b, kt) do {                                                    \
    const int k0_ = (kt) * 64;                                                \
    gload16(aP0 + k0_, &lA[b][tid][0]);                                       \
    gload16(aP1 + k0_, &lA[b][tid + 512][0]);                                 \
    gload16(bP0 + k0_, &lB[b][tid][0]);                                       \
    if (tid < 256) gload16(bP1 + k0_, &lB[b][tid + 512][0]);                  \
} while (0)

    GSTAGE(0, 0);
    __syncthreads();
    int buf = 0;
    const int kg = lane >> 4;
    const int lr = lane & 15;
    for (int kt = 0; kt < 16; ++kt) {
        if (kt + 1 < 16) GSTAGE(buf ^ 1, kt + 1);
#pragma unroll
        for (int kk = 0; kk < 2; ++kk) {
            const int k16 = kk * 4 + kg;
            s16x8 af[2], bfr[3];
#pragma unroll
            for (int m = 0; m < 2; ++m)
                af[m] = *(const s16x8*)&lA[buf][k16 * 128 + wr * 32 + m * 16 + lr][0];
#pragma unroll
            for (int g = 0; g < 3; ++g)
                bfr[g] = *(const s16x8*)&lB[buf][k16 * 96 + g * 32 + wc * 16 + lr][0];
#pragma unroll
            for (int g = 0; g < 3; ++g)
#pragma unroll
                for (int m = 0; m < 2; ++m)
                    acc[g][m] = __builtin_amdgcn_mfma_f32_16x16x32_bf16(af[m], bfr[g], acc[g][m], 0, 0, 0);
        }
        __syncthreads();
        buf ^= 1;
    }
#undef GSTAGE

    if (tid < 128) rowdot[tid] = 0.f;
    __syncthreads();

    const int ccol = lane & 15;
    const int crow4 = (lane >> 4) * 4;
    const int c = col0 + wc * 16 + ccol;
    float cbv[3], bhv[3];
#pragma unroll
    for (int g = 0; g < 3; ++g) {
        cbv[g] = cbias[g * SQ + c];
        bhv[g] = bhh[g * SQ + c];
    }

#pragma unroll
    for (int m = 0; m < 2; ++m) {
#pragma unroll
        for (int q = 0; q < 4; ++q) {
            const int row = row0 + wr * 32 + m * 16 + crow4 + q;
            const bool valid = (row < NROWS);
            float d = 0.f;
            if (valid) {
                const int e = row / BNN;
                const int rr = row - e * BNN;
                const int b_ = rr / 144;
                const int ni = (rr / 12) % 12;
                const int mi = rr % 12;
                const int bt = b_ * TQ + tt;
                const u16* gnp = Gnm_b + ((long)e * 96 + bt * 12 + ni) * 6144;
                const u16* gmp = Gnm_b + ((long)e * 96 + bt * 12 + mi) * 6144 + G3S;
                float gr  = acc[0][m][q] + bhv[0] + b2f(gnp[c]) + b2f(gmp[c]) + cbv[0];
                float gz  = acc[1][m][q] + bhv[1] + b2f(gnp[SQ + c]) + b2f(gmp[SQ + c]) + cbv[1];
                float ghn = acc[2][m][q] + bhv[2];
                float gin = b2f(gnp[2 * SQ + c]) + b2f(gmp[2 * SQ + c]) + cbv[2];
                float rg = sigmoidf(gr);
                float zg = sigmoidf(gz);
                float nn2 = tanhf(gin + rg * ghn);
                float hp = b2f(hb_in[(long)row * SQ + c]);
                float hn = (1.f - zg) * nn2 + zg * hp;
                hb_out[(long)row * SQ + c] = (u16)bh(hn);
                d = hn * Wa[(long)e * SQ + c];
            }
            d += __shfl_xor(d, 1); d += __shfl_xor(d, 2);
            d += __shfl_xor(d, 4); d += __shfl_xor(d, 8);
            if (valid && ccol == 0)
                atomicAdd(&rowdot[wr * 32 + m * 16 + crow4 + q], d);
        }
    }
    __syncthreads();
    if (tid < 128) {
        const int row = row0 + tid;
        if (row < NROWS) gs_part[((long)tt * 2048 + row) * 32 + ly] = rowdot[tid];
    }
}

// ============ GRU step tt=0, elementwise (h0 ~ 0: gh0 = bhh; h1 = (1-z)*n) ============
__global__ __launch_bounds__(256)
void gru0(const u16* __restrict__ Gnm_b, const float* __restrict__ cbias,
          const float* __restrict__ bhh,
          u16* __restrict__ hb_out,
          const float* __restrict__ Wa, const float* __restrict__ ba,
          float* __restrict__ gs)
{
    const int row = blockIdx.x;
    const int e = row / BNN;
    const int r = row % BNN;
    const int b_ = r / 144;
    const int ni = (r / 12) % 12;
    const int mi = r % 12;
    const int bt = b_ * TQ;

    const u16* gnp = Gnm_b + ((long)e * 96 + bt * 12 + ni) * 6144;
    const u16* gmp = Gnm_b + ((long)e * 96 + bt * 12 + mi) * 6144 + G3S;
    u16* hpb = hb_out + (long)row * SQ;

    const int s = threadIdx.x * 4;

    ushort4 nR = *(const ushort4*)(gnp + s);
    ushort4 nZ = *(const ushort4*)(gnp + SQ + s);
    ushort4 nN = *(const ushort4*)(gnp + 2 * SQ + s);
    ushort4 mR = *(const ushort4*)(gmp + s);
    ushort4 mZ = *(const ushort4*)(gmp + SQ + s);
    ushort4 mN = *(const ushort4*)(gmp + 2 * SQ + s);
    float4 cbR = *(const float4*)(cbias + s);
    float4 cbZ = *(const float4*)(cbias + SQ + s);
    float4 cbN = *(const float4*)(cbias + 2 * SQ + s);
    float4 bhR = *(const float4*)(bhh + s);
    float4 bhZ = *(const float4*)(bhh + SQ + s);
    float4 bhN = *(const float4*)(bhh + 2 * SQ + s);
    float4 wv  = *(const float4*)(Wa + (long)e * SQ + s);

    float4 hn4;
    float dot = 0.f;

#define GRU0_COMP(c, u)                                                       \
    {                                                                         \
        float rg = sigmoidf(b2f(nR.u) + b2f(mR.u) + cbR.c + bhR.c);           \
        float zg = sigmoidf(b2f(nZ.u) + b2f(mZ.u) + cbZ.c + bhZ.c);           \
        float nn = tanhf(b2f(nN.u) + b2f(mN.u) + cbN.c + rg * bhN.c);         \
        float hn = (1.f - zg) * nn;                                           \
        hn4.c = hn;                                                           \
        dot += hn * wv.c;                                                     \
    }
    GRU0_COMP(x, x) GRU0_COMP(y, y) GRU0_COMP(z, z) GRU0_COMP(w, w)
#undef GRU0_COMP

    ushort4 hb4;
    hb4.x = (u16)bh(hn4.x); hb4.y = (u16)bh(hn4.y);
    hb4.z = (u16)bh(hn4.z); hb4.w = (u16)bh(hn4.w);
    *(ushort4*)(hpb + s) = hb4;

    for (int off = 32; off > 0; off >>= 1) dot += __shfl_down(dot, off);
    __shared__ float red[4];
    if ((threadIdx.x & 63) == 0) red[threadIdx.x >> 6] = dot;
    __syncthreads();
    if (threadIdx.x == 0) {
        float tot = red[0] + red[1] + red[2] + red[3] + ba[e];
        gs[((bt * 12 + ni) * 12 + mi) * EQ + e] = sigmoidf(tot);
    }
}

// ---------- gs finalize for tt=1..3 (32 partials) ----------
__global__ void gs_fin_all(const float* __restrict__ gs_part, const float* __restrict__ ba,
                           float* __restrict__ gs)
{
    int idx = blockIdx.x * 256 + threadIdx.x;
    if (idx >= 3 * 2048) return;
    const int tt = 1 + (idx >> 11);
    const int row = idx & 2047;
    if (row >= NROWS) return;
    float s = 0.f;
#pragma unroll
    for (int j = 0; j < 32; ++j) s += gs_part[((long)tt * 2048 + row) * 32 + j];
    const int e = row / BNN;
    const int rr = row - e * BNN;
    const int b_ = rr / 144;
    const int ni = (rr / 12) % 12;
    const int mi = rr % 12;
    const int bt = b_ * TQ + tt;
    gs[((bt * 12 + ni) * 12 + mi) * EQ + e] = sigmoidf(s + ba[e]);
}

// ---------- generic split-K reduce ----------
__global__ __launch_bounds__(256)
void reduce_k(const float* __restrict__ part, int ksplit, int mn, int Nn,
              const float* __restrict__ bias, long sBiasB, int act,
              float* __restrict__ Cf, long sCfB, int ldcf,
              u16* __restrict__ Cb, long sCbB, int ldcb)
{
    int i4 = blockIdx.x * 256 + threadIdx.x;
    int total4 = mn >> 2;
    if (i4 >= total4) return;
    int b = blockIdx.y;
    const float4* p4 = (const float4*)part;
    float4 s = make_float4(0.f, 0.f, 0.f, 0.f);
    for (int ks = 0; ks < ksplit; ++ks) {
        float4 v = p4[(long)(b * ksplit + ks) * total4 + i4];
        s.x += v.x; s.y += v.y; s.z += v.z; s.w += v.w;
    }
    int i = i4 << 2;
    int r = i / Nn, c = i % Nn;
    if (bias) {
        float4 bv = *(const float4*)(bias + (long)b * sBiasB + c);
        s.x += bv.x; s.y += bv.y; s.z += bv.z; s.w += bv.w;
    }
    if (act == 1) {
        s.x = sigmoidf(s.x); s.y = sigmoidf(s.y); s.z = sigmoidf(s.z); s.w = sigmoidf(s.w);
    } else if (act == 2) {
        s.x = tanhf(s.x); s.y = tanhf(s.y); s.z = tanhf(s.z); s.w = tanhf(s.w);
    }
    if (Cf) *(float4*)(Cf + (long)b * sCfB + (long)r * ldcf + c) = s;
    if (Cb) {
        ushort4 o;
        o.x = (u16)bh(s.x); o.y = (u16)bh(s.y); o.z = (u16)bh(s.z); o.w = (u16)bh(s.w);
        *(ushort4*)(Cb + (long)b * sCbB + (long)r * ldcb + c) = o;
    }
}

// ---------- fused rz split-K reduce + sigmoid + ahat + zbuf ----------
__global__ __launch_bounds__(256)
void rz_ahat_k(const float* __restrict__ part, const float* __restrict__ brz,
               const float* __restrict__ prop, u16* __restrict__ amat_b,
               float* __restrict__ zbuf)
{
    int i = blockIdx.x * 256 + threadIdx.x;   // 0..98303
    int rrow = i >> 10, c = i & 1023;
    float sr = 0.f, sz = 0.f;
#pragma unroll
    for (int ks = 0; ks < 8; ++ks) {
        const float* p = part + (long)ks * 196608 + (long)rrow * 2048;
        sr += p[c]; sz += p[1024 + c];
    }
    float r = sigmoidf(sr + brz[c]);
    float z = sigmoidf(sz + brz[1024 + c]);
    amat_b[(long)rrow * 2048 + 1024 + c] = (u16)bh(r * prop[i]);
    zbuf[i] = z;
}

// ---------- fused hhat split-K reduce + tanh + prop update ----------
__global__ __launch_bounds__(256)
void hhat_prop_k(const float* __restrict__ part, const float* __restrict__ bh_,
                 const float* __restrict__ zbuf,
                 float* __restrict__ prop, u16* __restrict__ prop_b)
{
    int i = blockIdx.x * 256 + threadIdx.x;   // 0..98303
    float s = 0.f;
#pragma unroll
    for (int ks = 0; ks < 8; ++ks) s += part[(long)ks * 98304 + i];
    float hhat = tanhf(s + bh_[i & 1023]);
    float z = zbuf[i];
    float v = (1.f - z) * prop[i] + z * hhat;
    prop[i] = v;
    prop_b[i] = (u16)bh(v);
}

__global__ void cvt_bf16_k(const float* __restrict__ src, u16* __restrict__ dst, int n4)
{
    int i = blockIdx.x * 256 + threadIdx.x;
    if (i >= n4) return;
    float4 v = ((const float4*)src)[i];
    ushort4 o;
    o.x = (u16)bh(v.x); o.y = (u16)bh(v.y); o.z = (u16)bh(v.z); o.w = (u16)bh(v.w);
    ((ushort4*)dst)[i] = o;
}

__global__ __launch_bounds__(256)
void transpose_wc(const float* __restrict__ Wcomp, float* __restrict__ W1T, float* __restrict__ W2T)
{
    __shared__ float t1[32][33];
    __shared__ float t2[32][33];
    const int tx = threadIdx.x & 31;
    const int ty = threadIdx.x >> 5;
    const int d0 = blockIdx.x * 32;
    const int s0 = blockIdx.y * 32;
#pragma unroll
    for (int k = 0; k < 4; ++k) {
        int d = d0 + ty + k * 8;
        t1[ty + k * 8][tx] = Wcomp[(long)d * 2048 + s0 + tx];
        t2[ty + k * 8][tx] = Wcomp[(long)d * 2048 + 1024 + s0 + tx];
    }
    __syncthreads();
#pragma unroll
    for (int k = 0; k < 4; ++k) {
        int s = s0 + ty + k * 8;
        W1T[(long)s * 1024 + d0 + tx] = t1[tx][ty + k * 8];
        W2T[(long)s * 1024 + d0 + tx] = t2[tx][ty + k * 8];
    }
}

__global__ void pack_rz(const float* __restrict__ Wr, const float* __restrict__ Wz,
                        const float* __restrict__ br, const float* __restrict__ bz,
                        u16* __restrict__ Wrz, float* __restrict__ brz)
{
    int i4 = blockIdx.x * 256 + threadIdx.x;
    if (i4 < 512) {
        int c = i4 * 4;
        float4 b = (c < 1024) ? *(const float4*)(br + c) : *(const float4*)(bz + c - 1024);
        *(float4*)(brz + c) = b;
    }
    if (i4 >= 1048576) return;
    int i = i4 * 4;
    int j = i >> 11;
    int c = i & 2047;
    float4 v = (j < 1024) ? *(const float4*)(Wr + (long)j * 2048 + c)
                          : *(const float4*)(Wz + (long)(j - 1024) * 2048 + c);
    ushort4 o;
    o.x = (u16)bh(v.x); o.y = (u16)bh(v.y); o.z = (u16)bh(v.z); o.w = (u16)bh(v.w);
    *(ushort4*)(Wrz + i) = o;
}

__global__ void cbias_k(const float* __restrict__ Wih, const float* __restrict__ bih,
                        const float* __restrict__ bcomp, float* __restrict__ cbias)
{
    int g = blockIdx.x * blockDim.x + threadIdx.x;
    if (g >= G3S) return;
    const float* w = Wih + (long)g * SQ;
    float s = 0.f;
    for (int k = 0; k < SQ; k += 4) {
        float4 wv = *(const float4*)(w + k);
        float4 bv = *(const float4*)(bcomp + k);
        s += wv.x * bv.x + wv.y * bv.y + wv.z * bv.z + wv.w * bv.w;
    }
    cbias[g] = s + bih[g];
}

// ---------------- merged + amat fused ----------------
__global__ __launch_bounds__(256)
void merged_amat_k(const float* __restrict__ gs, const u16* __restrict__ msgs_b,
                   const float* __restrict__ prop, u16* __restrict__ amat_b)
{
    const int bn = blockIdx.x;
    const int bt = bn / 12;
    __shared__ float g[84];
    if (threadIdx.x < 84) g[threadIdx.x] = gs[bn * 84 + threadIdx.x];
    __syncthreads();
    const int s = threadIdx.x * 4;
    float4 acc = make_float4(0.f, 0.f, 0.f, 0.f);
    for (int j = 0; j < 84; ++j) {
        const ushort4 mv = *(const ushort4*)(msgs_b + ((long)(bt * 84 + j)) * SQ + s);
        float gj = g[j];
        acc.x += gj * b2f(mv.x);
        acc.y += gj * b2f(mv.y);
        acc.z += gj * b2f(mv.z);
        acc.w += gj * b2f(mv.w);
    }
    ushort4 o;
    o.x = (u16)bh(acc.x); o.y = (u16)bh(acc.y); o.z = (u16)bh(acc.z); o.w = (u16)bh(acc.w);
    *(ushort4*)(amat_b + (long)bn * 2048 + s) = o;
    float4 pv = *(const float4*)(prop + (long)bn * SQ + s);
    ushort4 o2;
    o2.x = (u16)bh(pv.x); o2.y = (u16)bh(pv.y); o2.z = (u16)bh(pv.z); o2.w = (u16)bh(pv.w);
    *(ushort4*)(amat_b + (long)bn * 2048 + 1024 + s) = o2;
}

// ---------------- final outputs ----------------
__global__ __launch_bounds__(256)
void outputs_k(const float* __restrict__ gs, float* __restrict__ out)
{
    __shared__ float s_act[672];
    __shared__ float s_asum[96];
    int tid = threadIdx.x;
    for (int idx = tid; idx < 672; idx += 256) {
        int bn = idx / 7, e = idx % 7;
        float sum = 0.f;
        for (int m = 0; m < 12; ++m) {
            float g0 = gs[bn * 84 + m * 7];
            sum += (1.f - g0) * gs[bn * 84 + m * 7 + e];
        }
        s_act[idx] = sum;
        out[idx] = sum;
    }
    for (int idx = tid; idx < 96; idx += 256) {
        float a = 0.f;
        for (int m = 0; m < 12; ++m) a += 1.f - gs[idx * 84 + m * 7];
        s_asum[idx] = a;
    }
    for (int idx = tid; idx < 1152; idx += 256) {
        int bn = idx / 12, m = idx % 12;
        out[720 + idx] = 1.f - gs[bn * 84 + m * 7];
    }
    __syncthreads();
    if (tid < 8) {
        float tmp[6];
        float mx = -1e30f;
        for (int e = 1; e < 7; ++e) {
            float sum = 0.f;
            for (int n = 0; n < 12; ++n) {
                int bn = tid * 12 + n;
                sum += s_act[bn * 7 + e] * s_asum[bn];
            }
            tmp[e - 1] = sum;
            mx = fmaxf(mx, sum);
        }
        float den = 0.f;
        for (int e = 0; e < 6; ++e) { tmp[e] = expf(tmp[e] - mx); den += tmp[e]; }
        for (int e = 0; e < 6; ++e) out[672 + tid * 6 + e] = tmp[e] / den;
    }
}

// ---------------- host ----------------
template<int AS32, int BS32>
static void launch_gemm(const void* A, long sAb, int lda,
                        const void* B, long sBb, int ldb,
                        const float* bias, long sBiasb,
                        float* C, long sCb, int ldc,
                        u16* Cb, long sCbb, int ldcb,
                        int M, int Nn, int K, int act, int batch, int ksplit,
                        hipStream_t stream)
{
    dim3 grid((M + 63) / 64, (Nn + 127) / 128, batch * ksplit);
    gemm_mfma<AS32, BS32><<<grid, dim3(256), 0, stream>>>(
        A, sAb, lda, B, sBb, ldb, bias, sBiasb, C, sCb, ldc, Cb, sCbb, ldcb,
        M, Nn, K, act, ksplit);
}

extern "C" void kernel_launch(void* const* d_in, const int* in_sizes, int n_in,
                              void* d_out, int out_size, void* d_ws, size_t ws_size,
                              hipStream_t stream)
{
    const float* pose  = (const float*)d_in[0];
    const float* Wc    = (const float*)d_in[5];
    const float* bc    = (const float*)d_in[6];
    const float* We    = (const float*)d_in[7];
    const float* be    = (const float*)d_in[8];
    const float* Wcomp = (const float*)d_in[9];
    const float* bcomp = (const float*)d_in[10];
    const float* Wr    = (const float*)d_in[11];
    const float* br    = (const float*)d_in[12];
    const float* Wz    = (const float*)d_in[13];
    const float* bz    = (const float*)d_in[14];
    const float* Wh    = (const float*)d_in[15];
    const float* bh_   = (const float*)d_in[16];
    const float* Wih   = (const float*)d_in[17];
    const float* Whh   = (const float*)d_in[18];
    const float* bih   = (const float*)d_in[19];
    const float* bhh   = (const float*)d_in[20];
    const float* Wa    = (const float*)d_in[21];
    const float* ba    = (const float*)d_in[22];

    float* ws = (float*)d_ws;
    // fp32 region
    float* prop    = ws;                    // 98304
    float* cbias   = prop + 98304;          // 3072
    float* scratch = cbias + 3072;          // 8257536  (split-K partials / W1T/W2T)
    float* gs      = scratch + 8257536;     // 8064
    float* zbuf    = gs + 8064;             // 98304
    float* brz     = zbuf + 98304;          // 2048
    float* gs_part = brz + 2048;            // 262144 (4 x 2048 x 32)
    float* fend    = gs_part + 262144;
    // bf16 region
    u16* Whh_b  = (u16*)fend;               // 3145728
    u16* Wnm_b  = Whh_b + 3145728;          // 6291456  (6144 x 1024)
    u16* Wrz_b  = Wnm_b + 6291456;          // 4194304
    u16* Gnm_b  = Wrz_b + 4194304;          // 4128768  (7 x 96 x 6144)
    u16* msgs_b = Gnm_b + 4128768;          // 688128
    u16* h_b0   = msgs_b + 688128;          // 2064384
    u16* h_b1   = h_b0 + 2064384;           // 2064384
    u16* prop_b = h_b1 + 2064384;           // 98304
    u16* amat_b = prop_b + 98304;           // 196608
    u16* pose_b = amat_b + 196608;          // 2534400
    u16* Wc_b   = pose_b + 2534400;         // 27033600

    float* W1T = scratch;                   // transient
    float* W2T = scratch + 1048576;         // transient

    // ---- once per call ----
    hipLaunchKernelGGL(cvt_bf16_k, dim3(3072), dim3(256), 0, stream, Whh, Whh_b, 786432);
    hipLaunchKernelGGL(cvt_bf16_k, dim3(2475), dim3(256), 0, stream, pose, pose_b, 633600);
    hipLaunchKernelGGL(cvt_bf16_k, dim3(26400), dim3(256), 0, stream, Wc, Wc_b, 6758400);
    hipLaunchKernelGGL(cbias_k, dim3(12), dim3(256), 0, stream, Wih, bih, bcomp, cbias);
    hipLaunchKernelGGL(transpose_wc, dim3(32, 32), dim3(256), 0, stream, Wcomp, W1T, W2T);
    hipLaunchKernelGGL(pack_rz, dim3(4096), dim3(256), 0, stream, Wr, Wz, br, bz, Wrz_b, brz);
    // Wnm rows 0..3071 = Wih @ W1T^T ; rows 3072..6143 = Wih @ W2T^T
    gemm128_f32<<<dim3(24, 8, 1), dim3(256), 0, stream>>>(
        Wih, SQ, W1T, SQ, nullptr, 0, SQ, Wnm_b, SQ, G3S, SQ, SQ, 1);
    gemm128_f32<<<dim3(24, 8, 1), dim3(256), 0, stream>>>(
        Wih, SQ, W2T, SQ, nullptr, 0, SQ, Wnm_b + (long)G3S * SQ, SQ, G3S, SQ, SQ, 1);
    // prop = pose @ Wc^T + bc : bf16 operands, ksplit=55
    launch_gemm<0, 0>(pose_b, 0, DIN, Wc_b, 0, DIN, nullptr, 0,
                      scratch, 98304, SQ, nullptr, 0, 0, 96, SQ, DIN, 0, 1, 55, stream);
    hipLaunchKernelGGL(reduce_k, dim3(96, 1), dim3(256), 0, stream,
                       scratch, 55, 98304, SQ, bc, 0L, 0,
                       prop, 0L, SQ, prop_b, 0L, SQ);

    for (int t = 0; t <= TSQ; ++t) {
        // msgs[bt,n,e,s] = prop @ We[e]^T + be[e] : batch 7, ksplit 4
        launch_gemm<0, 1>(prop_b, 0, SQ, We, (long)SQ * SQ, SQ, nullptr, 0,
                          scratch, 98304, SQ, nullptr, 0, 0, 96, SQ, SQ, 0, EQ, 4, stream);
        hipLaunchKernelGGL(reduce_k, dim3(96, EQ), dim3(256), 0, stream,
                           scratch, 4, 98304, SQ, be, (long)SQ, 0,
                           (float*)nullptr, 0L, 0, msgs_b, (long)SQ, EQ * SQ);
        // Gnm = msgs_e @ Wnm^T : batch 7, direct bf16 write
        launch_gemm<0, 0>(msgs_b, SQ, EQ * SQ, Wnm_b, 0, SQ, nullptr, 0,
                          nullptr, 0, 0, Gnm_b, 589824, 6 * SQ, 96, 6 * SQ, SQ, 0, EQ, 1, stream);
        // GRU scan: tt=0 elementwise, then 3 fused GEMM steps (bf16-carried h)
        hipLaunchKernelGGL(gru0, dim3(NROWS), dim3(256), 0, stream,
                           Gnm_b, cbias, bhh, h_b0, Wa, ba, gs);
        for (int tt = 1; tt < TQ; ++tt) {
            const u16* hin = (tt & 1) ? h_b0 : h_b1;
            u16* hout = (tt & 1) ? h_b1 : h_b0;
            hipLaunchKernelGGL(gh_gru, dim3(512), dim3(512), 0, stream,
                               hin, Whh_b, bhh, Gnm_b, cbias, hout, Wa, gs_part, tt);
        }
        hipLaunchKernelGGL(gs_fin_all, dim3(24), dim3(256), 0, stream, gs_part, ba, gs);
        if (t < TSQ) {
            hipLaunchKernelGGL(merged_amat_k, dim3(96), dim3(256), 0, stream,
                               gs, msgs_b, prop, amat_b);
            // rz partials : ksplit=8
            launch_gemm<0, 0>(amat_b, 0, 2 * SQ, Wrz_b, 0, 2 * SQ, nullptr, 0,
                              scratch, 196608, 2 * SQ, nullptr, 0, 0, 96, 2 * SQ, 2 * SQ, 0, 1, 8, stream);
            hipLaunchKernelGGL(rz_ahat_k, dim3(384), dim3(256), 0, stream,
                               scratch, brz, prop, amat_b, zbuf);
            // hhat partials : ksplit=8
            launch_gemm<0, 1>(amat_b, 0, 2 * SQ, Wh, 0, 2 * SQ, nullptr, 0,
                              scratch, 98304, SQ, nullptr, 0, 0, 96, SQ, 2 * SQ, 0, 1, 8, stream);
            hipLaunchKernelGGL(hhat_prop_k, dim3(384), dim3(256), 0, stream,
                               scratch, bh_, zbuf, prop, prop_b);
        }
    }

    hipLaunchKernelGGL(outputs_k, dim3(1), dim3(256), 0, stream, gs, (float*)d_out);
}

// Round 10
// 1124.538 us; speedup vs baseline: 5.3427x; 1.0058x over previous
//
#include <hip/hip_runtime.h>
#include <math.h>

// Problem constants
#define NQ 12
#define EQ 7
#define SQ 1024
#define TSQ 3
#define DIN 26400
#define BQ 2
#define TQ 4
#define BT 8          // B*T
#define BNN 288       // B*N*N
#define NROWS 2016    // E*BNN
#define G3S 3072      // 3*S
#define BK 32

typedef unsigned short u16;
typedef float f32x4 __attribute__((ext_vector_type(4)));
typedef short s16x8 __attribute__((ext_vector_type(8)));

__device__ __forceinline__ short bh(float f) {
    unsigned u = __float_as_uint(f);
    return (short)((u + 0x8000u) >> 16);
}
__device__ __forceinline__ float b2f(u16 u) {
    return __uint_as_float((unsigned)u << 16);
}
__device__ __forceinline__ s16x8 pack8(float4 a, float4 b) {
    s16x8 r;
    r[0] = bh(a.x); r[1] = bh(a.y); r[2] = bh(a.z); r[3] = bh(a.w);
    r[4] = bh(b.x); r[5] = bh(b.y); r[6] = bh(b.z); r[7] = bh(b.w);
    return r;
}
__device__ __forceinline__ void gload16(const void* g, void* l) {
    __builtin_amdgcn_global_load_lds(
        (const __attribute__((address_space(1))) unsigned*)g,
        (__attribute__((address_space(3))) unsigned*)l, 16, 0, 0);
}
__device__ inline float sigmoidf(float x) { return 1.f / (1.f + expf(-x)); }

// ================= bf16 MFMA GEMM, 64x128 tile: C = A(MxK) * B(NxK)^T =================
// Pure-bf16 path (<0,0>) uses counted-vmcnt pipeline: loads stay in flight across barriers.
template<int AS32, int BS32>
__global__ __launch_bounds__(256)
void gemm_mfma(const void* __restrict__ Ap, long sAb, int lda,
               const void* __restrict__ Bp, long sBb, int ldb,
               const float* __restrict__ bias, long sBiasb,
               float* __restrict__ C, long sCb, int ldc,
               u16* __restrict__ Cb, long sCbb, int ldcb,
               int M, int Nn, int K, int act, int ksplit)
{
    __shared__ __align__(16) u16 lA[2][256][8];
    __shared__ __align__(16) u16 lB[2][512][8];

    const int z = blockIdx.z;
    const int az = z / ksplit;
    const int ks = z - az * ksplit;
    const int Ksl = K / ksplit;
    const int kbase = ks * Ksl;

    const char* Abase = (const char*)Ap + (long)az * sAb * (AS32 ? 4 : 2);
    const char* Bbase = (const char*)Bp + (long)az * sBb * (BS32 ? 4 : 2);

    const int tid = threadIdx.x;
    const int lane = tid & 63;
    const int wave = tid >> 6;
    const int row0 = blockIdx.x * 64;
    const int col0 = blockIdx.y * 128;
    const int wcol = wave * 32;

    const int akg = tid >> 6;
    long arow = row0 + (tid & 63); if (arow >= M) arow = M - 1;
    const int bkg0 = tid >> 7;
    const int s1 = tid + 256;
    const int bkg1 = s1 >> 7;
    long brow0 = col0 + (tid & 127); if (brow0 >= Nn) brow0 = Nn - 1;
    long brow1 = col0 + (s1 & 127);  if (brow1 >= Nn) brow1 = Nn - 1;

    const int arw32 = tid >> 2, akg32 = tid & 3;
    long ar32 = row0 + arw32; if (ar32 >= M) ar32 = M - 1;
    const int brw32 = tid >> 1, bh32 = tid & 1;
    long br32 = col0 + brw32; if (br32 >= Nn) br32 = Nn - 1;

    f32x4 acc[4][2] = {};

#define STAGE(b, kt) do {                                                     \
    const int k0_ = kbase + (kt) * BK;                                        \
    if constexpr (AS32) {                                                     \
        const float* A32 = (const float*)Abase;                               \
        const float* p0 = A32 + ar32 * lda + k0_ + akg32 * 8;                 \
        *(s16x8*)&lA[b][akg32 * 64 + arw32][0] =                              \
            pack8(*(const float4*)p0, *(const float4*)(p0 + 4));              \
    } else {                                                                  \
        const u16* A16 = (const u16*)Abase;                                   \
        gload16(A16 + arow * lda + k0_ + akg * 8, &lA[b][tid][0]);            \
    }                                                                         \
    if constexpr (BS32) {                                                     \
        const float* B32 = (const float*)Bbase;                               \
        const float* q0 = B32 + br32 * ldb + k0_ + bh32 * 16;                 \
        *(s16x8*)&lB[b][(bh32 * 2) * 128 + brw32][0] =                        \
            pack8(*(const float4*)q0, *(const float4*)(q0 + 4));              \
        *(s16x8*)&lB[b][(bh32 * 2 + 1) * 128 + brw32][0] =                    \
            pack8(*(const float4*)(q0 + 8), *(const float4*)(q0 + 12));       \
    } else {                                                                  \
        const u16* B16 = (const u16*)Bbase;                                   \
        gload16(B16 + brow0 * ldb + k0_ + bkg0 * 8, &lB[b][tid][0]);          \
        gload16(B16 + brow1 * ldb + k0_ + bkg1 * 8, &lB[b][s1][0]);           \
    }                                                                         \
} while (0)

#define MFMA_BODY(bufi)                                                       \
    {                                                                         \
        s16x8 af[4], bfr[2];                                                  \
        _Pragma("unroll")                                                     \
        for (int m = 0; m < 4; ++m)                                           \
            af[m] = *(const s16x8*)&lA[bufi][kg * 64 + m * 16 + lr][0];       \
        _Pragma("unroll")                                                     \
        for (int n = 0; n < 2; ++n)                                           \
            bfr[n] = *(const s16x8*)&lB[bufi][kg * 128 + wcol + n * 16 + lr][0]; \
        _Pragma("unroll")                                                     \
        for (int m = 0; m < 4; ++m)                                           \
            _Pragma("unroll")                                                 \
            for (int n = 0; n < 2; ++n)                                       \
                acc[m][n] = __builtin_amdgcn_mfma_f32_16x16x32_bf16(af[m], bfr[n], acc[m][n], 0, 0, 0); \
    }

    const int nk = Ksl / BK;
    const int kg = lane >> 4;
    const int lr = lane & 15;
    int buf = 0;

    STAGE(0, 0);
    if constexpr (!AS32 && !BS32) {
        // counted-vmcnt pipeline: 3 gloads/thread/step stay in flight across the barrier
        for (int kt = 0; kt < nk; ++kt) {
            if (kt + 1 < nk) {
                STAGE(buf ^ 1, kt + 1);
                asm volatile("s_waitcnt vmcnt(3)" ::: "memory");
            } else {
                asm volatile("s_waitcnt vmcnt(0)" ::: "memory");
            }
            __builtin_amdgcn_s_barrier();
            __builtin_amdgcn_sched_barrier(0);
            MFMA_BODY(buf);
            __builtin_amdgcn_s_barrier();
            buf ^= 1;
        }
    } else {
        __syncthreads();
        for (int kt = 0; kt < nk; ++kt) {
            if (kt + 1 < nk) STAGE(buf ^ 1, kt + 1);
            MFMA_BODY(buf);
            __syncthreads();
            buf ^= 1;
        }
    }
#undef STAGE
#undef MFMA_BODY

    const int ccol = lane & 15;
    const int crow = (lane >> 4) * 4;
#pragma unroll
    for (int n = 0; n < 2; ++n) {
        const int c = col0 + wcol + n * 16 + ccol;
        const float bv = bias ? bias[(long)az * sBiasb + c] : 0.f;
#pragma unroll
        for (int m = 0; m < 4; ++m) {
            const int rb = row0 + m * 16 + crow;
#pragma unroll
            for (int q = 0; q < 4; ++q) {
                const int r = rb + q;
                if (r >= M) continue;
                float v = acc[m][n][q] + bv;
                if (act == 1) v = 1.f / (1.f + expf(-v));
                else if (act == 2) v = tanhf(v);
                if (C)  C[(long)z * sCb + (long)r * ldc + c] = v;
                if (Cb) Cb[(long)z * sCbb + (long)r * ldcb + c] = (u16)bh(v);
            }
        }
    }
}

// ============ 128x128-tile fp32-in GEMM (Wnm setup) ============
__global__ __launch_bounds__(256)
void gemm128_f32(const float* __restrict__ A, int lda,
                 const float* __restrict__ Bm, int ldb,
                 float* __restrict__ C, long sCb, int ldc,
                 u16* __restrict__ Cb, int ldcb,
                 int M, int Nn, int K, int ksplit)
{
    __shared__ __align__(16) u16 lA[2][512][8];
    __shared__ __align__(16) u16 lB[2][512][8];

    const int ks = blockIdx.z;
    const int Ksl = K / ksplit;
    const int kbase = ks * Ksl;

    const int tid = threadIdx.x;
    const int lane = tid & 63;
    const int wave = tid >> 6;
    const int row0 = blockIdx.x * 128;
    const int col0 = blockIdx.y * 128;
    const int wrow = (wave >> 1) * 64;
    const int wcol = (wave & 1) * 64;

    const int rw = tid >> 1, hf = tid & 1;
    long ar = row0 + rw; if (ar >= M) ar = M - 1;
    long br = col0 + rw; if (br >= Nn) br = Nn - 1;

    f32x4 acc[4][4] = {};

#define STAGE128(b, kt) do {                                                  \
    const int k0_ = kbase + (kt) * BK;                                        \
    const float* p = A + ar * lda + k0_ + hf * 16;                            \
    *(s16x8*)&lA[b][(hf * 2) * 128 + rw][0] =                                 \
        pack8(*(const float4*)p, *(const float4*)(p + 4));                    \
    *(s16x8*)&lA[b][(hf * 2 + 1) * 128 + rw][0] =                             \
        pack8(*(const float4*)(p + 8), *(const float4*)(p + 12));             \
    const float* q = Bm + br * ldb + k0_ + hf * 16;                           \
    *(s16x8*)&lB[b][(hf * 2) * 128 + rw][0] =                                 \
        pack8(*(const float4*)q, *(const float4*)(q + 4));                    \
    *(s16x8*)&lB[b][(hf * 2 + 1) * 128 + rw][0] =                             \
        pack8(*(const float4*)(q + 8), *(const float4*)(q + 12));             \
} while (0)

    const int nk = Ksl / BK;
    STAGE128(0, 0);
    __syncthreads();
    int buf = 0;
    const int kg = lane >> 4;
    const int lr = lane & 15;
    for (int kt = 0; kt < nk; ++kt) {
        if (kt + 1 < nk) STAGE128(buf ^ 1, kt + 1);
        s16x8 af[4], bfr[4];
#pragma unroll
        for (int m = 0; m < 4; ++m)
            af[m] = *(const s16x8*)&lA[buf][kg * 128 + wrow + m * 16 + lr][0];
#pragma unroll
        for (int n = 0; n < 4; ++n)
            bfr[n] = *(const s16x8*)&lB[buf][kg * 128 + wcol + n * 16 + lr][0];
#pragma unroll
        for (int m = 0; m < 4; ++m)
#pragma unroll
            for (int n = 0; n < 4; ++n)
                acc[m][n] = __builtin_amdgcn_mfma_f32_16x16x32_bf16(af[m], bfr[n], acc[m][n], 0, 0, 0);
        __syncthreads();
        buf ^= 1;
    }
#undef STAGE128

    const int ccol = lane & 15;
    const int crow = (lane >> 4) * 4;
#pragma unroll
    for (int n = 0; n < 4; ++n) {
        const int c = col0 + wcol + n * 16 + ccol;
#pragma unroll
        for (int m = 0; m < 4; ++m) {
            const int rb = row0 + wrow + m * 16 + crow;
#pragma unroll
            for (int q = 0; q < 4; ++q) {
                const int r = rb + q;
                if (r >= M) continue;
                float v = acc[m][n][q];
                if (C)  C[(long)ks * sCb + (long)r * ldc + c] = v;
                if (Cb) Cb[(long)r * ldcb + c] = (u16)bh(v);
            }
        }
    }
}

// ============ fused gh-GEMM + GRU update + score partial (v6: 128x64 + counted vmcnt) ============
// Grid 256 flat: lx = f>>4 (16 row-tiles of 128), ly = 2*(f&7)+((f>>3)&1) (16 col-tiles of 64).
// 5 gloads/thread/K-step kept in flight across the barrier (T4 counted-vmcnt).
__global__ __launch_bounds__(512)
void gh_gru(const u16* __restrict__ hb_in, const u16* __restrict__ Whh_b,
            const float* __restrict__ bhh, const u16* __restrict__ Gnm_b,
            const float* __restrict__ cbias,
            u16* __restrict__ hb_out,
            const float* __restrict__ Wa, float* __restrict__ gs_part, int tt)
{
    __shared__ __align__(16) u16 lA[2][1024][8];   // 32KB: [k16 0..7][row 0..127]
    __shared__ __align__(16) u16 lB[2][1536][8];   // 48KB: [k16 0..7][g*64+row]
    __shared__ float rowdot[128];

    const int f = blockIdx.x;
    const int ly = 2 * (f & 7) + ((f >> 3) & 1);   // 0..15 col-tile
    const int lx = f >> 4;                          // 0..15 row-tile
    const int row0 = lx * 128;
    const int col0 = ly * 64;

    const int tid = threadIdx.x;
    const int lane = tid & 63;
    const int wave = tid >> 6;     // 0..7
    const int wr = wave >> 1;      // 0..3 : 32-row slice
    const int wc = wave & 1;       // 0..1 : 32-col slice

    long arow = row0 + (tid & 127); if (arow >= NROWS) arow = NROWS - 1;

    const u16* aP0 = hb_in + arow * SQ + (tid >> 7) * 8;
    const u16* aP1 = aP0 + 32;
    const u16* bP[3];
#pragma unroll
    for (int j = 0; j < 3; ++j) {
        const int s = tid + j * 512;
        const int bk16 = s / 192;
        const int grow = s - bk16 * 192;
        bP[j] = Whh_b + (long)((grow >> 6) * SQ + col0 + (grow & 63)) * SQ + bk16 * 8;
    }

    f32x4 acc[3][2][2] = {};

#define GSTAGE(b, kt) do {                                                    \
    const int k0_ = (kt) * 64;                                                \
    gload16(aP0 + k0_, &lA[b][tid][0]);                                       \
    gload16(aP1 + k0_, &lA[b][tid + 512][0]);                                 \
    _Pragma("unroll")                                                         \
    for (int j = 0; j < 3; ++j)                                               \
        gload16(bP[j] + k0_, &lB[b][tid + j * 512][0]);                       \
} while (0)

    GSTAGE(0, 0);
    int buf = 0;
    const int kg = lane >> 4;
    const int lr = lane & 15;
    for (int kt = 0; kt < 16; ++kt) {
        if (kt + 1 < 16) {
            GSTAGE(buf ^ 1, kt + 1);
            asm volatile("s_waitcnt vmcnt(5)" ::: "memory");
        } else {
            asm volatile("s_waitcnt vmcnt(0)" ::: "memory");
        }
        __builtin_amdgcn_s_barrier();
        __builtin_amdgcn_sched_barrier(0);
#pragma unroll
        for (int kk = 0; kk < 2; ++kk) {
            const int k16 = kk * 4 + kg;
            s16x8 af[2], bfr[3][2];
#pragma unroll
            for (int m = 0; m < 2; ++m)
                af[m] = *(const s16x8*)&lA[buf][k16 * 128 + wr * 32 + m * 16 + lr][0];
#pragma unroll
            for (int g = 0; g < 3; ++g)
#pragma unroll
                for (int n = 0; n < 2; ++n)
                    bfr[g][n] = *(const s16x8*)&lB[buf][k16 * 192 + g * 64 + wc * 32 + n * 16 + lr][0];
#pragma unroll
            for (int g = 0; g < 3; ++g)
#pragma unroll
                for (int m = 0; m < 2; ++m)
#pragma unroll
                    for (int n = 0; n < 2; ++n)
                        acc[g][m][n] = __builtin_amdgcn_mfma_f32_16x16x32_bf16(af[m], bfr[g][n], acc[g][m][n], 0, 0, 0);
        }
        __builtin_amdgcn_s_barrier();
        buf ^= 1;
    }
#undef GSTAGE

    if (tid < 128) rowdot[tid] = 0.f;
    __syncthreads();

    const int ccol = lane & 15;
    const int crow4 = (lane >> 4) * 4;
    int col2[2];
    float cbv[3][2], bhv[3][2];
#pragma unroll
    for (int n = 0; n < 2; ++n) {
        const int c = col0 + wc * 32 + n * 16 + ccol;
        col2[n] = c;
#pragma unroll
        for (int g = 0; g < 3; ++g) {
            cbv[g][n] = cbias[g * SQ + c];
            bhv[g][n] = bhh[g * SQ + c];
        }
    }

#pragma unroll
    for (int m = 0; m < 2; ++m) {
#pragma unroll
        for (int q = 0; q < 4; ++q) {
            const int row = row0 + wr * 32 + m * 16 + crow4 + q;
            const bool valid = (row < NROWS);
            float d = 0.f;
            if (valid) {
                const int e = row / BNN;
                const int rr = row - e * BNN;
                const int b_ = rr / 144;
                const int ni = (rr / 12) % 12;
                const int mi = rr % 12;
                const int bt = b_ * TQ + tt;
                const u16* gnp = Gnm_b + ((long)e * 96 + bt * 12 + ni) * 6144;
                const u16* gmp = Gnm_b + ((long)e * 96 + bt * 12 + mi) * 6144 + G3S;
                const float* wap = Wa + (long)e * SQ;
#pragma unroll
                for (int n = 0; n < 2; ++n) {
                    const int c = col2[n];
                    float gr  = acc[0][m][n][q] + bhv[0][n] + b2f(gnp[c]) + b2f(gmp[c]) + cbv[0][n];
                    float gz  = acc[1][m][n][q] + bhv[1][n] + b2f(gnp[SQ + c]) + b2f(gmp[SQ + c]) + cbv[1][n];
                    float ghn = acc[2][m][n][q] + bhv[2][n];
                    float gin = b2f(gnp[2 * SQ + c]) + b2f(gmp[2 * SQ + c]) + cbv[2][n];
                    float rg = sigmoidf(gr);
                    float zg = sigmoidf(gz);
                    float nn2 = tanhf(gin + rg * ghn);
                    float hp = b2f(hb_in[(long)row * SQ + c]);
                    float hn = (1.f - zg) * nn2 + zg * hp;
                    hb_out[(long)row * SQ + c] = (u16)bh(hn);
                    d += hn * wap[c];
                }
            }
            d += __shfl_xor(d, 1); d += __shfl_xor(d, 2);
            d += __shfl_xor(d, 4); d += __shfl_xor(d, 8);
            if (valid && ccol == 0)
                atomicAdd(&rowdot[wr * 32 + m * 16 + crow4 + q], d);
        }
    }
    __syncthreads();
    if (tid < 128) {
        const int row = row0 + tid;
        if (row < NROWS) gs_part[((long)tt * 2048 + row) * 16 + ly] = rowdot[tid];
    }
}

// ============ GRU step tt=0, elementwise (h0 ~ 0: gh0 = bhh; h1 = (1-z)*n) ============
__global__ __launch_bounds__(256)
void gru0(const u16* __restrict__ Gnm_b, const float* __restrict__ cbias,
          const float* __restrict__ bhh,
          u16* __restrict__ hb_out,
          const float* __restrict__ Wa, const float* __restrict__ ba,
          float* __restrict__ gs)
{
    const int row = blockIdx.x;
    const int e = row / BNN;
    const int r = row % BNN;
    const int b_ = r / 144;
    const int ni = (r / 12) % 12;
    const int mi = r % 12;
    const int bt = b_ * TQ;

    const u16* gnp = Gnm_b + ((long)e * 96 + bt * 12 + ni) * 6144;
    const u16* gmp = Gnm_b + ((long)e * 96 + bt * 12 + mi) * 6144 + G3S;
    u16* hpb = hb_out + (long)row * SQ;

    const int s = threadIdx.x * 4;

    ushort4 nR = *(const ushort4*)(gnp + s);
    ushort4 nZ = *(const ushort4*)(gnp + SQ + s);
    ushort4 nN = *(const ushort4*)(gnp + 2 * SQ + s);
    ushort4 mR = *(const ushort4*)(gmp + s);
    ushort4 mZ = *(const ushort4*)(gmp + SQ + s);
    ushort4 mN = *(const ushort4*)(gmp + 2 * SQ + s);
    float4 cbR = *(const float4*)(cbias + s);
    float4 cbZ = *(const float4*)(cbias + SQ + s);
    float4 cbN = *(const float4*)(cbias + 2 * SQ + s);
    float4 bhR = *(const float4*)(bhh + s);
    float4 bhZ = *(const float4*)(bhh + SQ + s);
    float4 bhN = *(const float4*)(bhh + 2 * SQ + s);
    float4 wv  = *(const float4*)(Wa + (long)e * SQ + s);

    float4 hn4;
    float dot = 0.f;

#define GRU0_COMP(c, u)                                                       \
    {                                                                         \
        float rg = sigmoidf(b2f(nR.u) + b2f(mR.u) + cbR.c + bhR.c);           \
        float zg = sigmoidf(b2f(nZ.u) + b2f(mZ.u) + cbZ.c + bhZ.c);           \
        float nn = tanhf(b2f(nN.u) + b2f(mN.u) + cbN.c + rg * bhN.c);         \
        float hn = (1.f - zg) * nn;                                           \
        hn4.c = hn;                                                           \
        dot += hn * wv.c;                                                     \
    }
    GRU0_COMP(x, x) GRU0_COMP(y, y) GRU0_COMP(z, z) GRU0_COMP(w, w)
#undef GRU0_COMP

    ushort4 hb4;
    hb4.x = (u16)bh(hn4.x); hb4.y = (u16)bh(hn4.y);
    hb4.z = (u16)bh(hn4.z); hb4.w = (u16)bh(hn4.w);
    *(ushort4*)(hpb + s) = hb4;

    for (int off = 32; off > 0; off >>= 1) dot += __shfl_down(dot, off);
    __shared__ float red[4];
    if ((threadIdx.x & 63) == 0) red[threadIdx.x >> 6] = dot;
    __syncthreads();
    if (threadIdx.x == 0) {
        float tot = red[0] + red[1] + red[2] + red[3] + ba[e];
        gs[((bt * 12 + ni) * 12 + mi) * EQ + e] = sigmoidf(tot);
    }
}

// ---------- gs finalize for tt=1..3 (16 partials) ----------
__global__ void gs_fin_all(const float* __restrict__ gs_part, const float* __restrict__ ba,
                           float* __restrict__ gs)
{
    int idx = blockIdx.x * 256 + threadIdx.x;
    if (idx >= 3 * 2048) return;
    const int tt = 1 + (idx >> 11);
    const int row = idx & 2047;
    if (row >= NROWS) return;
    float s = 0.f;
#pragma unroll
    for (int j = 0; j < 16; ++j) s += gs_part[((long)tt * 2048 + row) * 16 + j];
    const int e = row / BNN;
    const int rr = row - e * BNN;
    const int b_ = rr / 144;
    const int ni = (rr / 12) % 12;
    const int mi = rr % 12;
    const int bt = b_ * TQ + tt;
    gs[((bt * 12 + ni) * 12 + mi) * EQ + e] = sigmoidf(s + ba[e]);
}

// ---------- generic split-K reduce ----------
__global__ __launch_bounds__(256)
void reduce_k(const float* __restrict__ part, int ksplit, int mn, int Nn,
              const float* __restrict__ bias, long sBiasB, int act,
              float* __restrict__ Cf, long sCfB, int ldcf,
              u16* __restrict__ Cb, long sCbB, int ldcb)
{
    int i4 = blockIdx.x * 256 + threadIdx.x;
    int total4 = mn >> 2;
    if (i4 >= total4) return;
    int b = blockIdx.y;
    const float4* p4 = (const float4*)part;
    float4 s = make_float4(0.f, 0.f, 0.f, 0.f);
    for (int ks = 0; ks < ksplit; ++ks) {
        float4 v = p4[(long)(b * ksplit + ks) * total4 + i4];
        s.x += v.x; s.y += v.y; s.z += v.z; s.w += v.w;
    }
    int i = i4 << 2;
    int r = i / Nn, c = i % Nn;
    if (bias) {
        float4 bv = *(const float4*)(bias + (long)b * sBiasB + c);
        s.x += bv.x; s.y += bv.y; s.z += bv.z; s.w += bv.w;
    }
    if (act == 1) {
        s.x = sigmoidf(s.x); s.y = sigmoidf(s.y); s.z = sigmoidf(s.z); s.w = sigmoidf(s.w);
    } else if (act == 2) {
        s.x = tanhf(s.x); s.y = tanhf(s.y); s.z = tanhf(s.z); s.w = tanhf(s.w);
    }
    if (Cf) *(float4*)(Cf + (long)b * sCfB + (long)r * ldcf + c) = s;
    if (Cb) {
        ushort4 o;
        o.x = (u16)bh(s.x); o.y = (u16)bh(s.y); o.z = (u16)bh(s.z); o.w = (u16)bh(s.w);
        *(ushort4*)(Cb + (long)b * sCbB + (long)r * ldcb + c) = o;
    }
}

// ---------- fused rz split-K reduce + sigmoid + ahat + zbuf ----------
__global__ __launch_bounds__(256)
void rz_ahat_k(const float* __restrict__ part, const float* __restrict__ brz,
               const float* __restrict__ prop, u16* __restrict__ amat_b,
               float* __restrict__ zbuf)
{
    int i = blockIdx.x * 256 + threadIdx.x;   // 0..98303
    int rrow = i >> 10, c = i & 1023;
    float sr = 0.f, sz = 0.f;
#pragma unroll
    for (int ks = 0; ks < 8; ++ks) {
        const float* p = part + (long)ks * 196608 + (long)rrow * 2048;
        sr += p[c]; sz += p[1024 + c];
    }
    float r = sigmoidf(sr + brz[c]);
    float z = sigmoidf(sz + brz[1024 + c]);
    amat_b[(long)rrow * 2048 + 1024 + c] = (u16)bh(r * prop[i]);
    zbuf[i] = z;
}

// ---------- fused hhat split-K reduce + tanh + prop update ----------
__global__ __launch_bounds__(256)
void hhat_prop_k(const float* __restrict__ part, const float* __restrict__ bh_,
                 const float* __restrict__ zbuf,
                 float* __restrict__ prop, u16* __restrict__ prop_b)
{
    int i = blockIdx.x * 256 + threadIdx.x;   // 0..98303
    float s = 0.f;
#pragma unroll
    for (int ks = 0; ks < 8; ++ks) s += part[(long)ks * 98304 + i];
    float hhat = tanhf(s + bh_[i & 1023]);
    float z = zbuf[i];
    float v = (1.f - z) * prop[i] + z * hhat;
    prop[i] = v;
    prop_b[i] = (u16)bh(v);
}

// ---------- fused 3-buffer fp32 -> bf16 convert ----------
__global__ void cvt3_bf16_k(const float* __restrict__ s0, u16* __restrict__ d0, int n0,
                            const float* __restrict__ s1, u16* __restrict__ d1, int n1,
                            const float* __restrict__ s2, u16* __restrict__ d2, int n2)
{
    int i = blockIdx.x * 256 + threadIdx.x;
    const float* s; u16* d; int base;
    if (i < n0) { s = s0; d = d0; base = i; }
    else if (i < n0 + n1) { s = s1; d = d1; base = i - n0; }
    else if (i < n0 + n1 + n2) { s = s2; d = d2; base = i - n0 - n1; }
    else return;
    float4 v = ((const float4*)s)[base];
    ushort4 o;
    o.x = (u16)bh(v.x); o.y = (u16)bh(v.y); o.z = (u16)bh(v.z); o.w = (u16)bh(v.w);
    ((ushort4*)d)[base] = o;
}

__global__ __launch_bounds__(256)
void transpose_wc(const float* __restrict__ Wcomp, float* __restrict__ W1T, float* __restrict__ W2T)
{
    __shared__ float t1[32][33];
    __shared__ float t2[32][33];
    const int tx = threadIdx.x & 31;
    const int ty = threadIdx.x >> 5;
    const int d0 = blockIdx.x * 32;
    const int s0 = blockIdx.y * 32;
#pragma unroll
    for (int k = 0; k < 4; ++k) {
        int d = d0 + ty + k * 8;
        t1[ty + k * 8][tx] = Wcomp[(long)d * 2048 + s0 + tx];
        t2[ty + k * 8][tx] = Wcomp[(long)d * 2048 + 1024 + s0 + tx];
    }
    __syncthreads();
#pragma unroll
    for (int k = 0; k < 4; ++k) {
        int s = s0 + ty + k * 8;
        W1T[(long)s * 1024 + d0 + tx] = t1[tx][ty + k * 8];
        W2T[(long)s * 1024 + d0 + tx] = t2[tx][ty + k * 8];
    }
}

__global__ void pack_rz(const float* __restrict__ Wr, const float* __restrict__ Wz,
                        const float* __restrict__ br, const float* __restrict__ bz,
                        u16* __restrict__ Wrz, float* __restrict__ brz)
{
    int i4 = blockIdx.x * 256 + threadIdx.x;
    if (i4 < 512) {
        int c = i4 * 4;
        float4 b = (c < 1024) ? *(const float4*)(br + c) : *(const float4*)(bz + c - 1024);
        *(float4*)(brz + c) = b;
    }
    if (i4 >= 1048576) return;
    int i = i4 * 4;
    int j = i >> 11;
    int c = i & 2047;
    float4 v = (j < 1024) ? *(const float4*)(Wr + (long)j * 2048 + c)
                          : *(const float4*)(Wz + (long)(j - 1024) * 2048 + c);
    ushort4 o;
    o.x = (u16)bh(v.x); o.y = (u16)bh(v.y); o.z = (u16)bh(v.z); o.w = (u16)bh(v.w);
    *(ushort4*)(Wrz + i) = o;
}

__global__ void cbias_k(const float* __restrict__ Wih, const float* __restrict__ bih,
                        const float* __restrict__ bcomp, float* __restrict__ cbias)
{
    int g = blockIdx.x * blockDim.x + threadIdx.x;
    if (g >= G3S) return;
    const float* w = Wih + (long)g * SQ;
    float s = 0.f;
    for (int k = 0; k < SQ; k += 4) {
        float4 wv = *(const float4*)(w + k);
        float4 bv = *(const float4*)(bcomp + k);
        s += wv.x * bv.x + wv.y * bv.y + wv.z * bv.z + wv.w * bv.w;
    }
    cbias[g] = s + bih[g];
}

// ---------------- merged + amat fused ----------------
__global__ __launch_bounds__(256)
void merged_amat_k(const float* __restrict__ gs, const u16* __restrict__ msgs_b,
                   const float* __restrict__ prop, u16* __restrict__ amat_b)
{
    const int bn = blockIdx.x;
    const int bt = bn / 12;
    __shared__ float g[84];
    if (threadIdx.x < 84) g[threadIdx.x] = gs[bn * 84 + threadIdx.x];
    __syncthreads();
    const int s = threadIdx.x * 4;
    float4 acc = make_float4(0.f, 0.f, 0.f, 0.f);
    for (int j = 0; j < 84; ++j) {
        const ushort4 mv = *(const ushort4*)(msgs_b + ((long)(bt * 84 + j)) * SQ + s);
        float gj = g[j];
        acc.x += gj * b2f(mv.x);
        acc.y += gj * b2f(mv.y);
        acc.z += gj * b2f(mv.z);
        acc.w += gj * b2f(mv.w);
    }
    ushort4 o;
    o.x = (u16)bh(acc.x); o.y = (u16)bh(acc.y); o.z = (u16)bh(acc.z); o.w = (u16)bh(acc.w);
    *(ushort4*)(amat_b + (long)bn * 2048 + s) = o;
    float4 pv = *(const float4*)(prop + (long)bn * SQ + s);
    ushort4 o2;
    o2.x = (u16)bh(pv.x); o2.y = (u16)bh(pv.y); o2.z = (u16)bh(pv.z); o2.w = (u16)bh(pv.w);
    *(ushort4*)(amat_b + (long)bn * 2048 + 1024 + s) = o2;
}

// ---------------- final outputs ----------------
__global__ __launch_bounds__(256)
void outputs_k(const float* __restrict__ gs, float* __restrict__ out)
{
    __shared__ float s_act[672];
    __shared__ float s_asum[96];
    int tid = threadIdx.x;
    for (int idx = tid; idx < 672; idx += 256) {
        int bn = idx / 7, e = idx % 7;
        float sum = 0.f;
        for (int m = 0; m < 12; ++m) {
            float g0 = gs[bn * 84 + m * 7];
            sum += (1.f - g0) * gs[bn * 84 + m * 7 + e];
        }
        s_act[idx] = sum;
        out[idx] = sum;
    }
    for (int idx = tid; idx < 96; idx += 256) {
        float a = 0.f;
        for (int m = 0; m < 12; ++m) a += 1.f - gs[idx * 84 + m * 7];
        s_asum[idx] = a;
    }
    for (int idx = tid; idx < 1152; idx += 256) {
        int bn = idx / 12, m = idx % 12;
        out[720 + idx] = 1.f - gs[bn * 84 + m * 7];
    }
    __syncthreads();
    if (tid < 8) {
        float tmp[6];
        float mx = -1e30f;
        for (int e = 1; e < 7; ++e) {
            float sum = 0.f;
            for (int n = 0; n < 12; ++n) {
                int bn = tid * 12 + n;
                sum += s_act[bn * 7 + e] * s_asum[bn];
            }
            tmp[e - 1] = sum;
            mx = fmaxf(mx, sum);
        }
        float den = 0.f;
        for (int e = 0; e < 6; ++e) { tmp[e] = expf(tmp[e] - mx); den += tmp[e]; }
        for (int e = 0; e < 6; ++e) out[672 + tid * 6 + e] = tmp[e] / den;
    }
}

// ---------------- host ----------------
template<int AS32, int BS32>
static void launch_gemm(const void* A, long sAb, int lda,
                        const void* B, long sBb, int ldb,
                        const float* bias, long sBiasb,
                        float* C, long sCb, int ldc,
                        u16* Cb, long sCbb, int ldcb,
                        int M, int Nn, int K, int act, int batch, int ksplit,
                        hipStream_t stream)
{
    dim3 grid((M + 63) / 64, (Nn + 127) / 128, batch * ksplit);
    gemm_mfma<AS32, BS32><<<grid, dim3(256), 0, stream>>>(
        A, sAb, lda, B, sBb, ldb, bias, sBiasb, C, sCb, ldc, Cb, sCbb, ldcb,
        M, Nn, K, act, ksplit);
}

extern "C" void kernel_launch(void* const* d_in, const int* in_sizes, int n_in,
                              void* d_out, int out_size, void* d_ws, size_t ws_size,
                              hipStream_t stream)
{
    const float* pose  = (const float*)d_in[0];
    const float* Wc    = (const float*)d_in[5];
    const float* bc    = (const float*)d_in[6];
    const float* We    = (const float*)d_in[7];
    const float* be    = (const float*)d_in[8];
    const float* Wcomp = (const float*)d_in[9];
    const float* bcomp = (const float*)d_in[10];
    const float* Wr    = (const float*)d_in[11];
    const float* br    = (const float*)d_in[12];
    const float* Wz    = (const float*)d_in[13];
    const float* bz    = (const float*)d_in[14];
    const float* Wh    = (const float*)d_in[15];
    const float* bh_   = (const float*)d_in[16];
    const float* Wih   = (const float*)d_in[17];
    const float* Whh   = (const float*)d_in[18];
    const float* bih   = (const float*)d_in[19];
    const float* bhh   = (const float*)d_in[20];
    const float* Wa    = (const float*)d_in[21];
    const float* ba    = (const float*)d_in[22];

    float* ws = (float*)d_ws;
    // fp32 region
    float* prop    = ws;                    // 98304
    float* cbias   = prop + 98304;          // 3072
    float* scratch = cbias + 3072;          // 8257536  (split-K partials / W1T/W2T)
    float* gs      = scratch + 8257536;     // 8064
    float* zbuf    = gs + 8064;             // 98304
    float* brz     = zbuf + 98304;          // 2048
    float* gs_part = brz + 2048;            // 131072 (4 x 2048 x 16)
    float* fend    = gs_part + 131072;
    // bf16 region
    u16* Whh_b  = (u16*)fend;               // 3145728
    u16* Wnm_b  = Whh_b + 3145728;          // 6291456  (6144 x 1024)
    u16* Wrz_b  = Wnm_b + 6291456;          // 4194304
    u16* Gnm_b  = Wrz_b + 4194304;          // 4128768  (7 x 96 x 6144)
    u16* msgs_b = Gnm_b + 4128768;          // 688128
    u16* h_b0   = msgs_b + 688128;          // 2064384
    u16* h_b1   = h_b0 + 2064384;           // 2064384
    u16* prop_b = h_b1 + 2064384;           // 98304
    u16* amat_b = prop_b + 98304;           // 196608
    u16* pose_b = amat_b + 196608;          // 2534400
    u16* Wc_b   = pose_b + 2534400;         // 27033600

    float* W1T = scratch;                   // transient
    float* W2T = scratch + 1048576;         // transient

    // ---- once per call ----
    // fused convert: Whh (786432 f4) + pose (633600 f4) + Wc (6758400 f4)
    hipLaunchKernelGGL(cvt3_bf16_k, dim3(31947), dim3(256), 0, stream,
                       Whh, Whh_b, 786432, pose, pose_b, 633600, Wc, Wc_b, 6758400);
    hipLaunchKernelGGL(cbias_k, dim3(12), dim3(256), 0, stream, Wih, bih, bcomp, cbias);
    hipLaunchKernelGGL(transpose_wc, dim3(32, 32), dim3(256), 0, stream, Wcomp, W1T, W2T);
    hipLaunchKernelGGL(pack_rz, dim3(4096), dim3(256), 0, stream, Wr, Wz, br, bz, Wrz_b, brz);
    // Wnm rows 0..3071 = Wih @ W1T^T ; rows 3072..6143 = Wih @ W2T^T
    gemm128_f32<<<dim3(24, 8, 1), dim3(256), 0, stream>>>(
        Wih, SQ, W1T, SQ, nullptr, 0, SQ, Wnm_b, SQ, G3S, SQ, SQ, 1);
    gemm128_f32<<<dim3(24, 8, 1), dim3(256), 0, stream>>>(
        Wih, SQ, W2T, SQ, nullptr, 0, SQ, Wnm_b + (long)G3S * SQ, SQ, G3S, SQ, SQ, 1);
    // prop = pose @ Wc^T + bc : bf16 operands, ksplit=55
    launch_gemm<0, 0>(pose_b, 0, DIN, Wc_b, 0, DIN, nullptr, 0,
                      scratch, 98304, SQ, nullptr, 0, 0, 96, SQ, DIN, 0, 1, 55, stream);
    hipLaunchKernelGGL(reduce_k, dim3(96, 1), dim3(256), 0, stream,
                       scratch, 55, 98304, SQ, bc, 0L, 0,
                       prop, 0L, SQ, prop_b, 0L, SQ);

    for (int t = 0; t <= TSQ; ++t) {
        // msgs[bt,n,e,s] = prop @ We[e]^T + be[e] : batch 7, ksplit 4
        launch_gemm<0, 1>(prop_b, 0, SQ, We, (long)SQ * SQ, SQ, nullptr, 0,
                          scratch, 98304, SQ, nullptr, 0, 0, 96, SQ, SQ, 0, EQ, 4, stream);
        hipLaunchKernelGGL(reduce_k, dim3(96, EQ), dim3(256), 0, stream,
                           scratch, 4, 98304, SQ, be, (long)SQ, 0,
                           (float*)nullptr, 0L, 0, msgs_b, (long)SQ, EQ * SQ);
        // Gnm = msgs_e @ Wnm^T : batch 7, direct bf16 write
        launch_gemm<0, 0>(msgs_b, SQ, EQ * SQ, Wnm_b, 0, SQ, nullptr, 0,
                          nullptr, 0, 0, Gnm_b, 589824, 6 * SQ, 96, 6 * SQ, SQ, 0, EQ, 1, stream);
        // GRU scan: tt=0 elementwise, then 3 fused GEMM steps (bf16-carried h)
        hipLaunchKernelGGL(gru0, dim3(NROWS), dim3(256), 0, stream,
                           Gnm_b, cbias, bhh, h_b0, Wa, ba, gs);
        for (int tt = 1; tt < TQ; ++tt) {
            const u16* hin = (tt & 1) ? h_b0 : h_b1;
            u16* hout = (tt & 1) ? h_b1 : h_b0;
            hipLaunchKernelGGL(gh_gru, dim3(256), dim3(512), 0, stream,
                               hin, Whh_b, bhh, Gnm_b, cbias, hout, Wa, gs_part, tt);
        }
        hipLaunchKernelGGL(gs_fin_all, dim3(24), dim3(256), 0, stream, gs_part, ba, gs);
        if (t < TSQ) {
            hipLaunchKernelGGL(merged_amat_k, dim3(96), dim3(256), 0, stream,
                               gs, msgs_b, prop, amat_b);
            // rz partials : ksplit=8
            launch_gemm<0, 0>(amat_b, 0, 2 * SQ, Wrz_b, 0, 2 * SQ, nullptr, 0,
                              scratch, 196608, 2 * SQ, nullptr, 0, 0, 96, 2 * SQ, 2 * SQ, 0, 1, 8, stream);
            hipLaunchKernelGGL(rz_ahat_k, dim3(384), dim3(256), 0, stream,
                               scratch, brz, prop, amat_b, zbuf);
            // hhat partials : ksplit=8
            launch_gemm<0, 1>(amat_b, 0, 2 * SQ, Wh, 0, 2 * SQ, nullptr, 0,
                              scratch, 98304, SQ, nullptr, 0, 0, 96, SQ, 2 * SQ, 0, 1, 8, stream);
            hipLaunchKernelGGL(hhat_prop_k, dim3(384), dim3(256), 0, stream,
                               scratch, bh_, zbuf, prop, prop_b);
        }
    }

    hipLaunchKernelGGL(outputs_k, dim3(1), dim3(256), 0, stream, gs, (float*)d_out);
}